// Round 1
// baseline (2112.970 us; speedup 1.0000x reference)
//
#include <hip/hip_runtime.h>
#include <math.h>

namespace {

constexpr int CB = 16;            // batches per chunk
constexpr int NCHUNK = 64 / CB;

// ---- workspace layout (float offsets) ----
constexpr size_t o_hnew = 0;
constexpr size_t o_q    = o_hnew + 64*512;
constexpr size_t o_u    = o_q    + 64*512;
constexpr size_t o_aw   = o_u    + 64*512;
constexpr size_t o_ctx  = o_aw   + 64*512;
constexpr size_t o_cc   = o_ctx  + 64*512;
constexpr size_t o_won  = o_cc   + 64*512;            // 64*4*512
constexpr size_t o_oo   = o_won  + 64*4*512;          // 256
constexpr size_t o_xT   = o_oo   + 256;
constexpr size_t o_hT   = o_xT   + 64*512;
constexpr size_t o_giT  = o_hT   + 64*512;            // 1536*64
constexpr size_t o_ghT  = o_giT  + 1536*64;
constexpr size_t o_part = o_ghT  + 1536*64;           // 64*8*4*1024
constexpr size_t o_big  = o_part + (size_t)64*8*4*1024;
constexpr size_t o_adj  = o_big;                      // CB*512*512
constexpr size_t o_h1   = o_adj  + (size_t)CB*512*512;
constexpr size_t o_bufA = o_h1   + (size_t)CB*512*512;
constexpr size_t o_w2w  = o_adj;                      // CB*512*1024 overlays adj+h1 (dead)

__device__ __forceinline__ float wave_sum(float v) {
#pragma unroll
  for (int off = 32; off; off >>= 1) v += __shfl_down(v, off, 64);
  return v;
}
__device__ __forceinline__ float wave_max(float v) {
#pragma unroll
  for (int off = 32; off; off >>= 1) v = fmaxf(v, __shfl_down(v, off, 64));
  return v;
}
__device__ __forceinline__ float2 blocksum2(float a, float b, float2* red, int t, int nw) {
#pragma unroll
  for (int off = 32; off; off >>= 1) {
    a += __shfl_down(a, off, 64);
    b += __shfl_down(b, off, 64);
  }
  __syncthreads();                 // protect red reuse from previous call
  if ((t & 63) == 0) red[t >> 6] = make_float2(a, b);
  __syncthreads();
  float sa = 0.f, sb = 0.f;
  for (int i = 0; i < nw; ++i) { sa += red[i].x; sb += red[i].y; }
  return make_float2(sa, sb);
}

// ======================= generic 64x64 fp32 tiled GEMM =======================
// C[M,N] = A[M,K] @ B[K,N] (+ epilogue per MODE), batched via blockIdx.z.
// MODE 0: += aw[(c0+z)*512+row] * u[(c0+z)*512+col]   (XW1 build)
// MODE 1: relu(x + bias[col])                         (h1)
// MODE 2: plain                                       (t, GRU gates)
// MODE 3: x + bias[col]                               (w2w_pre)
template<int MODE>
__global__ __launch_bounds__(256)
void gemm_tile(const float* __restrict__ A, int lda, long sA,
               const float* __restrict__ Bm, int ldb, long sB,
               float* __restrict__ C, int ldc, long sC,
               int K,
               const float* __restrict__ bias,
               const float* __restrict__ aw,
               const float* __restrict__ u,
               int c0)
{
  __shared__ float As[64][20];
  __shared__ float Bs[16][68];
  const int z = blockIdx.z;
  const float* Ab = A  + (long)z * sA;
  const float* Bp = Bm + (long)z * sB;
  float*       Cb = C  + (long)z * sC;
  const int tm = blockIdx.y * 64;
  const int tn = blockIdx.x * 64;
  const int t  = threadIdx.x;
  const int ty4 = (t >> 4) * 4;
  const int tx4 = (t & 15) * 4;
  const int aRow = t >> 2, aK = (t & 3) << 2;
  const int bK   = t >> 4, bN = (t & 15) << 2;

  float acc[4][4] = {};
  for (int k0 = 0; k0 < K; k0 += 16) {
    const float4 av = *(const float4*)&Ab[(long)(tm + aRow) * lda + k0 + aK];
    const float4 bv = *(const float4*)&Bp[(long)(k0 + bK) * ldb + tn + bN];
    __syncthreads();
    *(float4*)&As[aRow][aK] = av;
    *(float4*)&Bs[bK][bN]   = bv;
    __syncthreads();
#pragma unroll
    for (int k = 0; k < 16; ++k) {
      float a_[4], b_[4];
#pragma unroll
      for (int i = 0; i < 4; ++i) a_[i] = As[ty4 + i][k];
#pragma unroll
      for (int j = 0; j < 4; ++j) b_[j] = Bs[k][tx4 + j];
#pragma unroll
      for (int i = 0; i < 4; ++i)
#pragma unroll
        for (int j = 0; j < 4; ++j)
          acc[i][j] += a_[i] * b_[j];
    }
  }

#pragma unroll
  for (int i = 0; i < 4; ++i) {
    const int row = tm + ty4 + i;
    const int col = tn + tx4;
    float4 v = make_float4(acc[i][0], acc[i][1], acc[i][2], acc[i][3]);
    if (MODE == 0) {
      const float awv = aw[(c0 + z) * 512 + row];
      const float4 uv = *(const float4*)&u[(c0 + z) * 512 + col];
      v.x += awv * uv.x; v.y += awv * uv.y; v.z += awv * uv.z; v.w += awv * uv.w;
    } else if (MODE == 1) {
      const float4 bb = *(const float4*)&bias[col];
      v.x = fmaxf(v.x + bb.x, 0.f); v.y = fmaxf(v.y + bb.y, 0.f);
      v.z = fmaxf(v.z + bb.z, 0.f); v.w = fmaxf(v.w + bb.w, 0.f);
    } else if (MODE == 3) {
      const float4 bb = *(const float4*)&bias[col];
      v.x += bb.x; v.y += bb.y; v.z += bb.z; v.w += bb.w;
    }
    *(float4*)&Cb[(long)row * ldc + col] = v;
  }
}

// ======================= small fused kernels =======================

// Build xT[k*64+b] = emb[step[b]][k], hT[k*64+b] = last_hidden[b][k]
__global__ __launch_bounds__(256)
void k_prep(const int* __restrict__ step, const float* __restrict__ emb,
            const float* __restrict__ last_hidden, float* __restrict__ xT, float* __restrict__ hT)
{
  const int idx = blockIdx.x * 256 + threadIdx.x;   // 32768
  const int k = idx >> 6, b = idx & 63;
  xT[idx] = emb[(size_t)step[b] * 512 + k];
  hT[idx] = last_hidden[b * 512 + k];
}

// GRU gate combine (torch semantics); giT/ghT are (1536,64)
__global__ __launch_bounds__(256)
void k_gru(const float* __restrict__ giT, const float* __restrict__ ghT,
           const float* __restrict__ last_hidden, const float* __restrict__ b_ih,
           const float* __restrict__ b_hh, float* __restrict__ hnew, float* __restrict__ hnew_out)
{
  const int idx = blockIdx.x * 256 + threadIdx.x;   // 32768
  const int b = idx >> 9, tt = idx & 511;
  const float ir  = giT[tt * 64 + b]          + b_ih[tt];
  const float iz  = giT[(512 + tt) * 64 + b]  + b_ih[512 + tt];
  const float inn = giT[(1024 + tt) * 64 + b] + b_ih[1024 + tt];
  const float hr  = ghT[tt * 64 + b]          + b_hh[tt];
  const float hz  = ghT[(512 + tt) * 64 + b]  + b_hh[512 + tt];
  const float hn  = ghT[(1024 + tt) * 64 + b] + b_hh[1024 + tt];
  const float h   = last_hidden[idx];
  const float r = 1.f / (1.f + __expf(-(ir + hr)));
  const float z = 1.f / (1.f + __expf(-(iz + hz)));
  const float n = tanhf(inn + r * hn);
  const float o = (1.f - z) * n + z * h;
  hnew[idx] = o;
  hnew_out[idx] = o;
}

// q = h_new @ attn_W ; u = h_new @ gc1_W[:512]
__global__ __launch_bounds__(512)
void k_qu(const float* __restrict__ hnew, const float* __restrict__ attn_W,
          const float* __restrict__ gc1_W, float* __restrict__ q, float* __restrict__ u)
{
  const int b = blockIdx.x, j = threadIdx.x;
  __shared__ float hs[512];
  hs[j] = hnew[b * 512 + j];
  __syncthreads();
  float qa = 0.f, ua = 0.f;
  for (int h = 0; h < 512; ++h) {
    const float hv = hs[h];
    qa += hv * attn_W[(size_t)h * 512 + j];
    ua += hv * gc1_W[(size_t)h * 512 + j];
  }
  q[b * 512 + j] = qa;
  u[b * 512 + j] = ua;
}

// scores (softmax-shift-invariant: q·enc), softmax, context. One block per b.
__global__ __launch_bounds__(512)
void k_attn(const float* __restrict__ q, const float* __restrict__ enc,
            float* __restrict__ aw_dout, float* __restrict__ aw_ws, float* __restrict__ ctx)
{
  const int b = blockIdx.x, t = threadIdx.x;
  const int w = t >> 6, lane = t & 63;
  __shared__ float qs[512];
  __shared__ float sc[512];
  __shared__ float red[8];
  qs[t] = q[b * 512 + t];
  __syncthreads();
  for (int s = w; s < 512; s += 8) {
    const float* e = enc + ((size_t)s * 64 + b) * 512;
    float a = 0.f;
#pragma unroll
    for (int j = 0; j < 8; ++j) a += qs[lane + 64 * j] * e[lane + 64 * j];
    a = wave_sum(a);
    if (lane == 0) sc[s] = a;
  }
  __syncthreads();
  const float v = sc[t];
  float m = wave_max(v);
  if (lane == 0) red[w] = m;
  __syncthreads();
  float mm = red[0];
#pragma unroll
  for (int i = 1; i < 8; ++i) mm = fmaxf(mm, red[i]);
  const float e = __expf(v - mm);
  float s = wave_sum(e);
  __syncthreads();
  if (lane == 0) red[w] = s;
  __syncthreads();
  float tot = 0.f;
#pragma unroll
  for (int i = 0; i < 8; ++i) tot += red[i];
  const float awv = e / tot;
  aw_dout[b * 512 + t] = awv;
  aw_ws[b * 512 + t]   = awv;
  sc[t] = awv;
  __syncthreads();
  float a = 0.f;
  for (int s2 = 0; s2 < 512; ++s2)
    a += sc[s2] * enc[((size_t)s2 * 64 + b) * 512 + t];
  ctx[b * 512 + t] = a;
}

// concat_output = relu([h_new, ctx] @ concat_W.T + b)
__global__ __launch_bounds__(512)
void k_concat(const float* __restrict__ hnew, const float* __restrict__ ctx,
              const float* __restrict__ W, const float* __restrict__ bias,
              float* __restrict__ out_cc, float* __restrict__ cc_ws)
{
  const int b = blockIdx.x, o = threadIdx.x;
  __shared__ __align__(16) float cat[1024];
  cat[o] = hnew[b * 512 + o];
  cat[512 + o] = ctx[b * 512 + o];
  __syncthreads();
  const float* wr = W + (size_t)o * 1024;
  float acc = bias[o];
  for (int k = 0; k < 1024; k += 4) {
    const float4 wv = *(const float4*)&wr[k];
    const float4 cv = *(const float4*)&cat[k];
    acc += wv.x * cv.x + wv.y * cv.y + wv.z * cv.z + wv.w * cv.w;
  }
  acc = fmaxf(acc, 0.f);
  out_cc[b * 512 + o] = acc;
  cc_ws[b * 512 + o]  = acc;
}

// wo_n[b,o,s] = masked(word_op[b,s,o]) / (sum_s + 1e-30)
__global__ __launch_bounds__(512)
void k_wo(const float* __restrict__ word_op, const int* __restrict__ seq_mask, float* __restrict__ won)
{
  const int b = blockIdx.x, o = blockIdx.y, s = threadIdx.x;
  float v = word_op[((size_t)(b * 512 + s)) * 4 + o];
  if (seq_mask[b * 512 + s] != 0) v = 0.f;
  __shared__ float red[8];
  float sm = wave_sum(v);
  if ((s & 63) == 0) red[s >> 6] = sm;
  __syncthreads();
  float tot = 0.f;
#pragma unroll
  for (int i = 0; i < 8; ++i) tot += red[i];
  won[((size_t)b * 4 + o) * 512 + s] = v / (tot + 1e-30f);
}

// adj = where(exist==1, word_word, 0), one chunk of CB batches
__global__ __launch_bounds__(256)
void k_adj(const float* __restrict__ ww, const int* __restrict__ ex, float* __restrict__ adj, int c0)
{
  const size_t i = (size_t)blockIdx.x * 256 + threadIdx.x;
  const size_t base4 = (size_t)c0 * 512 * 512 / 4;
  const float4 w4 = ((const float4*)ww)[base4 + i];
  const int4   e4 = ((const int4*)ex)[base4 + i];
  float4 r;
  r.x = (e4.x == 1) ? w4.x : 0.f;
  r.y = (e4.y == 1) ? w4.y : 0.f;
  r.z = (e4.z == 1) ? w4.z : 0.f;
  r.w = (e4.w == 1) ? w4.w : 0.f;
  ((float4*)adj)[i] = r;
}

// Fused: LN(w2w_pre) + w_all, contracted with wo_n (4 op rows) -> partials.
// grid (CB, 8): block handles 64 s-rows for batch c0+z.
__global__ __launch_bounds__(256)
void k_reduce(const float* __restrict__ w2w, const float* __restrict__ aw,
              const float* __restrict__ hnew, const float* __restrict__ enc,
              const float* __restrict__ won, const float* __restrict__ ng,
              const float* __restrict__ nb, float* __restrict__ part, int c0)
{
  const int z = blockIdx.x;
  const int b = c0 + z;
  const int yb = blockIdx.y;
  const int t = threadIdx.x;
  __shared__ float2 red[4];
  float acc[4][4] = {};
  for (int s = yb * 64; s < yb * 64 + 64; ++s) {
    const float* row = w2w + ((size_t)z * 512 + s) * 1024;
    float x[4];
    float ls = 0.f, lss = 0.f;
#pragma unroll
    for (int k = 0; k < 4; ++k) { x[k] = row[t + 256 * k]; ls += x[k]; lss += x[k] * x[k]; }
    const float2 ss = blocksum2(ls, lss, red, t, 4);
    const float mean = ss.x * (1.f / 1024.f);
    const float var  = ss.y * (1.f / 1024.f) - mean * mean;
    const float inv  = rsqrtf(var + 1e-6f);
    const float awv = aw[b * 512 + s];
    const float w0 = won[((size_t)b * 4 + 0) * 512 + s];
    const float w1 = won[((size_t)b * 4 + 1) * 512 + s];
    const float w2 = won[((size_t)b * 4 + 2) * 512 + s];
    const float w3 = won[((size_t)b * 4 + 3) * 512 + s];
#pragma unroll
    for (int k = 0; k < 4; ++k) {
      const int d = t + 256 * k;
      float val = (x[k] - mean) * inv * ng[d] + nb[d];
      if (k < 2) val += awv * hnew[b * 512 + d];                       // s2w half
      else       val += enc[((size_t)s * 64 + b) * 512 + (d - 512)];   // enc half
      acc[0][k] += w0 * val; acc[1][k] += w1 * val;
      acc[2][k] += w2 * val; acc[3][k] += w3 * val;
    }
  }
#pragma unroll
  for (int o = 0; o < 4; ++o)
#pragma unroll
    for (int k = 0; k < 4; ++k)
      part[(((size_t)(b * 8 + yb) * 4 + o) << 10) + t + 256 * k] = acc[o][k];
}

// op head: ctx_op -> wo_W -> LN1 -> [.,ops] -> ot_W -> LN2 + ops -> dot(concat)
__global__ __launch_bounds__(512)
void k_op(const float* __restrict__ part, const float* __restrict__ wo_W, const float* __restrict__ wo_b,
          const float* __restrict__ n1g, const float* __restrict__ n1b,
          const float* __restrict__ ops, const float* __restrict__ ot_W, const float* __restrict__ ot_b,
          const float* __restrict__ n2g, const float* __restrict__ n2b,
          const float* __restrict__ cc, const float* __restrict__ ops_bias,
          float* __restrict__ oo)
{
  const int b = blockIdx.x, o = blockIdx.y, t = threadIdx.x;
  __shared__ __align__(16) float catA[1024];
  __shared__ float2 red[8];
  for (int d = t; d < 1024; d += 512) {
    float s = 0.f;
#pragma unroll
    for (int p = 0; p < 8; ++p)
      s += part[(((size_t)(b * 8 + p) * 4 + o) << 10) + d];
    catA[d] = s;
  }
  __syncthreads();
  float acc = wo_b[t];
  {
    const float* wr = wo_W + (size_t)t * 1024;
    for (int k = 0; k < 1024; k += 4) {
      const float4 wv = *(const float4*)&wr[k];
      const float4 cv = *(const float4*)&catA[k];
      acc += wv.x * cv.x + wv.y * cv.y + wv.z * cv.z + wv.w * cv.w;
    }
  }
  const float ot = fmaxf(acc, 0.f);
  const float2 s1s = blocksum2(ot, ot * ot, red, t, 8);
  const float m1 = s1s.x * (1.f / 512.f);
  const float v1 = s1s.y * (1.f / 512.f) - m1 * m1;
  const float s1 = (ot - m1) * rsqrtf(v1 + 1e-6f) * n1g[t] + n1b[t];
  __syncthreads();
  catA[t] = s1;
  catA[512 + t] = ops[o * 512 + t];
  __syncthreads();
  float acc2 = ot_b[t];
  {
    const float* wr = ot_W + (size_t)t * 1024;
    for (int k = 0; k < 1024; k += 4) {
      const float4 wv = *(const float4*)&wr[k];
      const float4 cv = *(const float4*)&catA[k];
      acc2 += wv.x * cv.x + wv.y * cv.y + wv.z * cv.z + wv.w * cv.w;
    }
  }
  const float oh = fmaxf(acc2, 0.f);
  const float2 s2s = blocksum2(oh, oh * oh, red, t, 8);
  const float m2 = s2s.x * (1.f / 512.f);
  const float v2 = s2s.y * (1.f / 512.f) - m2 * m2;
  const float opo = (oh - m2) * rsqrtf(v2 + 1e-6f) * n2g[t] + n2b[t] + ops[o * 512 + t];
  const float p = cc[b * 512 + t] * opo;
  const float2 s3 = blocksum2(p, 0.f, red, t, 8);
  if (t == 0) oo[b * 4 + o] = s3.x + ops_bias[o];
}

// nop head + log_softmax over 128
__global__ __launch_bounds__(128)
void k_final(const float* __restrict__ oo, const float* __restrict__ cc,
             const float* __restrict__ nop_W, const float* __restrict__ nop_b,
             float* __restrict__ outp)
{
  const int b = blockIdx.x, t = threadIdx.x;
  __shared__ __align__(16) float ccs[512];
  __shared__ float red[2];
  __shared__ float red2[2];
  for (int i = t; i < 512; i += 128) ccs[i] = cc[b * 512 + i];
  __syncthreads();
  float v;
  if (t < 4) {
    v = oo[b * 4 + t];
  } else {
    const int j = t - 4;
    const float* wr = nop_W + (size_t)j * 512;
    float a = nop_b[j];
    for (int k = 0; k < 512; k += 4) {
      const float4 w4 = *(const float4*)&wr[k];
      const float4 c4 = *(const float4*)&ccs[k];
      a += w4.x * c4.x + w4.y * c4.y + w4.z * c4.z + w4.w * c4.w;
    }
    v = a;
  }
  float m = wave_max(v);
  if ((t & 63) == 0) red[t >> 6] = m;
  __syncthreads();
  m = fmaxf(red[0], red[1]);
  const float e = __expf(v - m);
  float s = wave_sum(e);
  if ((t & 63) == 0) red2[t >> 6] = s;
  __syncthreads();
  s = red2[0] + red2[1];
  outp[b * 128 + t] = v - m - logf(s);
}

} // namespace

extern "C" void kernel_launch(void* const* d_in, const int* in_sizes, int n_in,
                              void* d_out, int out_size, void* d_ws, size_t ws_size,
                              hipStream_t stream)
{
  const int*   input_step  = (const int*)  d_in[0];
  const float* last_hidden = (const float*)d_in[1];
  const float* enc         = (const float*)d_in[2];
  const float* word_word   = (const float*)d_in[3];
  const float* word_op     = (const float*)d_in[4];
  const int*   word_exist  = (const int*)  d_in[5];
  const int*   seq_mask    = (const int*)  d_in[6];
  const float* emb         = (const float*)d_in[7];
  const float* W_ih        = (const float*)d_in[8];
  const float* W_hh        = (const float*)d_in[9];
  const float* b_ih        = (const float*)d_in[10];
  const float* b_hh        = (const float*)d_in[11];
  const float* attn_W      = (const float*)d_in[12];
  // d_in[13] attn_b: softmax-shift-invariant, unused
  const float* concat_W    = (const float*)d_in[14];
  const float* concat_b    = (const float*)d_in[15];
  const float* ops         = (const float*)d_in[16];
  const float* ops_bias    = (const float*)d_in[17];
  const float* nop_W       = (const float*)d_in[18];
  const float* nop_b       = (const float*)d_in[19];
  const float* gc1_W       = (const float*)d_in[20];
  const float* gc1_b       = (const float*)d_in[21];
  const float* gc2_W       = (const float*)d_in[22];
  const float* gc2_b       = (const float*)d_in[23];
  const float* norm_g      = (const float*)d_in[24];
  const float* norm_b      = (const float*)d_in[25];
  const float* norm1_g     = (const float*)d_in[26];
  const float* norm1_b     = (const float*)d_in[27];
  const float* norm2_g     = (const float*)d_in[28];
  const float* norm2_b     = (const float*)d_in[29];
  const float* wo_W        = (const float*)d_in[30];
  const float* wo_b        = (const float*)d_in[31];
  const float* ot_W        = (const float*)d_in[32];
  const float* ot_b        = (const float*)d_in[33];

  float* ws  = (float*)d_ws;
  float* out = (float*)d_out;

  float* hnew = ws + o_hnew;
  float* q    = ws + o_q;
  float* u    = ws + o_u;
  float* aw   = ws + o_aw;
  float* ctx  = ws + o_ctx;
  float* cc   = ws + o_cc;
  float* won  = ws + o_won;
  float* oo   = ws + o_oo;
  float* xT   = ws + o_xT;
  float* hT   = ws + o_hT;
  float* giT  = ws + o_giT;
  float* ghT  = ws + o_ghT;
  float* part = ws + o_part;
  float* adj  = ws + o_adj;
  float* h1   = ws + o_h1;
  float* bufA = ws + o_bufA;
  float* w2w  = ws + o_w2w;

  float* out_logits = out;                    // (64,128)
  float* out_hnew   = out + 8192;             // (1,64,512)
  float* out_aw     = out + 8192 + 32768;     // (64,1,512)
  float* out_cc     = out + 8192 + 65536;     // (64,512)

  // ---- GRU step ----
  k_prep<<<128, 256, 0, stream>>>(input_step, emb, last_hidden, xT, hT);
  gemm_tile<2><<<dim3(1, 24, 1), 256, 0, stream>>>(W_ih, 512, 0, xT, 64, 0, giT, 64, 0, 512,
                                                   nullptr, nullptr, nullptr, 0);
  gemm_tile<2><<<dim3(1, 24, 1), 256, 0, stream>>>(W_hh, 512, 0, hT, 64, 0, ghT, 64, 0, 512,
                                                   nullptr, nullptr, nullptr, 0);
  k_gru<<<128, 256, 0, stream>>>(giT, ghT, last_hidden, b_ih, b_hh, hnew, out_hnew);

  // ---- attention + concat head ----
  k_qu<<<64, 512, 0, stream>>>(hnew, attn_W, gc1_W, q, u);
  k_attn<<<64, 512, 0, stream>>>(q, enc, out_aw, aw, ctx);
  k_concat<<<64, 512, 0, stream>>>(hnew, ctx, concat_W, concat_b, out_cc, cc);
  k_wo<<<dim3(64, 4), 512, 0, stream>>>(word_op, seq_mask, won);

  // ---- GCN chain, chunked over batches ----
  for (int c = 0; c < NCHUNK; ++c) {
    const int c0 = c * CB;
    k_adj<<<CB * 512 * 512 / 4 / 256, 256, 0, stream>>>(word_word, word_exist, adj, c0);
    // XW1[b,s,:] = enc[s,b,:] @ gc1_W[512:] + aw[b,s]*u[b,:]
    gemm_tile<0><<<dim3(8, 8, CB), 256, 0, stream>>>(enc + (size_t)c0 * 512, 32768, 512,
        gc1_W + 512 * 512, 512, 0, bufA, 512, 262144, 512, nullptr, aw, u, c0);
    // h1 = relu(adj @ XW1 + gc1_b)
    gemm_tile<1><<<dim3(8, 8, CB), 256, 0, stream>>>(adj, 512, 262144, bufA, 512, 262144,
        h1, 512, 262144, 512, gc1_b, nullptr, nullptr, 0);
    // t = adj @ h1   (overwrites XW1)
    gemm_tile<2><<<dim3(8, 8, CB), 256, 0, stream>>>(adj, 512, 262144, h1, 512, 262144,
        bufA, 512, 262144, 512, nullptr, nullptr, nullptr, 0);
    // w2w_pre = t @ gc2_W + gc2_b   (overlays adj+h1, both dead)
    gemm_tile<3><<<dim3(16, 8, CB), 256, 0, stream>>>(bufA, 512, 262144, gc2_W, 1024, 0,
        w2w, 1024, 524288, 512, gc2_b, nullptr, nullptr, 0);
    // fused LN + residual + wo_n contraction
    k_reduce<<<dim3(CB, 8), 256, 0, stream>>>(w2w, aw, hnew, enc, won, norm_g, norm_b, part, c0);
  }

  // ---- op/nop heads + log_softmax ----
  k_op<<<dim3(64, 4), 512, 0, stream>>>(part, wo_W, wo_b, norm1_g, norm1_b, ops, ot_W, ot_b,
                                        norm2_g, norm2_b, cc, ops_bias, oo);
  k_final<<<64, 128, 0, stream>>>(oo, cc, nop_W, nop_b, out_logits);

  (void)in_sizes; (void)n_in; (void)out_size; (void)ws_size;
}

// Round 2
// 808.693 us; speedup vs baseline: 2.6128x; 2.6128x over previous
//
#include <hip/hip_runtime.h>
#include <math.h>

namespace {

typedef unsigned short ushort_t;
typedef __attribute__((ext_vector_type(8))) short short8;
typedef __attribute__((ext_vector_type(4))) float float4v;

__device__ __forceinline__ unsigned short f2bf(float x) {
  unsigned u = __float_as_uint(x);
  u += 0x7fffu + ((u >> 16) & 1u);        // RNE
  return (unsigned short)(u >> 16);
}
__device__ __forceinline__ float bf2f(unsigned short u) {
  return __uint_as_float((unsigned)u << 16);
}

__device__ __forceinline__ float wave_sum(float v) {
#pragma unroll
  for (int off = 32; off; off >>= 1) v += __shfl_down(v, off, 64);
  return v;
}
__device__ __forceinline__ float wave_max(float v) {
#pragma unroll
  for (int off = 32; off; off >>= 1) v = fmaxf(v, __shfl_down(v, off, 64));
  return v;
}
__device__ __forceinline__ float2 blocksum2(float a, float b, float2* red, int t, int nw) {
#pragma unroll
  for (int off = 32; off; off >>= 1) {
    a += __shfl_down(a, off, 64);
    b += __shfl_down(b, off, 64);
  }
  __syncthreads();
  if ((t & 63) == 0) red[t >> 6] = make_float2(a, b);
  __syncthreads();
  float sa = 0.f, sb = 0.f;
  for (int i = 0; i < nw; ++i) { sa += red[i].x; sb += red[i].y; }
  return make_float2(sa, sb);
}

// =================== bf16 MFMA NT-GEMM, 128x128 tile ===================
// C[M,N] = A[M,K] * Bt[N,K]^T.  All dims multiples of 128 (M>=256 ok), K mult of 32.
// MODE 0: bf16 out, v += u[(c0+z)*512+row]*aw[(c0+z)*512+col]
// MODE 1: bf16 out, relu(v + bias[row])
// MODE 2: bf16 out, plain
// MODE 3: bf16 out, v + bias[col]
// MODE 4: f32 out, plain
template<int MODE>
__global__ __launch_bounds__(256)
void mgemm(const ushort_t* __restrict__ A, int lda, long sA,
           const ushort_t* __restrict__ Bt, int ldb, long sB,
           void* __restrict__ C, int ldc, long sC, int K,
           const float* __restrict__ bias,
           const float* __restrict__ aw, const float* __restrict__ u, int c0)
{
  __shared__ __attribute__((aligned(16))) ushort_t As[128 * 32];
  __shared__ __attribute__((aligned(16))) ushort_t Bs[128 * 32];
  const int z = blockIdx.z;
  const ushort_t* Ab = A  + (long)z * sA;
  const ushort_t* Bb = Bt + (long)z * sB;
  const int tm = blockIdx.y * 128, tn = blockIdx.x * 128;
  const int t = threadIdx.x, wv = t >> 6, ln = t & 63;
  const int lrow = ln >> 2, lseg = ln & 3;        // staging: 16 rows x 4 segs of 16B
  const int frow = ln & 15, fko = (ln >> 4) * 8;  // fragment: m=ln&15, k-quad
  const int wm = (wv >> 1) * 64, wn = (wv & 1) * 64;

  float4v acc[4][4];
#pragma unroll
  for (int i = 0; i < 4; ++i)
#pragma unroll
    for (int j = 0; j < 4; ++j) acc[i][j] = (float4v)0.f;

  for (int k0 = 0; k0 < K; k0 += 32) {
#pragma unroll
    for (int half = 0; half < 2; ++half) {
      const int rbase = wv * 32 + half * 16;
      const ushort_t* ga = Ab + (long)(tm + rbase + lrow) * lda + k0 + lseg * 8;
      const ushort_t* gb = Bb + (long)(tn + rbase + lrow) * ldb + k0 + lseg * 8;
      __builtin_amdgcn_global_load_lds(
          (const __attribute__((address_space(1))) void*)ga,
          (__attribute__((address_space(3))) void*)&As[rbase * 32], 16, 0, 0);
      __builtin_amdgcn_global_load_lds(
          (const __attribute__((address_space(1))) void*)gb,
          (__attribute__((address_space(3))) void*)&Bs[rbase * 32], 16, 0, 0);
    }
    __syncthreads();
    short8 af[4], bfr[4];
#pragma unroll
    for (int i = 0; i < 4; ++i) af[i]  = *(const short8*)&As[(wm + i * 16 + frow) * 32 + fko];
#pragma unroll
    for (int j = 0; j < 4; ++j) bfr[j] = *(const short8*)&Bs[(wn + j * 16 + frow) * 32 + fko];
#pragma unroll
    for (int i = 0; i < 4; ++i)
#pragma unroll
      for (int j = 0; j < 4; ++j)
        acc[i][j] = __builtin_amdgcn_mfma_f32_16x16x32_bf16(af[i], bfr[j], acc[i][j], 0, 0, 0);
    __syncthreads();
  }

  // epilogue: C/D layout col=lane&15, row=(lane>>4)*4+reg
#pragma unroll
  for (int i = 0; i < 4; ++i) {
#pragma unroll
    for (int j = 0; j < 4; ++j) {
      const int col = tn + wn + j * 16 + (ln & 15);
#pragma unroll
      for (int reg = 0; reg < 4; ++reg) {
        const int row = tm + wm + i * 16 + (ln >> 4) * 4 + reg;
        float v = acc[i][j][reg];
        if (MODE == 0) v += u[(c0 + z) * 512 + row] * aw[(c0 + z) * 512 + col];
        else if (MODE == 1) v = fmaxf(v + bias[row], 0.f);
        else if (MODE == 3) v += bias[col];
        if (MODE == 4) ((float*)C)[(long)z * sC + (long)row * ldc + col] = v;
        else ((ushort_t*)C)[(long)z * sC + (long)row * ldc + col] = f2bf(v);
      }
    }
  }
}

// =================== fp32 GRU GEMM (dual A/B via z) ===================
__global__ __launch_bounds__(256)
void gemm_gru(const float* __restrict__ A0, const float* __restrict__ B0,
              const float* __restrict__ A1, const float* __restrict__ B1,
              float* __restrict__ C)
{
  __shared__ float As[64][20];
  __shared__ float Bs[16][68];
  const int z = blockIdx.z;
  const float* Ab = z ? A1 : A0;
  const float* Bp = z ? B1 : B0;
  float* Cb = C + z * 98304;
  const int tm = blockIdx.y * 64;
  const int t = threadIdx.x;
  const int ty4 = (t >> 4) * 4, tx4 = (t & 15) * 4;
  const int aRow = t >> 2, aK = (t & 3) << 2;
  const int bK = t >> 4, bN = (t & 15) << 2;
  float acc[4][4] = {};
  for (int k0 = 0; k0 < 512; k0 += 16) {
    const float4 av = *(const float4*)&Ab[(long)(tm + aRow) * 512 + k0 + aK];
    const float4 bv = *(const float4*)&Bp[(long)(k0 + bK) * 64 + bN];
    __syncthreads();
    *(float4*)&As[aRow][aK] = av;
    *(float4*)&Bs[bK][bN]   = bv;
    __syncthreads();
#pragma unroll
    for (int k = 0; k < 16; ++k) {
      float a_[4], b_[4];
#pragma unroll
      for (int i = 0; i < 4; ++i) a_[i] = As[ty4 + i][k];
#pragma unroll
      for (int j = 0; j < 4; ++j) b_[j] = Bs[k][tx4 + j];
#pragma unroll
      for (int i = 0; i < 4; ++i)
#pragma unroll
        for (int j = 0; j < 4; ++j) acc[i][j] += a_[i] * b_[j];
    }
  }
#pragma unroll
  for (int i = 0; i < 4; ++i)
    *(float4*)&Cb[(long)(tm + ty4 + i) * 64 + tx4] =
        make_float4(acc[i][0], acc[i][1], acc[i][2], acc[i][3]);
}

// =================== small fused kernels ===================

__global__ __launch_bounds__(256)
void k_prep(const int* __restrict__ step, const float* __restrict__ emb,
            const float* __restrict__ last_hidden, float* __restrict__ xT, float* __restrict__ hT)
{
  const int idx = blockIdx.x * 256 + threadIdx.x;
  const int k = idx >> 6, b = idx & 63;
  xT[idx] = emb[(size_t)step[b] * 512 + k];
  hT[idx] = last_hidden[b * 512 + k];
}

// weight bf16 conversions: gc1LT[d][k]=gc1_W[512+k][d]; gc2WT[e][d]=gc2_W[d][e]; woW/otW direct
__global__ __launch_bounds__(256)
void k_prep_w(const float* __restrict__ gc1_W, const float* __restrict__ gc2_W,
              const float* __restrict__ wo_W, const float* __restrict__ ot_W,
              ushort_t* __restrict__ gc1LT, ushort_t* __restrict__ gc2WT,
              ushort_t* __restrict__ woWb, ushort_t* __restrict__ otWb)
{
  int idx = blockIdx.x * 256 + threadIdx.x;
  if (idx < 262144) {
    const int d = idx >> 9, k = idx & 511;
    gc1LT[idx] = f2bf(gc1_W[(size_t)(512 + k) * 512 + d]);
    return;
  }
  idx -= 262144;
  if (idx < 524288) {
    const int e = idx >> 9, d = idx & 511;
    gc2WT[idx] = f2bf(gc2_W[(size_t)d * 1024 + e]);
    return;
  }
  idx -= 524288;
  if (idx < 524288) { woWb[idx] = f2bf(wo_W[idx]); return; }
  idx -= 524288;
  otWb[idx] = f2bf(ot_W[idx]);
}

__global__ __launch_bounds__(256)
void k_gru(const float* __restrict__ giT, const float* __restrict__ ghT,
           const float* __restrict__ last_hidden, const float* __restrict__ b_ih,
           const float* __restrict__ b_hh, float* __restrict__ hnew, float* __restrict__ hnew_out)
{
  const int idx = blockIdx.x * 256 + threadIdx.x;
  const int b = idx >> 9, tt = idx & 511;
  const float ir  = giT[tt * 64 + b]          + b_ih[tt];
  const float iz  = giT[(512 + tt) * 64 + b]  + b_ih[512 + tt];
  const float inn = giT[(1024 + tt) * 64 + b] + b_ih[1024 + tt];
  const float hr  = ghT[tt * 64 + b]          + b_hh[tt];
  const float hz  = ghT[(512 + tt) * 64 + b]  + b_hh[512 + tt];
  const float hn  = ghT[(1024 + tt) * 64 + b] + b_hh[1024 + tt];
  const float h   = last_hidden[idx];
  const float r = 1.f / (1.f + __expf(-(ir + hr)));
  const float z = 1.f / (1.f + __expf(-(iz + hz)));
  const float n = tanhf(inn + r * hn);
  const float o = (1.f - z) * n + z * h;
  hnew[idx] = o;
  hnew_out[idx] = o;
}

__global__ __launch_bounds__(512)
void k_qu(const float* __restrict__ hnew, const float* __restrict__ attn_W,
          const float* __restrict__ gc1_W, float* __restrict__ q, float* __restrict__ u)
{
  const int b = blockIdx.x, j = threadIdx.x;
  __shared__ float hs[512];
  hs[j] = hnew[b * 512 + j];
  __syncthreads();
  float qa = 0.f, ua = 0.f;
  for (int h = 0; h < 512; ++h) {
    const float hv = hs[h];
    qa += hv * attn_W[(size_t)h * 512 + j];
    ua += hv * gc1_W[(size_t)h * 512 + j];
  }
  q[b * 512 + j] = qa;
  u[b * 512 + j] = ua;
}

__global__ __launch_bounds__(512)
void k_attn(const float* __restrict__ q, const float* __restrict__ enc,
            float* __restrict__ aw_dout, float* __restrict__ aw_ws, float* __restrict__ ctx)
{
  const int b = blockIdx.x, t = threadIdx.x;
  const int w = t >> 6, lane = t & 63;
  __shared__ float qs[512];
  __shared__ float sc[512];
  __shared__ float red[8];
  qs[t] = q[b * 512 + t];
  __syncthreads();
  for (int s = w; s < 512; s += 8) {
    const float* e = enc + ((size_t)s * 64 + b) * 512;
    float a = 0.f;
#pragma unroll
    for (int j = 0; j < 8; ++j) a += qs[lane + 64 * j] * e[lane + 64 * j];
    a = wave_sum(a);
    if (lane == 0) sc[s] = a;
  }
  __syncthreads();
  const float v = sc[t];
  float m = wave_max(v);
  if (lane == 0) red[w] = m;
  __syncthreads();
  float mm = red[0];
#pragma unroll
  for (int i = 1; i < 8; ++i) mm = fmaxf(mm, red[i]);
  const float e = __expf(v - mm);
  float s = wave_sum(e);
  __syncthreads();
  if (lane == 0) red[w] = s;
  __syncthreads();
  float tot = 0.f;
#pragma unroll
  for (int i = 0; i < 8; ++i) tot += red[i];
  const float awv = e / tot;
  aw_dout[b * 512 + t] = awv;
  aw_ws[b * 512 + t]   = awv;
  sc[t] = awv;
  __syncthreads();
  float a = 0.f;
  for (int s2 = 0; s2 < 512; ++s2)
    a += sc[s2] * enc[((size_t)s2 * 64 + b) * 512 + t];
  ctx[b * 512 + t] = a;
}

__global__ __launch_bounds__(512)
void k_concat(const float* __restrict__ hnew, const float* __restrict__ ctx,
              const float* __restrict__ W, const float* __restrict__ bias,
              float* __restrict__ out_cc, float* __restrict__ cc_ws)
{
  const int b = blockIdx.x, o = threadIdx.x;
  __shared__ __align__(16) float cat[1024];
  cat[o] = hnew[b * 512 + o];
  cat[512 + o] = ctx[b * 512 + o];
  __syncthreads();
  const float* wr = W + (size_t)o * 1024;
  float acc = bias[o];
  for (int k = 0; k < 1024; k += 4) {
    const float4 wv = *(const float4*)&wr[k];
    const float4 cv = *(const float4*)&cat[k];
    acc += wv.x * cv.x + wv.y * cv.y + wv.z * cv.z + wv.w * cv.w;
  }
  acc = fmaxf(acc, 0.f);
  out_cc[b * 512 + o] = acc;
  cc_ws[b * 512 + o]  = acc;
}

__global__ __launch_bounds__(512)
void k_wo(const float* __restrict__ word_op, const int* __restrict__ seq_mask, float* __restrict__ won)
{
  const int b = blockIdx.x, o = blockIdx.y, s = threadIdx.x;
  float v = word_op[((size_t)(b * 512 + s)) * 4 + o];
  if (seq_mask[b * 512 + s] != 0) v = 0.f;
  __shared__ float red[8];
  float sm = wave_sum(v);
  if ((s & 63) == 0) red[s >> 6] = sm;
  __syncthreads();
  float tot = 0.f;
#pragma unroll
  for (int i = 0; i < 8; ++i) tot += red[i];
  won[((size_t)b * 4 + o) * 512 + s] = v / (tot + 1e-30f);
}

// adj (bf16) for chunk
__global__ __launch_bounds__(256)
void k_adjc(const float* __restrict__ ww, const int* __restrict__ ex,
            ushort_t* __restrict__ adj, int c0)
{
  const size_t i = (size_t)blockIdx.x * 256 + threadIdx.x;
  const size_t base4 = (size_t)c0 * 512 * 512 / 4;
  const float4 w4 = ((const float4*)ww)[base4 + i];
  const int4   e4 = ((const int4*)ex)[base4 + i];
  ushort4 r;
  r.x = (e4.x == 1) ? f2bf(w4.x) : 0;
  r.y = (e4.y == 1) ? f2bf(w4.y) : 0;
  r.z = (e4.z == 1) ? f2bf(w4.z) : 0;
  r.w = (e4.w == 1) ? f2bf(w4.w) : 0;
  ((ushort4*)adj)[i] = r;
}

// enc (bf16, batch-packed) for chunk: encb[z][s][k] = enc[s][c0+z][k]
__global__ __launch_bounds__(256)
void k_encc(const float* __restrict__ enc, ushort_t* __restrict__ encb, int c0)
{
  const size_t i = (size_t)blockIdx.x * 256 + threadIdx.x;   // group of 4 elems
  const size_t el = i * 4;
  const int k = el & 511;
  const int s = (el >> 9) & 511;
  const int z = el >> 18;
  const float4 v = *(const float4*)&enc[((size_t)s * 64 + c0 + z) * 512 + k];
  ushort4 r;
  r.x = f2bf(v.x); r.y = f2bf(v.y); r.z = f2bf(v.z); r.w = f2bf(v.w);
  ((ushort4*)encb)[i] = r;
}

// Fused: LN(w2w bf16) + w_all residual, contracted with wo_n -> partials
__global__ __launch_bounds__(256)
void k_reduce(const ushort_t* __restrict__ w2w, const float* __restrict__ aw,
              const float* __restrict__ hnew, const float* __restrict__ enc,
              const float* __restrict__ won, const float* __restrict__ ng,
              const float* __restrict__ nb, float* __restrict__ part, int c0)
{
  const int z = blockIdx.x, b = c0 + z, yb = blockIdx.y, t = threadIdx.x;
  __shared__ float2 red[4];
  const int d0 = 4 * t;
  const float4 ngv = *(const float4*)&ng[d0];
  const float4 nbv = *(const float4*)&nb[d0];
  float acc[4][4] = {};
  for (int s = yb * 64; s < yb * 64 + 64; ++s) {
    const ushort4 xu = *(const ushort4*)&w2w[((size_t)z * 512 + s) * 1024 + d0];
    float x[4] = {bf2f(xu.x), bf2f(xu.y), bf2f(xu.z), bf2f(xu.w)};
    float ls = x[0] + x[1] + x[2] + x[3];
    float lss = x[0]*x[0] + x[1]*x[1] + x[2]*x[2] + x[3]*x[3];
    const float2 ss = blocksum2(ls, lss, red, t, 4);
    const float mean = ss.x * (1.f / 1024.f);
    const float var  = ss.y * (1.f / 1024.f) - mean * mean;
    const float inv  = rsqrtf(var + 1e-6f);
    const float awv = aw[b * 512 + s];
    float4 res;
    if (t < 128) {
      res = *(const float4*)&hnew[b * 512 + d0];
      res.x *= awv; res.y *= awv; res.z *= awv; res.w *= awv;
    } else {
      res = *(const float4*)&enc[((size_t)s * 64 + b) * 512 + d0 - 512];
    }
    const float w0 = won[((size_t)b * 4 + 0) * 512 + s];
    const float w1 = won[((size_t)b * 4 + 1) * 512 + s];
    const float w2 = won[((size_t)b * 4 + 2) * 512 + s];
    const float w3 = won[((size_t)b * 4 + 3) * 512 + s];
    const float rr[4] = {res.x, res.y, res.z, res.w};
    const float gg[4] = {ngv.x, ngv.y, ngv.z, ngv.w};
    const float bb[4] = {nbv.x, nbv.y, nbv.z, nbv.w};
#pragma unroll
    for (int k = 0; k < 4; ++k) {
      const float val = (x[k] - mean) * inv * gg[k] + bb[k] + rr[k];
      acc[0][k] += w0 * val; acc[1][k] += w1 * val;
      acc[2][k] += w2 * val; acc[3][k] += w3 * val;
    }
  }
#pragma unroll
  for (int o = 0; o < 4; ++o)
#pragma unroll
    for (int k = 0; k < 4; ++k)
      part[(((size_t)(b * 8 + yb) * 4 + o) << 10) + d0 + k] = acc[o][k];
}

// sum 8 partials -> ctx_op bf16 (256 x 1024)
__global__ __launch_bounds__(256)
void k_psum(const float* __restrict__ part, ushort_t* __restrict__ ctxop)
{
  const int idx = blockIdx.x * 256 + threadIdx.x;   // 262144
  const int r = idx >> 10, d = idx & 1023;
  const int b = r >> 2, o = r & 3;
  float s = 0.f;
#pragma unroll
  for (int p = 0; p < 8; ++p)
    s += part[(((size_t)(b * 8 + p) * 4 + o) << 10) + d];
  ctxop[idx] = f2bf(s);
}

// relu+bias, LN1, build op_all bf16 = [s1, ops[o]]
__global__ __launch_bounds__(512)
void k_ln1(const float* __restrict__ oppre, const float* __restrict__ wo_b,
           const float* __restrict__ n1g, const float* __restrict__ n1b,
           const float* __restrict__ ops, ushort_t* __restrict__ opall)
{
  const int r = blockIdx.x, t = threadIdx.x;
  const int o = r & 3;
  __shared__ float2 red[8];
  const float val = fmaxf(oppre[(size_t)r * 512 + t] + wo_b[t], 0.f);
  const float2 ss = blocksum2(val, val * val, red, t, 8);
  const float m = ss.x * (1.f / 512.f);
  const float v = ss.y * (1.f / 512.f) - m * m;
  const float s1 = (val - m) * rsqrtf(v + 1e-6f) * n1g[t] + n1b[t];
  opall[(size_t)r * 1024 + t] = f2bf(s1);
  opall[(size_t)r * 1024 + 512 + t] = f2bf(ops[o * 512 + t]);
}

// relu+bias, LN2 + ops, dot with concat_output -> oo
__global__ __launch_bounds__(512)
void k_ln2dot(const float* __restrict__ ohpre, const float* __restrict__ ot_b,
              const float* __restrict__ n2g, const float* __restrict__ n2b,
              const float* __restrict__ ops, const float* __restrict__ cc,
              const float* __restrict__ ops_bias, float* __restrict__ oo)
{
  const int r = blockIdx.x, t = threadIdx.x;
  const int b = r >> 2, o = r & 3;
  __shared__ float2 red[8];
  const float oh = fmaxf(ohpre[(size_t)r * 512 + t] + ot_b[t], 0.f);
  const float2 ss = blocksum2(oh, oh * oh, red, t, 8);
  const float m = ss.x * (1.f / 512.f);
  const float v = ss.y * (1.f / 512.f) - m * m;
  const float opo = (oh - m) * rsqrtf(v + 1e-6f) * n2g[t] + n2b[t] + ops[o * 512 + t];
  const float p = cc[b * 512 + t] * opo;
  const float2 s3 = blocksum2(p, 0.f, red, t, 8);
  if (t == 0) oo[r] = s3.x + ops_bias[o];
}

__global__ __launch_bounds__(128)
void k_final(const float* __restrict__ oo, const float* __restrict__ cc,
             const float* __restrict__ nop_W, const float* __restrict__ nop_b,
             float* __restrict__ outp)
{
  const int b = blockIdx.x, t = threadIdx.x;
  __shared__ __align__(16) float ccs[512];
  __shared__ float red[2];
  __shared__ float red2[2];
  for (int i = t; i < 512; i += 128) ccs[i] = cc[b * 512 + i];
  __syncthreads();
  float v;
  if (t < 4) {
    v = oo[b * 4 + t];
  } else {
    const int j = t - 4;
    const float* wr = nop_W + (size_t)j * 512;
    float a = nop_b[j];
    for (int k = 0; k < 512; k += 4) {
      const float4 w4 = *(const float4*)&wr[k];
      const float4 c4 = *(const float4*)&ccs[k];
      a += w4.x * c4.x + w4.y * c4.y + w4.z * c4.z + w4.w * c4.w;
    }
    v = a;
  }
  float m = wave_max(v);
  if ((t & 63) == 0) red[t >> 6] = m;
  __syncthreads();
  m = fmaxf(red[0], red[1]);
  const float e = __expf(v - m);
  float s = wave_sum(e);
  if ((t & 63) == 0) red2[t >> 6] = s;
  __syncthreads();
  s = red2[0] + red2[1];
  outp[b * 128 + t] = v - m - logf(s);
}

} // namespace

extern "C" void kernel_launch(void* const* d_in, const int* in_sizes, int n_in,
                              void* d_out, int out_size, void* d_ws, size_t ws_size,
                              hipStream_t stream)
{
  const int*   input_step  = (const int*)  d_in[0];
  const float* last_hidden = (const float*)d_in[1];
  const float* enc         = (const float*)d_in[2];
  const float* word_word   = (const float*)d_in[3];
  const float* word_op     = (const float*)d_in[4];
  const int*   word_exist  = (const int*)  d_in[5];
  const int*   seq_mask    = (const int*)  d_in[6];
  const float* emb         = (const float*)d_in[7];
  const float* W_ih        = (const float*)d_in[8];
  const float* W_hh        = (const float*)d_in[9];
  const float* b_ih        = (const float*)d_in[10];
  const float* b_hh        = (const float*)d_in[11];
  const float* attn_W      = (const float*)d_in[12];
  const float* concat_W    = (const float*)d_in[14];
  const float* concat_b    = (const float*)d_in[15];
  const float* ops         = (const float*)d_in[16];
  const float* ops_bias    = (const float*)d_in[17];
  const float* nop_W       = (const float*)d_in[18];
  const float* nop_b       = (const float*)d_in[19];
  const float* gc1_W       = (const float*)d_in[20];
  const float* gc1_b       = (const float*)d_in[21];
  const float* gc2_W       = (const float*)d_in[22];
  const float* gc2_b       = (const float*)d_in[23];
  const float* norm_g      = (const float*)d_in[24];
  const float* norm_b      = (const float*)d_in[25];
  const float* norm1_g     = (const float*)d_in[26];
  const float* norm1_b     = (const float*)d_in[27];
  const float* norm2_g     = (const float*)d_in[28];
  const float* norm2_b     = (const float*)d_in[29];
  const float* wo_W        = (const float*)d_in[30];
  const float* wo_b        = (const float*)d_in[31];
  const float* ot_W        = (const float*)d_in[32];
  const float* ot_b        = (const float*)d_in[33];

  float* ws  = (float*)d_ws;
  float* out = (float*)d_out;

  // ---- workspace layout (floats) ----
  size_t off = 0;
  auto take = [&](size_t n) { size_t o = off; off += n; return o; };
  const size_t o_hnew = take(32768);
  const size_t o_q    = take(32768);
  const size_t o_u    = take(32768);
  const size_t o_aw   = take(32768);
  const size_t o_ctx  = take(32768);
  const size_t o_cc   = take(32768);
  const size_t o_won  = take(131072);
  const size_t o_oo   = take(256);
  const size_t o_xT   = take(32768);
  const size_t o_hT   = take(32768);
  const size_t o_giT  = take(98304);
  const size_t o_ghT  = take(98304); (void)o_ghT;
  const size_t o_part = take(2097152);
  const size_t o_oppre = take(131072);
  const size_t o_ohpre = take(131072);
  const size_t o_gc1LT = take(131072);
  const size_t o_gc2WT = take(262144);
  const size_t o_woW   = take(262144);
  const size_t o_otW   = take(262144);
  const size_t o_ctxop = take(131072);
  const size_t o_opall = take(131072);
  const size_t base = off;

  // pick chunk size by available workspace (constant across calls -> graph-safe)
  int CB = 16;
  if (ws_size >= (base + 64ull * 655360) * 4) CB = 64;
  else if (ws_size >= (base + 32ull * 655360) * 4) CB = 32;
  const int nch = 64 / CB;

  const size_t o_adjbf = take((size_t)CB * 131072);
  const size_t o_h1t   = take((size_t)CB * 131072);
  const size_t o_tmat  = take((size_t)CB * 131072);
  const size_t o_encbf = take((size_t)CB * 131072);
  const size_t o_xw1t  = take((size_t)CB * 131072);
  const size_t o_w2w   = o_encbf;          // overlays encbf+xw1t (dead at E4)

  float* hnew = ws + o_hnew;
  float* q    = ws + o_q;
  float* u    = ws + o_u;
  float* aw   = ws + o_aw;
  float* ctx  = ws + o_ctx;
  float* cc   = ws + o_cc;
  float* won  = ws + o_won;
  float* oo   = ws + o_oo;
  float* xT   = ws + o_xT;
  float* hT   = ws + o_hT;
  float* giT  = ws + o_giT;
  float* part = ws + o_part;
  float* oppre = ws + o_oppre;
  float* ohpre = ws + o_ohpre;
  ushort_t* gc1LT = (ushort_t*)(ws + o_gc1LT);
  ushort_t* gc2WT = (ushort_t*)(ws + o_gc2WT);
  ushort_t* woWb  = (ushort_t*)(ws + o_woW);
  ushort_t* otWb  = (ushort_t*)(ws + o_otW);
  ushort_t* ctxop = (ushort_t*)(ws + o_ctxop);
  ushort_t* opall = (ushort_t*)(ws + o_opall);
  ushort_t* adjbf = (ushort_t*)(ws + o_adjbf);
  ushort_t* h1t   = (ushort_t*)(ws + o_h1t);
  ushort_t* tmat  = (ushort_t*)(ws + o_tmat);
  ushort_t* encbf = (ushort_t*)(ws + o_encbf);
  ushort_t* xw1t  = (ushort_t*)(ws + o_xw1t);
  ushort_t* w2wbf = (ushort_t*)(ws + o_w2w);

  float* out_logits = out;
  float* out_hnew   = out + 8192;
  float* out_aw     = out + 8192 + 32768;
  float* out_cc     = out + 8192 + 65536;

  // ---- weight conversions + GRU ----
  k_prep_w<<<7168, 256, 0, stream>>>(gc1_W, gc2_W, wo_W, ot_W, gc1LT, gc2WT, woWb, otWb);
  k_prep<<<128, 256, 0, stream>>>(input_step, emb, last_hidden, xT, hT);
  gemm_gru<<<dim3(1, 24, 2), 256, 0, stream>>>(W_ih, xT, W_hh, hT, giT);
  k_gru<<<128, 256, 0, stream>>>(giT, ws + o_ghT, last_hidden, b_ih, b_hh, hnew, out_hnew);

  // ---- attention + concat + wo_n ----
  k_qu<<<64, 512, 0, stream>>>(hnew, attn_W, gc1_W, q, u);
  k_attn<<<64, 512, 0, stream>>>(q, enc, out_aw, aw, ctx);
  k_concat<<<64, 512, 0, stream>>>(hnew, ctx, concat_W, concat_b, out_cc, cc);
  k_wo<<<dim3(64, 4), 512, 0, stream>>>(word_op, seq_mask, won);

  // ---- GCN chain (bf16 MFMA), chunked ----
  for (int c = 0; c < nch; ++c) {
    const int c0 = c * CB;
    k_adjc<<<CB * 256, 256, 0, stream>>>(word_word, word_exist, adjbf, c0);
    k_encc<<<CB * 256, 256, 0, stream>>>(enc, encbf, c0);
    // XW1T[d][s] = gc1LT[d][:] . enc_b[s][:] + u[b][d]*aw[b][s]
    mgemm<0><<<dim3(4, 4, CB), 256, 0, stream>>>(gc1LT, 512, 0, encbf, 512, 262144,
        xw1t, 512, 262144, 512, nullptr, aw, u, c0);
    // h1T[d][s] = relu(XW1T[d][:] . adj[s][:] + gc1_b[d])
    mgemm<1><<<dim3(4, 4, CB), 256, 0, stream>>>(xw1t, 512, 262144, adjbf, 512, 262144,
        h1t, 512, 262144, 512, gc1_b, nullptr, nullptr, 0);
    // t[s][d] = adj[s][:] . h1T[d][:]
    mgemm<2><<<dim3(4, 4, CB), 256, 0, stream>>>(adjbf, 512, 262144, h1t, 512, 262144,
        tmat, 512, 262144, 512, nullptr, nullptr, nullptr, 0);
    // w2w[s][e] = t[s][:] . gc2WT[e][:] + gc2_b[e]
    mgemm<3><<<dim3(8, 4, CB), 256, 0, stream>>>(tmat, 512, 262144, gc2WT, 512, 0,
        w2wbf, 1024, 524288, 512, gc2_b, nullptr, nullptr, 0);
    k_reduce<<<dim3(CB, 8), 256, 0, stream>>>(w2wbf, aw, hnew, enc, won, norm_g, norm_b, part, c0);
  }

  // ---- op head (MFMA GEMMs) + nop head + log_softmax ----
  k_psum<<<1024, 256, 0, stream>>>(part, ctxop);
  mgemm<4><<<dim3(4, 2, 1), 256, 0, stream>>>(ctxop, 1024, 0, woWb, 1024, 0,
      oppre, 512, 0, 1024, nullptr, nullptr, nullptr, 0);
  k_ln1<<<256, 512, 0, stream>>>(oppre, wo_b, norm1_g, norm1_b, ops, opall);
  mgemm<4><<<dim3(4, 2, 1), 256, 0, stream>>>(opall, 1024, 0, otWb, 1024, 0,
      ohpre, 512, 0, 1024, nullptr, nullptr, nullptr, 0);
  k_ln2dot<<<256, 512, 0, stream>>>(ohpre, ot_b, norm2_g, norm2_b, ops, cc, ops_bias, oo);
  k_final<<<64, 128, 0, stream>>>(oo, cc, nop_W, nop_b, out_logits);

  (void)in_sizes; (void)n_in; (void)out_size;
}

// Round 3
// 760.073 us; speedup vs baseline: 2.7800x; 1.0640x over previous
//
#include <hip/hip_runtime.h>
#include <math.h>

namespace {

typedef unsigned short ushort_t;
typedef __attribute__((ext_vector_type(8))) short short8;
typedef __attribute__((ext_vector_type(4))) float float4v;

__device__ __forceinline__ unsigned short f2bf(float x) {
  unsigned u = __float_as_uint(x);
  u += 0x7fffu + ((u >> 16) & 1u);        // RNE
  return (unsigned short)(u >> 16);
}
__device__ __forceinline__ float bf2f(unsigned short u) {
  return __uint_as_float((unsigned)u << 16);
}

__device__ __forceinline__ float wave_sum(float v) {
#pragma unroll
  for (int off = 32; off; off >>= 1) v += __shfl_down(v, off, 64);
  return v;
}
__device__ __forceinline__ float wave_max(float v) {
#pragma unroll
  for (int off = 32; off; off >>= 1) v = fmaxf(v, __shfl_down(v, off, 64));
  return v;
}
__device__ __forceinline__ float2 blocksum2(float a, float b, float2* red, int t, int nw) {
#pragma unroll
  for (int off = 32; off; off >>= 1) {
    a += __shfl_down(a, off, 64);
    b += __shfl_down(b, off, 64);
  }
  __syncthreads();
  if ((t & 63) == 0) red[t >> 6] = make_float2(a, b);
  __syncthreads();
  float sa = 0.f, sb = 0.f;
  for (int i = 0; i < nw; ++i) { sa += red[i].x; sb += red[i].y; }
  return make_float2(sa, sb);
}

// =================== bf16 MFMA NT-GEMM, 128x128 tile ===================
// C[M,N] = A[M,K] * Bt[N,K]^T.  All dims multiples of 128 (M>=256 ok), K mult of 32.
// MODE 0: bf16 out, v += u[(c0+z)*512+row]*aw[(c0+z)*512+col]
// MODE 1: bf16 out, relu(v + bias[row])
// MODE 2: bf16 out, plain
// MODE 3: bf16 out, v + bias[col]
// MODE 4: f32 out, plain
template<int MODE>
__global__ __launch_bounds__(256)
void mgemm(const ushort_t* __restrict__ A, int lda, long sA,
           const ushort_t* __restrict__ Bt, int ldb, long sB,
           void* __restrict__ C, int ldc, long sC, int K,
           const float* __restrict__ bias,
           const float* __restrict__ aw, const float* __restrict__ u, int c0)
{
  __shared__ __attribute__((aligned(16))) ushort_t As[128 * 32];
  __shared__ __attribute__((aligned(16))) ushort_t Bs[128 * 32];
  const int z = blockIdx.z;
  const ushort_t* Ab = A  + (long)z * sA;
  const ushort_t* Bb = Bt + (long)z * sB;
  const int tm = blockIdx.y * 128, tn = blockIdx.x * 128;
  const int t = threadIdx.x, wv = t >> 6, ln = t & 63;
  const int lrow = ln >> 2, lseg = ln & 3;        // staging: 16 rows x 4 segs of 16B
  const int frow = ln & 15, fko = (ln >> 4) * 8;  // fragment: m=ln&15, k-quad
  const int wm = (wv >> 1) * 64, wn = (wv & 1) * 64;

  float4v acc[4][4];
#pragma unroll
  for (int i = 0; i < 4; ++i)
#pragma unroll
    for (int j = 0; j < 4; ++j) acc[i][j] = (float4v)0.f;

  for (int k0 = 0; k0 < K; k0 += 32) {
#pragma unroll
    for (int half = 0; half < 2; ++half) {
      const int rbase = wv * 32 + half * 16;
      const ushort_t* ga = Ab + (long)(tm + rbase + lrow) * lda + k0 + lseg * 8;
      const ushort_t* gb = Bb + (long)(tn + rbase + lrow) * ldb + k0 + lseg * 8;
      __builtin_amdgcn_global_load_lds(
          (const __attribute__((address_space(1))) void*)ga,
          (__attribute__((address_space(3))) void*)&As[rbase * 32], 16, 0, 0);
      __builtin_amdgcn_global_load_lds(
          (const __attribute__((address_space(1))) void*)gb,
          (__attribute__((address_space(3))) void*)&Bs[rbase * 32], 16, 0, 0);
    }
    __syncthreads();
    short8 af[4], bfr[4];
#pragma unroll
    for (int i = 0; i < 4; ++i) af[i]  = *(const short8*)&As[(wm + i * 16 + frow) * 32 + fko];
#pragma unroll
    for (int j = 0; j < 4; ++j) bfr[j] = *(const short8*)&Bs[(wn + j * 16 + frow) * 32 + fko];
#pragma unroll
    for (int i = 0; i < 4; ++i)
#pragma unroll
      for (int j = 0; j < 4; ++j)
        acc[i][j] = __builtin_amdgcn_mfma_f32_16x16x32_bf16(af[i], bfr[j], acc[i][j], 0, 0, 0);
    __syncthreads();
  }

  // epilogue: C/D layout col=lane&15, row=(lane>>4)*4+reg
#pragma unroll
  for (int i = 0; i < 4; ++i) {
#pragma unroll
    for (int j = 0; j < 4; ++j) {
      const int col = tn + wn + j * 16 + (ln & 15);
#pragma unroll
      for (int reg = 0; reg < 4; ++reg) {
        const int row = tm + wm + i * 16 + (ln >> 4) * 4 + reg;
        float v = acc[i][j][reg];
        if (MODE == 0) v += u[(c0 + z) * 512 + row] * aw[(c0 + z) * 512 + col];
        else if (MODE == 1) v = fmaxf(v + bias[row], 0.f);
        else if (MODE == 3) v += bias[col];
        if (MODE == 4) ((float*)C)[(long)z * sC + (long)row * ldc + col] = v;
        else ((ushort_t*)C)[(long)z * sC + (long)row * ldc + col] = f2bf(v);
      }
    }
  }
}

// =================== fp32 GRU GEMM (dual A/B via z) ===================
__global__ __launch_bounds__(256)
void gemm_gru(const float* __restrict__ A0, const float* __restrict__ B0,
              const float* __restrict__ A1, const float* __restrict__ B1,
              float* __restrict__ C)
{
  __shared__ float As[64][20];
  __shared__ float Bs[16][68];
  const int z = blockIdx.z;
  const float* Ab = z ? A1 : A0;
  const float* Bp = z ? B1 : B0;
  float* Cb = C + z * 98304;
  const int tm = blockIdx.y * 64;
  const int t = threadIdx.x;
  const int ty4 = (t >> 4) * 4, tx4 = (t & 15) * 4;
  const int aRow = t >> 2, aK = (t & 3) << 2;
  const int bK = t >> 4, bN = (t & 15) << 2;
  float acc[4][4] = {};
  for (int k0 = 0; k0 < 512; k0 += 16) {
    const float4 av = *(const float4*)&Ab[(long)(tm + aRow) * 512 + k0 + aK];
    const float4 bv = *(const float4*)&Bp[(long)(k0 + bK) * 64 + bN];
    __syncthreads();
    *(float4*)&As[aRow][aK] = av;
    *(float4*)&Bs[bK][bN]   = bv;
    __syncthreads();
#pragma unroll
    for (int k = 0; k < 16; ++k) {
      float a_[4], b_[4];
#pragma unroll
      for (int i = 0; i < 4; ++i) a_[i] = As[ty4 + i][k];
#pragma unroll
      for (int j = 0; j < 4; ++j) b_[j] = Bs[k][tx4 + j];
#pragma unroll
      for (int i = 0; i < 4; ++i)
#pragma unroll
        for (int j = 0; j < 4; ++j) acc[i][j] += a_[i] * b_[j];
    }
  }
#pragma unroll
  for (int i = 0; i < 4; ++i)
    *(float4*)&Cb[(long)(tm + ty4 + i) * 64 + tx4] =
        make_float4(acc[i][0], acc[i][1], acc[i][2], acc[i][3]);
}

// =================== small fused kernels ===================

__global__ __launch_bounds__(256)
void k_prep(const int* __restrict__ step, const float* __restrict__ emb,
            const float* __restrict__ last_hidden, float* __restrict__ xT, float* __restrict__ hT)
{
  const int idx = blockIdx.x * 256 + threadIdx.x;
  const int k = idx >> 6, b = idx & 63;
  xT[idx] = emb[(size_t)step[b] * 512 + k];
  hT[idx] = last_hidden[b * 512 + k];
}

// weight conversions:
//  gc1LT[d][k]=bf(gc1_W[512+k][d]); gc2WT[e][d]=bf(gc2_W[d][e]); woWb/otWb direct bf;
//  cWT[k][o]=concat_W[o][k] (fp32); nWT[k][j]=nop_W[j][k] (fp32, j padded to 128)
__global__ __launch_bounds__(256)
void k_prep_w(const float* __restrict__ gc1_W, const float* __restrict__ gc2_W,
              const float* __restrict__ wo_W, const float* __restrict__ ot_W,
              const float* __restrict__ concat_W, const float* __restrict__ nop_W,
              ushort_t* __restrict__ gc1LT, ushort_t* __restrict__ gc2WT,
              ushort_t* __restrict__ woWb, ushort_t* __restrict__ otWb,
              float* __restrict__ cWT, float* __restrict__ nWT)
{
  int idx = blockIdx.x * 256 + threadIdx.x;
  if (idx < 262144) {
    const int d = idx >> 9, k = idx & 511;
    gc1LT[idx] = f2bf(gc1_W[(size_t)(512 + k) * 512 + d]);
    return;
  }
  idx -= 262144;
  if (idx < 524288) {
    const int e = idx >> 9, d = idx & 511;
    gc2WT[idx] = f2bf(gc2_W[(size_t)d * 1024 + e]);
    return;
  }
  idx -= 524288;
  if (idx < 524288) { woWb[idx] = f2bf(wo_W[idx]); return; }
  idx -= 524288;
  if (idx < 524288) { otWb[idx] = f2bf(ot_W[idx]); return; }
  idx -= 524288;
  if (idx < 524288) {
    const int k = idx >> 9, o = idx & 511;
    cWT[idx] = concat_W[(size_t)o * 1024 + k];
    return;
  }
  idx -= 524288;
  if (idx < 65536) {
    const int k = idx >> 7, j = idx & 127;
    nWT[idx] = (j < 124) ? nop_W[(size_t)j * 512 + k] : 0.f;
  }
}

__global__ __launch_bounds__(256)
void k_gru(const float* __restrict__ giT, const float* __restrict__ ghT,
           const float* __restrict__ last_hidden, const float* __restrict__ b_ih,
           const float* __restrict__ b_hh, float* __restrict__ hnew, float* __restrict__ hnew_out)
{
  const int idx = blockIdx.x * 256 + threadIdx.x;
  const int b = idx >> 9, tt = idx & 511;
  const float ir  = giT[tt * 64 + b]          + b_ih[tt];
  const float iz  = giT[(512 + tt) * 64 + b]  + b_ih[512 + tt];
  const float inn = giT[(1024 + tt) * 64 + b] + b_ih[1024 + tt];
  const float hr  = ghT[tt * 64 + b]          + b_hh[tt];
  const float hz  = ghT[(512 + tt) * 64 + b]  + b_hh[512 + tt];
  const float hn  = ghT[(1024 + tt) * 64 + b] + b_hh[1024 + tt];
  const float h   = last_hidden[idx];
  const float r = 1.f / (1.f + __expf(-(ir + hr)));
  const float z = 1.f / (1.f + __expf(-(iz + hz)));
  const float n = tanhf(inn + r * hn);
  const float o = (1.f - z) * n + z * h;
  hnew[idx] = o;
  hnew_out[idx] = o;
}

// q = h_new @ attn_W ; u = h_new @ gc1_W[:512].  grid (64,4) x 128 threads.
__global__ __launch_bounds__(128)
void k_qu(const float* __restrict__ hnew, const float* __restrict__ attn_W,
          const float* __restrict__ gc1_W, float* __restrict__ q, float* __restrict__ u)
{
  const int b = blockIdx.x, j = blockIdx.y * 128 + threadIdx.x;
  __shared__ float hs[512];
  for (int i = threadIdx.x; i < 512; i += 128) hs[i] = hnew[b * 512 + i];
  __syncthreads();
  float qa = 0.f, ua = 0.f;
  for (int h = 0; h < 512; ++h) {
    const float hv = hs[h];
    qa += hv * attn_W[(size_t)h * 512 + j];
    ua += hv * gc1_W[(size_t)h * 512 + j];
  }
  q[b * 512 + j] = qa;
  u[b * 512 + j] = ua;
}

// scores[b,s] = q[b]·enc[s,b]; also emits encbf[b][s][k] (bf16) when emit!=0.
// grid (64,16) x 256 threads: 4 waves x 8 s each.
__global__ __launch_bounds__(256)
void k_score(const float* __restrict__ q, const float* __restrict__ enc,
             float* __restrict__ scores, ushort_t* __restrict__ encb, int emit)
{
  const int b = blockIdx.x, p = blockIdx.y;
  const int t = threadIdx.x, wv = t >> 6, ln = t & 63;
  __shared__ float qs[512];
  for (int i = t; i < 512; i += 256) qs[i] = q[b * 512 + i];
  __syncthreads();
  const int e0 = ln * 8;
  const float4 q0 = *(const float4*)&qs[e0];
  const float4 q1 = *(const float4*)&qs[e0 + 4];
  for (int it = 0; it < 8; ++it) {
    const int s = p * 32 + wv * 8 + it;
    const float* e = enc + ((size_t)s * 64 + b) * 512 + e0;
    const float4 v0 = *(const float4*)e;
    const float4 v1 = *(const float4*)(e + 4);
    float a = q0.x * v0.x + q0.y * v0.y + q0.z * v0.z + q0.w * v0.w
            + q1.x * v1.x + q1.y * v1.y + q1.z * v1.z + q1.w * v1.w;
    if (emit) {
      short8 o;
      o[0] = (short)f2bf(v0.x); o[1] = (short)f2bf(v0.y);
      o[2] = (short)f2bf(v0.z); o[3] = (short)f2bf(v0.w);
      o[4] = (short)f2bf(v1.x); o[5] = (short)f2bf(v1.y);
      o[6] = (short)f2bf(v1.z); o[7] = (short)f2bf(v1.w);
      *(short8*)&encb[(size_t)b * 262144 + (size_t)s * 512 + e0] = o;
    }
    a = wave_sum(a);
    if (ln == 0) scores[b * 512 + s] = a;
  }
}

// softmax over scores -> aw (ws + output)
__global__ __launch_bounds__(512)
void k_softmax(const float* __restrict__ scores, float* __restrict__ aw_dout,
               float* __restrict__ aw_ws)
{
  const int b = blockIdx.x, t = threadIdx.x;
  const int w = t >> 6, lane = t & 63;
  __shared__ float red[8];
  const float v = scores[b * 512 + t];
  float m = wave_max(v);
  if (lane == 0) red[w] = m;
  __syncthreads();
  float mm = red[0];
#pragma unroll
  for (int i = 1; i < 8; ++i) mm = fmaxf(mm, red[i]);
  const float e = __expf(v - mm);
  float s = wave_sum(e);
  __syncthreads();
  if (lane == 0) red[w] = s;
  __syncthreads();
  float tot = 0.f;
#pragma unroll
  for (int i = 0; i < 8; ++i) tot += red[i];
  const float awv = e / tot;
  aw_dout[b * 512 + t] = awv;
  aw_ws[b * 512 + t]   = awv;
}

// context partials: ctxpart[b][p][t] = sum_{s in p-chunk} aw[b,s]*enc[s,b,t]
// grid (64,16) x 512 threads, 32 s per block
__global__ __launch_bounds__(512)
void k_ctx(const float* __restrict__ aw, const float* __restrict__ enc,
           float* __restrict__ ctxpart)
{
  const int b = blockIdx.x, p = blockIdx.y, t = threadIdx.x;
  __shared__ float aws[32];
  if (t < 32) aws[t] = aw[b * 512 + p * 32 + t];
  __syncthreads();
  float acc = 0.f;
#pragma unroll 4
  for (int si = 0; si < 32; ++si)
    acc += aws[si] * enc[((size_t)(p * 32 + si) * 64 + b) * 512 + t];
  ctxpart[((size_t)b * 16 + p) * 512 + t] = acc;
}

// concat_output = relu([h_new, sum_p ctxpart] @ cWT + b).  grid (64,4) x 128.
__global__ __launch_bounds__(128)
void k_concat(const float* __restrict__ hnew, const float* __restrict__ ctxpart,
              const float* __restrict__ cWT, const float* __restrict__ bias,
              float* __restrict__ out_cc, float* __restrict__ cc_ws)
{
  const int b = blockIdx.x, o = blockIdx.y * 128 + threadIdx.x;
  __shared__ __align__(16) float cat[1024];
  for (int m = 0; m < 8; ++m) {
    const int i = threadIdx.x + 128 * m;
    if (i < 512) {
      cat[i] = hnew[b * 512 + i];
    } else {
      const int d = i - 512;
      float s = 0.f;
#pragma unroll
      for (int pp = 0; pp < 16; ++pp) s += ctxpart[((size_t)b * 16 + pp) * 512 + d];
      cat[i] = s;
    }
  }
  __syncthreads();
  float acc = bias[o];
  for (int k = 0; k < 1024; k += 4) {
    acc += cat[k]     * cWT[(size_t)k * 512 + o]
         + cat[k + 1] * cWT[(size_t)(k + 1) * 512 + o]
         + cat[k + 2] * cWT[(size_t)(k + 2) * 512 + o]
         + cat[k + 3] * cWT[(size_t)(k + 3) * 512 + o];
  }
  acc = fmaxf(acc, 0.f);
  out_cc[b * 512 + o] = acc;
  cc_ws[b * 512 + o]  = acc;
}

__global__ __launch_bounds__(512)
void k_wo(const float* __restrict__ word_op, const int* __restrict__ seq_mask, float* __restrict__ won)
{
  const int b = blockIdx.x, o = blockIdx.y, s = threadIdx.x;
  float v = word_op[((size_t)(b * 512 + s)) * 4 + o];
  if (seq_mask[b * 512 + s] != 0) v = 0.f;
  __shared__ float red[8];
  float sm = wave_sum(v);
  if ((s & 63) == 0) red[s >> 6] = sm;
  __syncthreads();
  float tot = 0.f;
#pragma unroll
  for (int i = 0; i < 8; ++i) tot += red[i];
  won[((size_t)b * 4 + o) * 512 + s] = v / (tot + 1e-30f);
}

// adj (bf16) for chunk
__global__ __launch_bounds__(256)
void k_adjc(const float* __restrict__ ww, const int* __restrict__ ex,
            ushort_t* __restrict__ adj, int c0)
{
  const size_t i = (size_t)blockIdx.x * 256 + threadIdx.x;
  const size_t base4 = (size_t)c0 * 512 * 512 / 4;
  const float4 w4 = ((const float4*)ww)[base4 + i];
  const int4   e4 = ((const int4*)ex)[base4 + i];
  ushort4 r;
  r.x = (e4.x == 1) ? f2bf(w4.x) : 0;
  r.y = (e4.y == 1) ? f2bf(w4.y) : 0;
  r.z = (e4.z == 1) ? f2bf(w4.z) : 0;
  r.w = (e4.w == 1) ? f2bf(w4.w) : 0;
  ((ushort4*)adj)[i] = r;
}

// enc (bf16, batch-packed) for chunk (only used when CB<64): encb[z][s][k]=enc[s][c0+z][k]
__global__ __launch_bounds__(256)
void k_encc(const float* __restrict__ enc, ushort_t* __restrict__ encb, int c0)
{
  const size_t i = (size_t)blockIdx.x * 256 + threadIdx.x;
  const size_t el = i * 4;
  const int k = el & 511;
  const int s = (el >> 9) & 511;
  const int z = el >> 18;
  const float4 v = *(const float4*)&enc[((size_t)s * 64 + c0 + z) * 512 + k];
  ushort4 r;
  r.x = f2bf(v.x); r.y = f2bf(v.y); r.z = f2bf(v.z); r.w = f2bf(v.w);
  ((ushort4*)encb)[i] = r;
}

// Fused: LN(w2w bf16) + w_all residual (enc from encbf), contracted with wo_n -> partials
__global__ __launch_bounds__(256)
void k_reduce(const ushort_t* __restrict__ w2w, const float* __restrict__ aw,
              const float* __restrict__ hnew, const ushort_t* __restrict__ encb,
              const float* __restrict__ won, const float* __restrict__ ng,
              const float* __restrict__ nb, float* __restrict__ part, int c0)
{
  const int z = blockIdx.x, b = c0 + z, yb = blockIdx.y, t = threadIdx.x;
  __shared__ float2 red[4];
  const int d0 = 4 * t;
  const float4 ngv = *(const float4*)&ng[d0];
  const float4 nbv = *(const float4*)&nb[d0];
  float acc[4][4] = {};
  for (int s = yb * 64; s < yb * 64 + 64; ++s) {
    const ushort4 xu = *(const ushort4*)&w2w[((size_t)z * 512 + s) * 1024 + d0];
    float x[4] = {bf2f(xu.x), bf2f(xu.y), bf2f(xu.z), bf2f(xu.w)};
    float ls = x[0] + x[1] + x[2] + x[3];
    float lss = x[0]*x[0] + x[1]*x[1] + x[2]*x[2] + x[3]*x[3];
    const float2 ss = blocksum2(ls, lss, red, t, 4);
    const float mean = ss.x * (1.f / 1024.f);
    const float var  = ss.y * (1.f / 1024.f) - mean * mean;
    const float inv  = rsqrtf(var + 1e-6f);
    const float awv = aw[b * 512 + s];
    float rr[4];
    if (t < 128) {
      const float4 hv = *(const float4*)&hnew[b * 512 + d0];
      rr[0] = awv * hv.x; rr[1] = awv * hv.y; rr[2] = awv * hv.z; rr[3] = awv * hv.w;
    } else {
      const ushort4 ev = *(const ushort4*)&encb[((size_t)z * 512 + s) * 512 + d0 - 512];
      rr[0] = bf2f(ev.x); rr[1] = bf2f(ev.y); rr[2] = bf2f(ev.z); rr[3] = bf2f(ev.w);
    }
    const float w0 = won[((size_t)b * 4 + 0) * 512 + s];
    const float w1 = won[((size_t)b * 4 + 1) * 512 + s];
    const float w2 = won[((size_t)b * 4 + 2) * 512 + s];
    const float w3 = won[((size_t)b * 4 + 3) * 512 + s];
    const float gg[4] = {ngv.x, ngv.y, ngv.z, ngv.w};
    const float bb[4] = {nbv.x, nbv.y, nbv.z, nbv.w};
#pragma unroll
    for (int k = 0; k < 4; ++k) {
      const float val = (x[k] - mean) * inv * gg[k] + bb[k] + rr[k];
      acc[0][k] += w0 * val; acc[1][k] += w1 * val;
      acc[2][k] += w2 * val; acc[3][k] += w3 * val;
    }
  }
#pragma unroll
  for (int o = 0; o < 4; ++o)
#pragma unroll
    for (int k = 0; k < 4; ++k)
      part[(((size_t)(b * 8 + yb) * 4 + o) << 10) + d0 + k] = acc[o][k];
}

// sum 8 partials -> ctx_op bf16 (256 x 1024)
__global__ __launch_bounds__(256)
void k_psum(const float* __restrict__ part, ushort_t* __restrict__ ctxop)
{
  const int idx = blockIdx.x * 256 + threadIdx.x;   // 262144
  const int r = idx >> 10, d = idx & 1023;
  const int b = r >> 2, o = r & 3;
  float s = 0.f;
#pragma unroll
  for (int p = 0; p < 8; ++p)
    s += part[(((size_t)(b * 8 + p) * 4 + o) << 10) + d];
  ctxop[idx] = f2bf(s);
}

// relu+bias, LN1, build op_all bf16 = [s1, ops[o]]
__global__ __launch_bounds__(512)
void k_ln1(const float* __restrict__ oppre, const float* __restrict__ wo_b,
           const float* __restrict__ n1g, const float* __restrict__ n1b,
           const float* __restrict__ ops, ushort_t* __restrict__ opall)
{
  const int r = blockIdx.x, t = threadIdx.x;
  const int o = r & 3;
  __shared__ float2 red[8];
  const float val = fmaxf(oppre[(size_t)r * 512 + t] + wo_b[t], 0.f);
  const float2 ss = blocksum2(val, val * val, red, t, 8);
  const float m = ss.x * (1.f / 512.f);
  const float v = ss.y * (1.f / 512.f) - m * m;
  const float s1 = (val - m) * rsqrtf(v + 1e-6f) * n1g[t] + n1b[t];
  opall[(size_t)r * 1024 + t] = f2bf(s1);
  opall[(size_t)r * 1024 + 512 + t] = f2bf(ops[o * 512 + t]);
}

// relu+bias, LN2 + ops, dot with concat_output -> oo
__global__ __launch_bounds__(512)
void k_ln2dot(const float* __restrict__ ohpre, const float* __restrict__ ot_b,
              const float* __restrict__ n2g, const float* __restrict__ n2b,
              const float* __restrict__ ops, const float* __restrict__ cc,
              const float* __restrict__ ops_bias, float* __restrict__ oo)
{
  const int r = blockIdx.x, t = threadIdx.x;
  const int b = r >> 2, o = r & 3;
  __shared__ float2 red[8];
  const float oh = fmaxf(ohpre[(size_t)r * 512 + t] + ot_b[t], 0.f);
  const float2 ss = blocksum2(oh, oh * oh, red, t, 8);
  const float m = ss.x * (1.f / 512.f);
  const float v = ss.y * (1.f / 512.f) - m * m;
  const float opo = (oh - m) * rsqrtf(v + 1e-6f) * n2g[t] + n2b[t] + ops[o * 512 + t];
  const float p = cc[b * 512 + t] * opo;
  const float2 s3 = blocksum2(p, 0.f, red, t, 8);
  if (t == 0) oo[r] = s3.x + ops_bias[o];
}

// nop head (coalesced via nWT) + log_softmax over 128
__global__ __launch_bounds__(128)
void k_final(const float* __restrict__ oo, const float* __restrict__ cc,
             const float* __restrict__ nWT, const float* __restrict__ nop_b,
             float* __restrict__ outp)
{
  const int b = blockIdx.x, t = threadIdx.x;
  __shared__ __align__(16) float ccs[512];
  __shared__ float red[2];
  __shared__ float red2[2];
  for (int i = t; i < 512; i += 128) ccs[i] = cc[b * 512 + i];
  __syncthreads();
  float v;
  if (t < 4) {
    v = oo[b * 4 + t];
  } else {
    const int j = t - 4;
    float a = nop_b[j];
    for (int k = 0; k < 512; ++k) a += ccs[k] * nWT[k * 128 + j];
    v = a;
  }
  float m = wave_max(v);
  if ((t & 63) == 0) red[t >> 6] = m;
  __syncthreads();
  m = fmaxf(red[0], red[1]);
  const float e = __expf(v - m);
  float s = wave_sum(e);
  if ((t & 63) == 0) red2[t >> 6] = s;
  __syncthreads();
  s = red2[0] + red2[1];
  outp[b * 128 + t] = v - m - logf(s);
}

} // namespace

extern "C" void kernel_launch(void* const* d_in, const int* in_sizes, int n_in,
                              void* d_out, int out_size, void* d_ws, size_t ws_size,
                              hipStream_t stream)
{
  const int*   input_step  = (const int*)  d_in[0];
  const float* last_hidden = (const float*)d_in[1];
  const float* enc         = (const float*)d_in[2];
  const float* word_word   = (const float*)d_in[3];
  const float* word_op     = (const float*)d_in[4];
  const int*   word_exist  = (const int*)  d_in[5];
  const int*   seq_mask    = (const int*)  d_in[6];
  const float* emb         = (const float*)d_in[7];
  const float* W_ih        = (const float*)d_in[8];
  const float* W_hh        = (const float*)d_in[9];
  const float* b_ih        = (const float*)d_in[10];
  const float* b_hh        = (const float*)d_in[11];
  const float* attn_W      = (const float*)d_in[12];
  const float* concat_W    = (const float*)d_in[14];
  const float* concat_b    = (const float*)d_in[15];
  const float* ops         = (const float*)d_in[16];
  const float* ops_bias    = (const float*)d_in[17];
  const float* nop_W       = (const float*)d_in[18];
  const float* nop_b       = (const float*)d_in[19];
  const float* gc1_W       = (const float*)d_in[20];
  const float* gc1_b       = (const float*)d_in[21];
  const float* gc2_W       = (const float*)d_in[22];
  const float* gc2_b       = (const float*)d_in[23];
  const float* norm_g      = (const float*)d_in[24];
  const float* norm_b      = (const float*)d_in[25];
  const float* norm1_g     = (const float*)d_in[26];
  const float* norm1_b     = (const float*)d_in[27];
  const float* norm2_g     = (const float*)d_in[28];
  const float* norm2_b     = (const float*)d_in[29];
  const float* wo_W        = (const float*)d_in[30];
  const float* wo_b        = (const float*)d_in[31];
  const float* ot_W        = (const float*)d_in[32];
  const float* ot_b        = (const float*)d_in[33];

  float* ws  = (float*)d_ws;
  float* out = (float*)d_out;

  // ---- workspace layout (floats) ----
  size_t off = 0;
  auto take = [&](size_t n) { size_t o = off; off += n; return o; };
  const size_t o_hnew = take(32768);
  const size_t o_q    = take(32768);
  const size_t o_u    = take(32768);
  const size_t o_aw   = take(32768);
  const size_t o_scores = take(32768);
  const size_t o_ctxpart = take(524288);   // 64*16*512
  const size_t o_cc   = take(32768);
  const size_t o_won  = take(131072);
  const size_t o_oo   = take(256);
  const size_t o_xT   = take(32768);
  const size_t o_hT   = take(32768);
  const size_t o_giT  = take(98304);
  const size_t o_ghT  = take(98304); (void)o_ghT;
  const size_t o_part = take(2097152);
  const size_t o_oppre = take(131072);
  const size_t o_ohpre = take(131072);
  const size_t o_gc1LT = take(131072);
  const size_t o_gc2WT = take(262144);
  const size_t o_woW   = take(262144);
  const size_t o_otW   = take(262144);
  const size_t o_cWT   = take(524288);
  const size_t o_nWT   = take(65536);
  const size_t o_ctxop = take(131072);
  const size_t o_opall = take(131072);
  const size_t base = off;

  // pick chunk size by available workspace (constant across calls -> graph-safe)
  int CB = 16;
  if (ws_size >= (base + 64ull * 655360) * 4) CB = 64;
  else if (ws_size >= (base + 32ull * 655360) * 4) CB = 32;
  const int nch = 64 / CB;

  const size_t o_adjbf = take((size_t)CB * 131072);
  const size_t o_h1t   = take((size_t)CB * 131072);
  const size_t o_tmat  = take((size_t)CB * 131072);
  const size_t o_encbf = take((size_t)CB * 131072);
  const size_t o_xw1t  = take((size_t)CB * 131072);
  const size_t o_w2w   = o_adjbf;          // overlays adjbf+h1t (dead after mgemm<2>)

  float* hnew = ws + o_hnew;
  float* q    = ws + o_q;
  float* u    = ws + o_u;
  float* aw   = ws + o_aw;
  float* scores = ws + o_scores;
  float* ctxpart = ws + o_ctxpart;
  float* cc   = ws + o_cc;
  float* won  = ws + o_won;
  float* oo   = ws + o_oo;
  float* xT   = ws + o_xT;
  float* hT   = ws + o_hT;
  float* giT  = ws + o_giT;
  float* part = ws + o_part;
  float* oppre = ws + o_oppre;
  float* ohpre = ws + o_ohpre;
  float* cWT  = ws + o_cWT;
  float* nWT  = ws + o_nWT;
  ushort_t* gc1LT = (ushort_t*)(ws + o_gc1LT);
  ushort_t* gc2WT = (ushort_t*)(ws + o_gc2WT);
  ushort_t* woWb  = (ushort_t*)(ws + o_woW);
  ushort_t* otWb  = (ushort_t*)(ws + o_otW);
  ushort_t* ctxop = (ushort_t*)(ws + o_ctxop);
  ushort_t* opall = (ushort_t*)(ws + o_opall);
  ushort_t* adjbf = (ushort_t*)(ws + o_adjbf);
  ushort_t* h1t   = (ushort_t*)(ws + o_h1t);
  ushort_t* tmat  = (ushort_t*)(ws + o_tmat);
  ushort_t* encbf = (ushort_t*)(ws + o_encbf);
  ushort_t* xw1t  = (ushort_t*)(ws + o_xw1t);
  ushort_t* w2wbf = (ushort_t*)(ws + o_w2w);

  float* out_logits = out;
  float* out_hnew   = out + 8192;
  float* out_aw     = out + 8192 + 32768;
  float* out_cc     = out + 8192 + 65536;

  // ---- weight conversions + GRU ----
  k_prep_w<<<9472, 256, 0, stream>>>(gc1_W, gc2_W, wo_W, ot_W, concat_W, nop_W,
                                     gc1LT, gc2WT, woWb, otWb, cWT, nWT);
  k_prep<<<128, 256, 0, stream>>>(input_step, emb, last_hidden, xT, hT);
  gemm_gru<<<dim3(1, 24, 2), 256, 0, stream>>>(W_ih, xT, W_hh, hT, giT);
  k_gru<<<128, 256, 0, stream>>>(giT, ws + o_ghT, last_hidden, b_ih, b_hh, hnew, out_hnew);

  // ---- attention (split, parallel) + concat + wo_n ----
  k_qu<<<dim3(64, 4), 128, 0, stream>>>(hnew, attn_W, gc1_W, q, u);
  k_score<<<dim3(64, 16), 256, 0, stream>>>(q, enc, scores, encbf, CB == 64 ? 1 : 0);
  k_softmax<<<64, 512, 0, stream>>>(scores, out_aw, aw);
  k_ctx<<<dim3(64, 16), 512, 0, stream>>>(aw, enc, ctxpart);
  k_concat<<<dim3(64, 4), 128, 0, stream>>>(hnew, ctxpart, cWT, concat_b, out_cc, cc);
  k_wo<<<dim3(64, 4), 512, 0, stream>>>(word_op, seq_mask, won);

  // ---- GCN chain (bf16 MFMA), chunked ----
  for (int c = 0; c < nch; ++c) {
    const int c0 = c * CB;
    k_adjc<<<CB * 256, 256, 0, stream>>>(word_word, word_exist, adjbf, c0);
    if (CB != 64) k_encc<<<CB * 256, 256, 0, stream>>>(enc, encbf, c0);
    // XW1T[d][s] = gc1LT[d][:] . enc_b[s][:] + u[b][d]*aw[b][s]
    mgemm<0><<<dim3(4, 4, CB), 256, 0, stream>>>(gc1LT, 512, 0, encbf, 512, 262144,
        xw1t, 512, 262144, 512, nullptr, aw, u, c0);
    // h1T[d][s] = relu(XW1T[d][:] . adj[s][:] + gc1_b[d])
    mgemm<1><<<dim3(4, 4, CB), 256, 0, stream>>>(xw1t, 512, 262144, adjbf, 512, 262144,
        h1t, 512, 262144, 512, gc1_b, nullptr, nullptr, 0);
    // t[s][d] = adj[s][:] . h1T[d][:]
    mgemm<2><<<dim3(4, 4, CB), 256, 0, stream>>>(adjbf, 512, 262144, h1t, 512, 262144,
        tmat, 512, 262144, 512, nullptr, nullptr, nullptr, 0);
    // w2w[s][e] = t[s][:] . gc2WT[e][:] + gc2_b[e]   (overlays adjbf+h1t)
    mgemm<3><<<dim3(8, 4, CB), 256, 0, stream>>>(tmat, 512, 262144, gc2WT, 512, 0,
        w2wbf, 1024, 524288, 512, gc2_b, nullptr, nullptr, 0);
    k_reduce<<<dim3(CB, 8), 256, 0, stream>>>(w2wbf, aw, hnew, encbf, won, norm_g, norm_b, part, c0);
  }

  // ---- op head (MFMA GEMMs) + nop head + log_softmax ----
  k_psum<<<1024, 256, 0, stream>>>(part, ctxop);
  mgemm<4><<<dim3(4, 2, 1), 256, 0, stream>>>(ctxop, 1024, 0, woWb, 1024, 0,
      oppre, 512, 0, 1024, nullptr, nullptr, nullptr, 0);
  k_ln1<<<256, 512, 0, stream>>>(oppre, wo_b, norm1_g, norm1_b, ops, opall);
  mgemm<4><<<dim3(4, 2, 1), 256, 0, stream>>>(opall, 1024, 0, otWb, 1024, 0,
      ohpre, 512, 0, 1024, nullptr, nullptr, nullptr, 0);
  k_ln2dot<<<256, 512, 0, stream>>>(ohpre, ot_b, norm2_g, norm2_b, ops, cc, ops_bias, oo);
  k_final<<<64, 128, 0, stream>>>(oo, cc, nWT, nop_b, out_logits);

  (void)in_sizes; (void)n_in; (void)out_size;
}

// Round 4
// 699.046 us; speedup vs baseline: 3.0226x; 1.0873x over previous
//
#include <hip/hip_runtime.h>
#include <math.h>

namespace {

typedef unsigned short ushort_t;
typedef __attribute__((ext_vector_type(8))) short short8;
typedef __attribute__((ext_vector_type(4))) float float4v;

__device__ __forceinline__ unsigned short f2bf(float x) {
  unsigned u = __float_as_uint(x);
  u += 0x7fffu + ((u >> 16) & 1u);        // RNE
  return (unsigned short)(u >> 16);
}
__device__ __forceinline__ float bf2f(unsigned short u) {
  return __uint_as_float((unsigned)u << 16);
}
__device__ __forceinline__ void bf8_to_f(const ushort_t* p, float* o) {
  const short8 v = *(const short8*)p;
#pragma unroll
  for (int k = 0; k < 8; ++k) o[k] = bf2f((unsigned short)v[k]);
}

__device__ __forceinline__ float wave_sum(float v) {
#pragma unroll
  for (int off = 32; off; off >>= 1) v += __shfl_down(v, off, 64);
  return v;
}
__device__ __forceinline__ float wave_max(float v) {
#pragma unroll
  for (int off = 32; off; off >>= 1) v = fmaxf(v, __shfl_down(v, off, 64));
  return v;
}
__device__ __forceinline__ float2 blocksum2(float a, float b, float2* red, int t, int nw) {
#pragma unroll
  for (int off = 32; off; off >>= 1) {
    a += __shfl_down(a, off, 64);
    b += __shfl_down(b, off, 64);
  }
  __syncthreads();
  if ((t & 63) == 0) red[t >> 6] = make_float2(a, b);
  __syncthreads();
  float sa = 0.f, sb = 0.f;
  for (int i = 0; i < nw; ++i) { sa += red[i].x; sb += red[i].y; }
  return make_float2(sa, sb);
}

// =================== bf16 MFMA NT-GEMM, 128x128 tile, BK=64 ===================
// C[M,N] = A[M,K] * Bt[N,K]^T.  M,N multiples of 128, K mult of 64.
// MODE 0: bf16 out, v += u[(c0+z)*512+row]*aw[(c0+z)*512+col]
// MODE 1: bf16 out, relu(v + bias[row])
// MODE 2: bf16 out, plain
// MODE 3: bf16 out, v + bias[col]
// MODE 4: f32 out, plain
template<int MODE>
__global__ __launch_bounds__(256)
void mgemm(const ushort_t* __restrict__ A, int lda, long sA,
           const ushort_t* __restrict__ Bt, int ldb, long sB,
           void* __restrict__ C, int ldc, long sC, int K,
           const float* __restrict__ bias,
           const float* __restrict__ aw, const float* __restrict__ u, int c0)
{
  __shared__ __attribute__((aligned(16))) ushort_t As[2][128 * 32];
  __shared__ __attribute__((aligned(16))) ushort_t Bs[2][128 * 32];
  const int z = blockIdx.z;
  const ushort_t* Ab = A  + (long)z * sA;
  const ushort_t* Bb = Bt + (long)z * sB;
  const int tm = blockIdx.y * 128, tn = blockIdx.x * 128;
  const int t = threadIdx.x, wv = t >> 6, ln = t & 63;
  const int lrow = ln >> 2, lseg = ln & 3;        // staging: 16 rows x 4 segs of 16B
  const int frow = ln & 15, fko = (ln >> 4) * 8;  // fragment: m=ln&15, k-quad
  const int wm = (wv >> 1) * 64, wn = (wv & 1) * 64;

  float4v acc[4][4];
#pragma unroll
  for (int i = 0; i < 4; ++i)
#pragma unroll
    for (int j = 0; j < 4; ++j) acc[i][j] = (float4v)0.f;

  for (int k0 = 0; k0 < K; k0 += 64) {
#pragma unroll
    for (int h2 = 0; h2 < 2; ++h2) {
#pragma unroll
      for (int half = 0; half < 2; ++half) {
        const int rbase = wv * 32 + half * 16;
        const ushort_t* ga = Ab + (long)(tm + rbase + lrow) * lda + k0 + h2 * 32 + lseg * 8;
        const ushort_t* gb = Bb + (long)(tn + rbase + lrow) * ldb + k0 + h2 * 32 + lseg * 8;
        __builtin_amdgcn_global_load_lds(
            (const __attribute__((address_space(1))) void*)ga,
            (__attribute__((address_space(3))) void*)&As[h2][rbase * 32], 16, 0, 0);
        __builtin_amdgcn_global_load_lds(
            (const __attribute__((address_space(1))) void*)gb,
            (__attribute__((address_space(3))) void*)&Bs[h2][rbase * 32], 16, 0, 0);
      }
    }
    __syncthreads();
#pragma unroll
    for (int h2 = 0; h2 < 2; ++h2) {
      short8 af[4], bfr[4];
#pragma unroll
      for (int i = 0; i < 4; ++i) af[i]  = *(const short8*)&As[h2][(wm + i * 16 + frow) * 32 + fko];
#pragma unroll
      for (int j = 0; j < 4; ++j) bfr[j] = *(const short8*)&Bs[h2][(wn + j * 16 + frow) * 32 + fko];
#pragma unroll
      for (int i = 0; i < 4; ++i)
#pragma unroll
        for (int j = 0; j < 4; ++j)
          acc[i][j] = __builtin_amdgcn_mfma_f32_16x16x32_bf16(af[i], bfr[j], acc[i][j], 0, 0, 0);
    }
    __syncthreads();
  }

  // epilogue: C/D layout col=lane&15, row=(lane>>4)*4+reg
#pragma unroll
  for (int i = 0; i < 4; ++i) {
#pragma unroll
    for (int j = 0; j < 4; ++j) {
      const int col = tn + wn + j * 16 + (ln & 15);
#pragma unroll
      for (int reg = 0; reg < 4; ++reg) {
        const int row = tm + wm + i * 16 + (ln >> 4) * 4 + reg;
        float v = acc[i][j][reg];
        if (MODE == 0) v += u[(c0 + z) * 512 + row] * aw[(c0 + z) * 512 + col];
        else if (MODE == 1) v = fmaxf(v + bias[row], 0.f);
        else if (MODE == 3) v += bias[col];
        if (MODE == 4) ((float*)C)[(long)z * sC + (long)row * ldc + col] = v;
        else ((ushort_t*)C)[(long)z * sC + (long)row * ldc + col] = f2bf(v);
      }
    }
  }
}

// =================== fp32 GRU GEMM (dual A/B via z) ===================
__global__ __launch_bounds__(256)
void gemm_gru(const float* __restrict__ A0, const float* __restrict__ B0,
              const float* __restrict__ A1, const float* __restrict__ B1,
              float* __restrict__ C)
{
  __shared__ float As[64][20];
  __shared__ float Bs[16][68];
  const int z = blockIdx.z;
  const float* Ab = z ? A1 : A0;
  const float* Bp = z ? B1 : B0;
  float* Cb = C + z * 98304;
  const int tm = blockIdx.y * 64;
  const int t = threadIdx.x;
  const int ty4 = (t >> 4) * 4, tx4 = (t & 15) * 4;
  const int aRow = t >> 2, aK = (t & 3) << 2;
  const int bK = t >> 4, bN = (t & 15) << 2;
  float acc[4][4] = {};
  for (int k0 = 0; k0 < 512; k0 += 16) {
    const float4 av = *(const float4*)&Ab[(long)(tm + aRow) * 512 + k0 + aK];
    const float4 bv = *(const float4*)&Bp[(long)(k0 + bK) * 64 + bN];
    __syncthreads();
    *(float4*)&As[aRow][aK] = av;
    *(float4*)&Bs[bK][bN]   = bv;
    __syncthreads();
#pragma unroll
    for (int k = 0; k < 16; ++k) {
      float a_[4], b_[4];
#pragma unroll
      for (int i = 0; i < 4; ++i) a_[i] = As[ty4 + i][k];
#pragma unroll
      for (int j = 0; j < 4; ++j) b_[j] = Bs[k][tx4 + j];
#pragma unroll
      for (int i = 0; i < 4; ++i)
#pragma unroll
        for (int j = 0; j < 4; ++j) acc[i][j] += a_[i] * b_[j];
    }
  }
#pragma unroll
  for (int i = 0; i < 4; ++i)
    *(float4*)&Cb[(long)(tm + ty4 + i) * 64 + tx4] =
        make_float4(acc[i][0], acc[i][1], acc[i][2], acc[i][3]);
}

// =================== small fused kernels ===================

__global__ __launch_bounds__(256)
void k_prep(const int* __restrict__ step, const float* __restrict__ emb,
            const float* __restrict__ last_hidden, float* __restrict__ xT, float* __restrict__ hT)
{
  const int idx = blockIdx.x * 256 + threadIdx.x;
  const int k = idx >> 6, b = idx & 63;
  xT[idx] = emb[(size_t)step[b] * 512 + k];
  hT[idx] = last_hidden[b * 512 + k];
}

// weight conversions:
//  gc1LT[d][k]=bf(gc1_W[512+k][d]); gc2WT[e][d]=bf(gc2_W[d][e]); woWb/otWb direct bf;
//  cWT[k][o]=concat_W[o][k] (fp32); nWT[k][j]=nop_W[j][k] (fp32, j padded to 128)
__global__ __launch_bounds__(256)
void k_prep_w(const float* __restrict__ gc1_W, const float* __restrict__ gc2_W,
              const float* __restrict__ wo_W, const float* __restrict__ ot_W,
              const float* __restrict__ concat_W, const float* __restrict__ nop_W,
              ushort_t* __restrict__ gc1LT, ushort_t* __restrict__ gc2WT,
              ushort_t* __restrict__ woWb, ushort_t* __restrict__ otWb,
              float* __restrict__ cWT, float* __restrict__ nWT)
{
  int idx = blockIdx.x * 256 + threadIdx.x;
  if (idx < 262144) {
    const int d = idx >> 9, k = idx & 511;
    gc1LT[idx] = f2bf(gc1_W[(size_t)(512 + k) * 512 + d]);
    return;
  }
  idx -= 262144;
  if (idx < 524288) {
    const int e = idx >> 9, d = idx & 511;
    gc2WT[idx] = f2bf(gc2_W[(size_t)d * 1024 + e]);
    return;
  }
  idx -= 524288;
  if (idx < 524288) { woWb[idx] = f2bf(wo_W[idx]); return; }
  idx -= 524288;
  if (idx < 524288) { otWb[idx] = f2bf(ot_W[idx]); return; }
  idx -= 524288;
  if (idx < 524288) {
    const int k = idx >> 9, o = idx & 511;
    cWT[idx] = concat_W[(size_t)o * 1024 + k];
    return;
  }
  idx -= 524288;
  if (idx < 65536) {
    const int k = idx >> 7, j = idx & 127;
    nWT[idx] = (j < 124) ? nop_W[(size_t)j * 512 + k] : 0.f;
  }
}

__global__ __launch_bounds__(256)
void k_gru(const float* __restrict__ giT, const float* __restrict__ ghT,
           const float* __restrict__ last_hidden, const float* __restrict__ b_ih,
           const float* __restrict__ b_hh, float* __restrict__ hnew, float* __restrict__ hnew_out)
{
  const int idx = blockIdx.x * 256 + threadIdx.x;
  const int b = idx >> 9, tt = idx & 511;
  const float ir  = giT[tt * 64 + b]          + b_ih[tt];
  const float iz  = giT[(512 + tt) * 64 + b]  + b_ih[512 + tt];
  const float inn = giT[(1024 + tt) * 64 + b] + b_ih[1024 + tt];
  const float hr  = ghT[tt * 64 + b]          + b_hh[tt];
  const float hz  = ghT[(512 + tt) * 64 + b]  + b_hh[512 + tt];
  const float hn  = ghT[(1024 + tt) * 64 + b] + b_hh[1024 + tt];
  const float h   = last_hidden[idx];
  const float r = 1.f / (1.f + __expf(-(ir + hr)));
  const float z = 1.f / (1.f + __expf(-(iz + hz)));
  const float n = tanhf(inn + r * hn);
  const float o = (1.f - z) * n + z * h;
  hnew[idx] = o;
  hnew_out[idx] = o;
}

// q = h_new @ attn_W ; u = h_new @ gc1_W[:512].  grid (64,4) x 128 threads.
__global__ __launch_bounds__(128)
void k_qu(const float* __restrict__ hnew, const float* __restrict__ attn_W,
          const float* __restrict__ gc1_W, float* __restrict__ q, float* __restrict__ u)
{
  const int b = blockIdx.x, j = blockIdx.y * 128 + threadIdx.x;
  __shared__ float hs[512];
  for (int i = threadIdx.x; i < 512; i += 128) hs[i] = hnew[b * 512 + i];
  __syncthreads();
  float qa = 0.f, ua = 0.f;
  for (int h = 0; h < 512; ++h) {
    const float hv = hs[h];
    qa += hv * attn_W[(size_t)h * 512 + j];
    ua += hv * gc1_W[(size_t)h * 512 + j];
  }
  q[b * 512 + j] = qa;
  u[b * 512 + j] = ua;
}

// scores[b,s] = q[b]·enc[s,b]; also emits encbf[b][s][k] (bf16) when emit!=0.
__global__ __launch_bounds__(256)
void k_score(const float* __restrict__ q, const float* __restrict__ enc,
             float* __restrict__ scores, ushort_t* __restrict__ encb, int emit)
{
  const int b = blockIdx.x, p = blockIdx.y;
  const int t = threadIdx.x, wv = t >> 6, ln = t & 63;
  __shared__ float qs[512];
  for (int i = t; i < 512; i += 256) qs[i] = q[b * 512 + i];
  __syncthreads();
  const int e0 = ln * 8;
  const float4 q0 = *(const float4*)&qs[e0];
  const float4 q1 = *(const float4*)&qs[e0 + 4];
  for (int it = 0; it < 8; ++it) {
    const int s = p * 32 + wv * 8 + it;
    const float* e = enc + ((size_t)s * 64 + b) * 512 + e0;
    const float4 v0 = *(const float4*)e;
    const float4 v1 = *(const float4*)(e + 4);
    float a = q0.x * v0.x + q0.y * v0.y + q0.z * v0.z + q0.w * v0.w
            + q1.x * v1.x + q1.y * v1.y + q1.z * v1.z + q1.w * v1.w;
    if (emit) {
      short8 o;
      o[0] = (short)f2bf(v0.x); o[1] = (short)f2bf(v0.y);
      o[2] = (short)f2bf(v0.z); o[3] = (short)f2bf(v0.w);
      o[4] = (short)f2bf(v1.x); o[5] = (short)f2bf(v1.y);
      o[6] = (short)f2bf(v1.z); o[7] = (short)f2bf(v1.w);
      *(short8*)&encb[(size_t)b * 262144 + (size_t)s * 512 + e0] = o;
    }
    a = wave_sum(a);
    if (ln == 0) scores[b * 512 + s] = a;
  }
}

// softmax over scores -> aw (ws + output)
__global__ __launch_bounds__(512)
void k_softmax(const float* __restrict__ scores, float* __restrict__ aw_dout,
               float* __restrict__ aw_ws)
{
  const int b = blockIdx.x, t = threadIdx.x;
  const int w = t >> 6, lane = t & 63;
  __shared__ float red[8];
  const float v = scores[b * 512 + t];
  float m = wave_max(v);
  if (lane == 0) red[w] = m;
  __syncthreads();
  float mm = red[0];
#pragma unroll
  for (int i = 1; i < 8; ++i) mm = fmaxf(mm, red[i]);
  const float e = __expf(v - mm);
  float s = wave_sum(e);
  __syncthreads();
  if (lane == 0) red[w] = s;
  __syncthreads();
  float tot = 0.f;
#pragma unroll
  for (int i = 0; i < 8; ++i) tot += red[i];
  const float awv = e / tot;
  aw_dout[b * 512 + t] = awv;
  aw_ws[b * 512 + t]   = awv;
}

// context partials: ctxpart[b][p][t] = sum_{s in p-chunk} aw[b,s]*enc[s,b,t]
__global__ __launch_bounds__(512)
void k_ctx(const float* __restrict__ aw, const float* __restrict__ enc,
           float* __restrict__ ctxpart)
{
  const int b = blockIdx.x, p = blockIdx.y, t = threadIdx.x;
  __shared__ float aws[32];
  if (t < 32) aws[t] = aw[b * 512 + p * 32 + t];
  __syncthreads();
  float acc = 0.f;
#pragma unroll 4
  for (int si = 0; si < 32; ++si)
    acc += aws[si] * enc[((size_t)(p * 32 + si) * 64 + b) * 512 + t];
  ctxpart[((size_t)b * 16 + p) * 512 + t] = acc;
}

// concat_output = relu([h_new, sum_p ctxpart] @ cWT + b).  grid (64,4) x 128.
__global__ __launch_bounds__(128)
void k_concat(const float* __restrict__ hnew, const float* __restrict__ ctxpart,
              const float* __restrict__ cWT, const float* __restrict__ bias,
              float* __restrict__ out_cc, float* __restrict__ cc_ws)
{
  const int b = blockIdx.x, o = blockIdx.y * 128 + threadIdx.x;
  __shared__ __align__(16) float cat[1024];
  for (int m = 0; m < 8; ++m) {
    const int i = threadIdx.x + 128 * m;
    if (i < 512) {
      cat[i] = hnew[b * 512 + i];
    } else {
      const int d = i - 512;
      float s = 0.f;
#pragma unroll
      for (int pp = 0; pp < 16; ++pp) s += ctxpart[((size_t)b * 16 + pp) * 512 + d];
      cat[i] = s;
    }
  }
  __syncthreads();
  float acc = bias[o];
  for (int k = 0; k < 1024; k += 4) {
    acc += cat[k]     * cWT[(size_t)k * 512 + o]
         + cat[k + 1] * cWT[(size_t)(k + 1) * 512 + o]
         + cat[k + 2] * cWT[(size_t)(k + 2) * 512 + o]
         + cat[k + 3] * cWT[(size_t)(k + 3) * 512 + o];
  }
  acc = fmaxf(acc, 0.f);
  out_cc[b * 512 + o] = acc;
  cc_ws[b * 512 + o]  = acc;
}

__global__ __launch_bounds__(512)
void k_wo(const float* __restrict__ word_op, const int* __restrict__ seq_mask, float* __restrict__ won)
{
  const int b = blockIdx.x, o = blockIdx.y, s = threadIdx.x;
  float v = word_op[((size_t)(b * 512 + s)) * 4 + o];
  if (seq_mask[b * 512 + s] != 0) v = 0.f;
  __shared__ float red[8];
  float sm = wave_sum(v);
  if ((s & 63) == 0) red[s >> 6] = sm;
  __syncthreads();
  float tot = 0.f;
#pragma unroll
  for (int i = 0; i < 8; ++i) tot += red[i];
  won[((size_t)b * 4 + o) * 512 + s] = v / (tot + 1e-30f);
}

// adj (bf16) for chunk
__global__ __launch_bounds__(256)
void k_adjc(const float* __restrict__ ww, const int* __restrict__ ex,
            ushort_t* __restrict__ adj, int c0)
{
  const size_t i = (size_t)blockIdx.x * 256 + threadIdx.x;
  const size_t base4 = (size_t)c0 * 512 * 512 / 4;
  const float4 w4 = ((const float4*)ww)[base4 + i];
  const int4   e4 = ((const int4*)ex)[base4 + i];
  ushort4 r;
  r.x = (e4.x == 1) ? f2bf(w4.x) : 0;
  r.y = (e4.y == 1) ? f2bf(w4.y) : 0;
  r.z = (e4.z == 1) ? f2bf(w4.z) : 0;
  r.w = (e4.w == 1) ? f2bf(w4.w) : 0;
  ((ushort4*)adj)[i] = r;
}

// enc (bf16, batch-packed) for chunk (only used when CB<64)
__global__ __launch_bounds__(256)
void k_encc(const float* __restrict__ enc, ushort_t* __restrict__ encb, int c0)
{
  const size_t i = (size_t)blockIdx.x * 256 + threadIdx.x;
  const size_t el = i * 4;
  const int k = el & 511;
  const int s = (el >> 9) & 511;
  const int z = el >> 18;
  const float4 v = *(const float4*)&enc[((size_t)s * 64 + c0 + z) * 512 + k];
  ushort4 r;
  r.x = f2bf(v.x); r.y = f2bf(v.y); r.z = f2bf(v.z); r.w = f2bf(v.w);
  ((ushort4*)encb)[i] = r;
}

// Barrier-free fused LN + residual + wo_n contraction.
// grid (CB, 8); 4 waves/block; wave handles 16 s-rows, one full row (1024 d) per iter.
__global__ __launch_bounds__(256)
void k_red2(const ushort_t* __restrict__ w2w, const float* __restrict__ aw,
            const float* __restrict__ hnew, const ushort_t* __restrict__ encb,
            const float* __restrict__ won, const float* __restrict__ ng,
            const float* __restrict__ nb, float* __restrict__ part, int c0)
{
  const int z = blockIdx.x, b = c0 + z, yb = blockIdx.y;
  const int t = threadIdx.x, wv = t >> 6, ln = t & 63;
  __shared__ float sw[64][5];               // won0..3, aw per s-local
  __shared__ float accs[2][4][1024];        // cross-wave combine (32 KB)
  for (int i = t; i < 320; i += 256) {
    const int sl = i / 5, c_ = i - sl * 5;
    const int sg = yb * 64 + sl;
    sw[sl][c_] = (c_ < 4) ? won[((size_t)b * 4 + c_) * 512 + sg] : aw[b * 512 + sg];
  }
  const int d0 = ln * 16;
  float gg[16], bb[16], hv[16];
#pragma unroll
  for (int k = 0; k < 16; k += 4) {
    *(float4*)&gg[k] = *(const float4*)&ng[d0 + k];
    *(float4*)&bb[k] = *(const float4*)&nb[d0 + k];
  }
  if (ln < 32) {
#pragma unroll
    for (int k = 0; k < 16; k += 4)
      *(float4*)&hv[k] = *(const float4*)&hnew[b * 512 + d0 + k];
  }
  float acc[4][16];
#pragma unroll
  for (int o = 0; o < 4; ++o)
#pragma unroll
    for (int k = 0; k < 16; ++k) acc[o][k] = 0.f;
  __syncthreads();
  for (int it = 0; it < 16; ++it) {
    const int sl = wv * 16 + it;
    const int s = yb * 64 + sl;
    const ushort_t* row = w2w + ((size_t)z * 512 + s) * 1024 + d0;
    float x[16];
    bf8_to_f(row, x);
    bf8_to_f(row + 8, x + 8);
    float ls = 0.f, lss = 0.f;
#pragma unroll
    for (int k = 0; k < 16; ++k) { ls += x[k]; lss += x[k] * x[k]; }
#pragma unroll
    for (int off = 32; off; off >>= 1) {
      ls  += __shfl_xor(ls,  off, 64);
      lss += __shfl_xor(lss, off, 64);
    }
    const float mean = ls * (1.f / 1024.f);
    const float var  = lss * (1.f / 1024.f) - mean * mean;
    const float inv  = rsqrtf(var + 1e-6f);
    float res[16];
    if (ln < 32) {
      const float a_ = sw[sl][4];
#pragma unroll
      for (int k = 0; k < 16; ++k) res[k] = a_ * hv[k];
    } else {
      const ushort_t* er = encb + ((size_t)z * 512 + s) * 512 + (d0 - 512);
      bf8_to_f(er, res);
      bf8_to_f(er + 8, res + 8);
    }
    const float w0 = sw[sl][0], w1 = sw[sl][1], w2 = sw[sl][2], w3 = sw[sl][3];
#pragma unroll
    for (int k = 0; k < 16; ++k) {
      const float val = (x[k] - mean) * inv * gg[k] + bb[k] + res[k];
      acc[0][k] += w0 * val; acc[1][k] += w1 * val;
      acc[2][k] += w2 * val; acc[3][k] += w3 * val;
    }
  }
  if (wv < 2) {
#pragma unroll
    for (int o = 0; o < 4; ++o)
#pragma unroll
      for (int k = 0; k < 16; k += 4)
        *(float4*)&accs[wv][o][d0 + k] = *(float4*)&acc[o][k];
  }
  __syncthreads();
  if (wv >= 2) {
#pragma unroll
    for (int o = 0; o < 4; ++o)
#pragma unroll
      for (int k = 0; k < 16; ++k)
        accs[wv - 2][o][d0 + k] += acc[o][k];
  }
  __syncthreads();
  for (int i = t; i < 4096; i += 256) {
    const int o = i >> 10, d = i & 1023;
    part[(((size_t)(b * 8 + yb) * 4 + o) << 10) + d] = accs[0][o][d] + accs[1][o][d];
  }
}

// sum 8 partials -> ctx_op bf16 (256 x 1024)
__global__ __launch_bounds__(256)
void k_psum(const float* __restrict__ part, ushort_t* __restrict__ ctxop)
{
  const int idx = blockIdx.x * 256 + threadIdx.x;   // 262144
  const int r = idx >> 10, d = idx & 1023;
  const int b = r >> 2, o = r & 3;
  float s = 0.f;
#pragma unroll
  for (int p = 0; p < 8; ++p)
    s += part[(((size_t)(b * 8 + p) * 4 + o) << 10) + d];
  ctxop[idx] = f2bf(s);
}

// relu+bias, LN1, build op_all bf16 = [s1, ops[o]]
__global__ __launch_bounds__(512)
void k_ln1(const float* __restrict__ oppre, const float* __restrict__ wo_b,
           const float* __restrict__ n1g, const float* __restrict__ n1b,
           const float* __restrict__ ops, ushort_t* __restrict__ opall)
{
  const int r = blockIdx.x, t = threadIdx.x;
  const int o = r & 3;
  __shared__ float2 red[8];
  const float val = fmaxf(oppre[(size_t)r * 512 + t] + wo_b[t], 0.f);
  const float2 ss = blocksum2(val, val * val, red, t, 8);
  const float m = ss.x * (1.f / 512.f);
  const float v = ss.y * (1.f / 512.f) - m * m;
  const float s1 = (val - m) * rsqrtf(v + 1e-6f) * n1g[t] + n1b[t];
  opall[(size_t)r * 1024 + t] = f2bf(s1);
  opall[(size_t)r * 1024 + 512 + t] = f2bf(ops[o * 512 + t]);
}

// relu+bias, LN2 + ops, dot with concat_output -> oo
__global__ __launch_bounds__(512)
void k_ln2dot(const float* __restrict__ ohpre, const float* __restrict__ ot_b,
              const float* __restrict__ n2g, const float* __restrict__ n2b,
              const float* __restrict__ ops, const float* __restrict__ cc,
              const float* __restrict__ ops_bias, float* __restrict__ oo)
{
  const int r = blockIdx.x, t = threadIdx.x;
  const int b = r >> 2, o = r & 3;
  __shared__ float2 red[8];
  const float oh = fmaxf(ohpre[(size_t)r * 512 + t] + ot_b[t], 0.f);
  const float2 ss = blocksum2(oh, oh * oh, red, t, 8);
  const float m = ss.x * (1.f / 512.f);
  const float v = ss.y * (1.f / 512.f) - m * m;
  const float opo = (oh - m) * rsqrtf(v + 1e-6f) * n2g[t] + n2b[t] + ops[o * 512 + t];
  const float p = cc[b * 512 + t] * opo;
  const float2 s3 = blocksum2(p, 0.f, red, t, 8);
  if (t == 0) oo[r] = s3.x + ops_bias[o];
}

// nop head (coalesced via nWT) + log_softmax over 128
__global__ __launch_bounds__(128)
void k_final(const float* __restrict__ oo, const float* __restrict__ cc,
             const float* __restrict__ nWT, const float* __restrict__ nop_b,
             float* __restrict__ outp)
{
  const int b = blockIdx.x, t = threadIdx.x;
  __shared__ __align__(16) float ccs[512];
  __shared__ float red[2];
  __shared__ float red2[2];
  for (int i = t; i < 512; i += 128) ccs[i] = cc[b * 512 + i];
  __syncthreads();
  float v;
  if (t < 4) {
    v = oo[b * 4 + t];
  } else {
    const int j = t - 4;
    float a = nop_b[j];
    for (int k = 0; k < 512; ++k) a += ccs[k] * nWT[k * 128 + j];
    v = a;
  }
  float m = wave_max(v);
  if ((t & 63) == 0) red[t >> 6] = m;
  __syncthreads();
  m = fmaxf(red[0], red[1]);
  const float e = __expf(v - m);
  float s = wave_sum(e);
  if ((t & 63) == 0) red2[t >> 6] = s;
  __syncthreads();
  s = red2[0] + red2[1];
  outp[b * 128 + t] = v - m - logf(s);
}

} // namespace

extern "C" void kernel_launch(void* const* d_in, const int* in_sizes, int n_in,
                              void* d_out, int out_size, void* d_ws, size_t ws_size,
                              hipStream_t stream)
{
  const int*   input_step  = (const int*)  d_in[0];
  const float* last_hidden = (const float*)d_in[1];
  const float* enc         = (const float*)d_in[2];
  const float* word_word   = (const float*)d_in[3];
  const float* word_op     = (const float*)d_in[4];
  const int*   word_exist  = (const int*)  d_in[5];
  const int*   seq_mask    = (const int*)  d_in[6];
  const float* emb         = (const float*)d_in[7];
  const float* W_ih        = (const float*)d_in[8];
  const float* W_hh        = (const float*)d_in[9];
  const float* b_ih        = (const float*)d_in[10];
  const float* b_hh        = (const float*)d_in[11];
  const float* attn_W      = (const float*)d_in[12];
  const float* concat_W    = (const float*)d_in[14];
  const float* concat_b    = (const float*)d_in[15];
  const float* ops         = (const float*)d_in[16];
  const float* ops_bias    = (const float*)d_in[17];
  const float* nop_W       = (const float*)d_in[18];
  const float* nop_b       = (const float*)d_in[19];
  const float* gc1_W       = (const float*)d_in[20];
  const float* gc1_b       = (const float*)d_in[21];
  const float* gc2_W       = (const float*)d_in[22];
  const float* gc2_b       = (const float*)d_in[23];
  const float* norm_g      = (const float*)d_in[24];
  const float* norm_b      = (const float*)d_in[25];
  const float* norm1_g     = (const float*)d_in[26];
  const float* norm1_b     = (const float*)d_in[27];
  const float* norm2_g     = (const float*)d_in[28];
  const float* norm2_b     = (const float*)d_in[29];
  const float* wo_W        = (const float*)d_in[30];
  const float* wo_b        = (const float*)d_in[31];
  const float* ot_W        = (const float*)d_in[32];
  const float* ot_b        = (const float*)d_in[33];

  float* ws  = (float*)d_ws;
  float* out = (float*)d_out;

  // ---- workspace layout (floats) ----
  size_t off = 0;
  auto take = [&](size_t n) { size_t o = off; off += n; return o; };
  const size_t o_hnew = take(32768);
  const size_t o_q    = take(32768);
  const size_t o_u    = take(32768);
  const size_t o_aw   = take(32768);
  const size_t o_scores = take(32768);
  const size_t o_ctxpart = take(524288);   // 64*16*512
  const size_t o_cc   = take(32768);
  const size_t o_won  = take(131072);
  const size_t o_oo   = take(256);
  const size_t o_xT   = take(32768);
  const size_t o_hT   = take(32768);
  const size_t o_giT  = take(98304);
  const size_t o_ghT  = take(98304); (void)o_ghT;
  const size_t o_part = take(2097152);
  const size_t o_oppre = take(131072);
  const size_t o_ohpre = take(131072);
  const size_t o_gc1LT = take(131072);
  const size_t o_gc2WT = take(262144);
  const size_t o_woW   = take(262144);
  const size_t o_otW   = take(262144);
  const size_t o_cWT   = take(524288);
  const size_t o_nWT   = take(65536);
  const size_t o_ctxop = take(131072);
  const size_t o_opall = take(131072);
  const size_t base = off;

  // pick chunk size by available workspace (constant across calls -> graph-safe)
  int CB = 16;
  if (ws_size >= (base + 64ull * 655360) * 4) CB = 64;
  else if (ws_size >= (base + 32ull * 655360) * 4) CB = 32;
  const int nch = 64 / CB;

  const size_t o_adjbf = take((size_t)CB * 131072);
  const size_t o_h1t   = take((size_t)CB * 131072);
  const size_t o_tmat  = take((size_t)CB * 131072);
  const size_t o_encbf = take((size_t)CB * 131072);
  const size_t o_xw1t  = take((size_t)CB * 131072);
  const size_t o_w2w   = o_adjbf;          // overlays adjbf+h1t (dead after mgemm<2>)

  float* hnew = ws + o_hnew;
  float* q    = ws + o_q;
  float* u    = ws + o_u;
  float* aw   = ws + o_aw;
  float* scores = ws + o_scores;
  float* ctxpart = ws + o_ctxpart;
  float* cc   = ws + o_cc;
  float* won  = ws + o_won;
  float* oo   = ws + o_oo;
  float* xT   = ws + o_xT;
  float* hT   = ws + o_hT;
  float* giT  = ws + o_giT;
  float* part = ws + o_part;
  float* oppre = ws + o_oppre;
  float* ohpre = ws + o_ohpre;
  float* cWT  = ws + o_cWT;
  float* nWT  = ws + o_nWT;
  ushort_t* gc1LT = (ushort_t*)(ws + o_gc1LT);
  ushort_t* gc2WT = (ushort_t*)(ws + o_gc2WT);
  ushort_t* woWb  = (ushort_t*)(ws + o_woW);
  ushort_t* otWb  = (ushort_t*)(ws + o_otW);
  ushort_t* ctxop = (ushort_t*)(ws + o_ctxop);
  ushort_t* opall = (ushort_t*)(ws + o_opall);
  ushort_t* adjbf = (ushort_t*)(ws + o_adjbf);
  ushort_t* h1t   = (ushort_t*)(ws + o_h1t);
  ushort_t* tmat  = (ushort_t*)(ws + o_tmat);
  ushort_t* encbf = (ushort_t*)(ws + o_encbf);
  ushort_t* xw1t  = (ushort_t*)(ws + o_xw1t);
  ushort_t* w2wbf = (ushort_t*)(ws + o_w2w);

  float* out_logits = out;
  float* out_hnew   = out + 8192;
  float* out_aw     = out + 8192 + 32768;
  float* out_cc     = out + 8192 + 65536;

  // ---- weight conversions + GRU ----
  k_prep_w<<<9472, 256, 0, stream>>>(gc1_W, gc2_W, wo_W, ot_W, concat_W, nop_W,
                                     gc1LT, gc2WT, woWb, otWb, cWT, nWT);
  k_prep<<<128, 256, 0, stream>>>(input_step, emb, last_hidden, xT, hT);
  gemm_gru<<<dim3(1, 24, 2), 256, 0, stream>>>(W_ih, xT, W_hh, hT, giT);
  k_gru<<<128, 256, 0, stream>>>(giT, ws + o_ghT, last_hidden, b_ih, b_hh, hnew, out_hnew);

  // ---- attention (split, parallel) + concat + wo_n ----
  k_qu<<<dim3(64, 4), 128, 0, stream>>>(hnew, attn_W, gc1_W, q, u);
  k_score<<<dim3(64, 16), 256, 0, stream>>>(q, enc, scores, encbf, CB == 64 ? 1 : 0);
  k_softmax<<<64, 512, 0, stream>>>(scores, out_aw, aw);
  k_ctx<<<dim3(64, 16), 512, 0, stream>>>(aw, enc, ctxpart);
  k_concat<<<dim3(64, 4), 128, 0, stream>>>(hnew, ctxpart, cWT, concat_b, out_cc, cc);
  k_wo<<<dim3(64, 4), 512, 0, stream>>>(word_op, seq_mask, won);

  // ---- GCN chain (bf16 MFMA), chunked ----
  for (int c = 0; c < nch; ++c) {
    const int c0 = c * CB;
    k_adjc<<<CB * 256, 256, 0, stream>>>(word_word, word_exist, adjbf, c0);
    if (CB != 64) k_encc<<<CB * 256, 256, 0, stream>>>(enc, encbf, c0);
    // XW1T[d][s] = gc1LT[d][:] . enc_b[s][:] + u[b][d]*aw[b][s]
    mgemm<0><<<dim3(4, 4, CB), 256, 0, stream>>>(gc1LT, 512, 0, encbf, 512, 262144,
        xw1t, 512, 262144, 512, nullptr, aw, u, c0);
    // h1T[d][s] = relu(XW1T[d][:] . adj[s][:] + gc1_b[d])
    mgemm<1><<<dim3(4, 4, CB), 256, 0, stream>>>(xw1t, 512, 262144, adjbf, 512, 262144,
        h1t, 512, 262144, 512, gc1_b, nullptr, nullptr, 0);
    // t[s][d] = adj[s][:] . h1T[d][:]
    mgemm<2><<<dim3(4, 4, CB), 256, 0, stream>>>(adjbf, 512, 262144, h1t, 512, 262144,
        tmat, 512, 262144, 512, nullptr, nullptr, nullptr, 0);
    // w2w[s][e] = t[s][:] . gc2WT[e][:] + gc2_b[e]   (overlays adjbf+h1t)
    mgemm<3><<<dim3(8, 4, CB), 256, 0, stream>>>(tmat, 512, 262144, gc2WT, 512, 0,
        w2wbf, 1024, 524288, 512, gc2_b, nullptr, nullptr, 0);
    k_red2<<<dim3(CB, 8), 256, 0, stream>>>(w2wbf, aw, hnew, encbf, won, norm_g, norm_b, part, c0);
  }

  // ---- op head (MFMA GEMMs) + nop head + log_softmax ----
  k_psum<<<1024, 256, 0, stream>>>(part, ctxop);
  mgemm<4><<<dim3(4, 2, 1), 256, 0, stream>>>(ctxop, 1024, 0, woWb, 1024, 0,
      oppre, 512, 0, 1024, nullptr, nullptr, nullptr, 0);
  k_ln1<<<256, 512, 0, stream>>>(oppre, wo_b, norm1_g, norm1_b, ops, opall);
  mgemm<4><<<dim3(4, 2, 1), 256, 0, stream>>>(opall, 1024, 0, otWb, 1024, 0,
      ohpre, 512, 0, 1024, nullptr, nullptr, nullptr, 0);
  k_ln2dot<<<256, 512, 0, stream>>>(ohpre, ot_b, norm2_g, norm2_b, ops, cc, ops_bias, oo);
  k_final<<<64, 128, 0, stream>>>(oo, cc, nWT, nop_b, out_logits);

  (void)in_sizes; (void)n_in; (void)out_size;
}

// Round 5
// 657.180 us; speedup vs baseline: 3.2152x; 1.0637x over previous
//
#include <hip/hip_runtime.h>
#include <math.h>

namespace {

typedef unsigned short ushort_t;
typedef __attribute__((ext_vector_type(8))) short short8;
typedef __attribute__((ext_vector_type(4))) float float4v;

__device__ __forceinline__ unsigned short f2bf(float x) {
  unsigned u = __float_as_uint(x);
  u += 0x7fffu + ((u >> 16) & 1u);        // RNE
  return (unsigned short)(u >> 16);
}
__device__ __forceinline__ float bf2f(unsigned short u) {
  return __uint_as_float((unsigned)u << 16);
}
__device__ __forceinline__ void bf8_to_f(const ushort_t* p, float* o) {
  const short8 v = *(const short8*)p;
#pragma unroll
  for (int k = 0; k < 8; ++k) o[k] = bf2f((unsigned short)v[k]);
}

__device__ __forceinline__ float wave_sum(float v) {
#pragma unroll
  for (int off = 32; off; off >>= 1) v += __shfl_down(v, off, 64);
  return v;
}
__device__ __forceinline__ float wave_max(float v) {
#pragma unroll
  for (int off = 32; off; off >>= 1) v = fmaxf(v, __shfl_down(v, off, 64));
  return v;
}
__device__ __forceinline__ float2 blocksum2(float a, float b, float2* red, int t, int nw) {
#pragma unroll
  for (int off = 32; off; off >>= 1) {
    a += __shfl_down(a, off, 64);
    b += __shfl_down(b, off, 64);
  }
  __syncthreads();
  if ((t & 63) == 0) red[t >> 6] = make_float2(a, b);
  __syncthreads();
  float sa = 0.f, sb = 0.f;
  for (int i = 0; i < nw; ++i) { sa += red[i].x; sb += red[i].y; }
  return make_float2(sa, sb);
}

// =================== bf16 MFMA NT-GEMM, 128x128 tile, BK=64 ===================
// C[M,N] = A[M,K] * Bt[N,K]^T.  M,N multiples of 128, K mult of 64.
// XCD-aware z-grouped block swizzle (nz % 8 == 0) + LDS seg-XOR (bank-conflict-free).
// MODE 0: bf16 out, v += u[(c0+z)*512+row]*aw[(c0+z)*512+col]
// MODE 1: bf16 out, relu(v + bias[row])
// MODE 2: bf16 out, plain
// MODE 3: bf16 out, v + bias[col]
// MODE 4: f32 out, plain
template<int MODE>
__global__ __launch_bounds__(256)
void mgemm(const ushort_t* __restrict__ A, int lda, long sA,
           const ushort_t* __restrict__ Bt, int ldb, long sB,
           void* __restrict__ C, int ldc, long sC, int K,
           const float* __restrict__ bias,
           const float* __restrict__ aw, const float* __restrict__ u, int c0)
{
  __shared__ __attribute__((aligned(16))) ushort_t As[2][128 * 32];
  __shared__ __attribute__((aligned(16))) ushort_t Bs[2][128 * 32];

  // ---- XCD-aware swizzle: group all xy-tiles of one z on one XCD ----
  int bx = blockIdx.x, by = blockIdx.y, bz = blockIdx.z;
  const int nx = gridDim.x, ny = gridDim.y, nz = gridDim.z;
  if ((nz & 7) == 0) {
    const int nxy = nx * ny;
    const int L = bx + nx * (by + ny * bz);
    const int xcd = L & 7;
    const int idx = L >> 3;
    const int lz = idx / nxy;
    const int xy = idx - lz * nxy;
    bz = xcd + 8 * lz;
    bx = xy % nx;
    by = xy / nx;
  }

  const int z = bz;
  const ushort_t* Ab = A  + (long)z * sA;
  const ushort_t* Bb = Bt + (long)z * sB;
  const int tm = by * 128, tn = bx * 128;
  const int t = threadIdx.x, wv = t >> 6, ln = t & 63;
  const int lrow = ln >> 2, lseg = ln & 3;        // staging: 16 rows x 4 segs of 16B
  const int gseg = lseg ^ ((lrow >> 1) & 3);      // bank-conflict-free seg XOR
  const int frow = ln & 15, q = ln >> 4;          // fragment: m=ln&15, k-quad
  const int sw8 = (frow >> 1) & 3;
  const int aoff = (q ^ sw8) << 3;
  const int wm = (wv >> 1) * 64, wn = (wv & 1) * 64;

  float4v acc[4][4];
#pragma unroll
  for (int i = 0; i < 4; ++i)
#pragma unroll
    for (int j = 0; j < 4; ++j) acc[i][j] = (float4v)0.f;

  for (int k0 = 0; k0 < K; k0 += 64) {
#pragma unroll
    for (int h2 = 0; h2 < 2; ++h2) {
#pragma unroll
      for (int half = 0; half < 2; ++half) {
        const int rbase = wv * 32 + half * 16;
        const ushort_t* ga = Ab + (long)(tm + rbase + lrow) * lda + k0 + h2 * 32 + gseg * 8;
        const ushort_t* gb = Bb + (long)(tn + rbase + lrow) * ldb + k0 + h2 * 32 + gseg * 8;
        __builtin_amdgcn_global_load_lds(
            (const __attribute__((address_space(1))) void*)ga,
            (__attribute__((address_space(3))) void*)&As[h2][rbase * 32], 16, 0, 0);
        __builtin_amdgcn_global_load_lds(
            (const __attribute__((address_space(1))) void*)gb,
            (__attribute__((address_space(3))) void*)&Bs[h2][rbase * 32], 16, 0, 0);
      }
    }
    __syncthreads();
#pragma unroll
    for (int h2 = 0; h2 < 2; ++h2) {
      short8 af[4], bfr[4];
#pragma unroll
      for (int i = 0; i < 4; ++i) af[i]  = *(const short8*)&As[h2][(wm + i * 16 + frow) * 32 + aoff];
#pragma unroll
      for (int j = 0; j < 4; ++j) bfr[j] = *(const short8*)&Bs[h2][(wn + j * 16 + frow) * 32 + aoff];
#pragma unroll
      for (int i = 0; i < 4; ++i)
#pragma unroll
        for (int j = 0; j < 4; ++j)
          acc[i][j] = __builtin_amdgcn_mfma_f32_16x16x32_bf16(af[i], bfr[j], acc[i][j], 0, 0, 0);
    }
    __syncthreads();
  }

  // epilogue: C/D layout col=lane&15, row=(lane>>4)*4+reg
#pragma unroll
  for (int i = 0; i < 4; ++i) {
#pragma unroll
    for (int j = 0; j < 4; ++j) {
      const int col = tn + wn + j * 16 + (ln & 15);
#pragma unroll
      for (int reg = 0; reg < 4; ++reg) {
        const int row = tm + wm + i * 16 + (ln >> 4) * 4 + reg;
        float v = acc[i][j][reg];
        if (MODE == 0) v += u[(c0 + z) * 512 + row] * aw[(c0 + z) * 512 + col];
        else if (MODE == 1) v = fmaxf(v + bias[row], 0.f);
        else if (MODE == 3) v += bias[col];
        if (MODE == 4) ((float*)C)[(long)z * sC + (long)row * ldc + col] = v;
        else ((ushort_t*)C)[(long)z * sC + (long)row * ldc + col] = f2bf(v);
      }
    }
  }
}

// =================== fp32 GRU GEMM (dual A/B via z) ===================
__global__ __launch_bounds__(256)
void gemm_gru(const float* __restrict__ A0, const float* __restrict__ B0,
              const float* __restrict__ A1, const float* __restrict__ B1,
              float* __restrict__ C)
{
  __shared__ float As[64][20];
  __shared__ float Bs[16][68];
  const int z = blockIdx.z;
  const float* Ab = z ? A1 : A0;
  const float* Bp = z ? B1 : B0;
  float* Cb = C + z * 98304;
  const int tm = blockIdx.y * 64;
  const int t = threadIdx.x;
  const int ty4 = (t >> 4) * 4, tx4 = (t & 15) * 4;
  const int aRow = t >> 2, aK = (t & 3) << 2;
  const int bK = t >> 4, bN = (t & 15) << 2;
  float acc[4][4] = {};
  for (int k0 = 0; k0 < 512; k0 += 16) {
    const float4 av = *(const float4*)&Ab[(long)(tm + aRow) * 512 + k0 + aK];
    const float4 bv = *(const float4*)&Bp[(long)(k0 + bK) * 64 + bN];
    __syncthreads();
    *(float4*)&As[aRow][aK] = av;
    *(float4*)&Bs[bK][bN]   = bv;
    __syncthreads();
#pragma unroll
    for (int k = 0; k < 16; ++k) {
      float a_[4], b_[4];
#pragma unroll
      for (int i = 0; i < 4; ++i) a_[i] = As[ty4 + i][k];
#pragma unroll
      for (int j = 0; j < 4; ++j) b_[j] = Bs[k][tx4 + j];
#pragma unroll
      for (int i = 0; i < 4; ++i)
#pragma unroll
        for (int j = 0; j < 4; ++j) acc[i][j] += a_[i] * b_[j];
    }
  }
#pragma unroll
  for (int i = 0; i < 4; ++i)
    *(float4*)&Cb[(long)(tm + ty4 + i) * 64 + tx4] =
        make_float4(acc[i][0], acc[i][1], acc[i][2], acc[i][3]);
}

// =================== small fused kernels ===================

__global__ __launch_bounds__(256)
void k_prep(const int* __restrict__ step, const float* __restrict__ emb,
            const float* __restrict__ last_hidden, float* __restrict__ xT, float* __restrict__ hT)
{
  const int idx = blockIdx.x * 256 + threadIdx.x;
  const int k = idx >> 6, b = idx & 63;
  xT[idx] = emb[(size_t)step[b] * 512 + k];
  hT[idx] = last_hidden[b * 512 + k];
}

// weight conversions:
//  gc1LT[d][k]=bf(gc1_W[512+k][d]); gc2WT[e][d]=bf(gc2_W[d][e]); woWb/otWb direct bf;
//  cWT[k][o]=concat_W[o][k] (fp32); nWT[k][j]=nop_W[j][k] (fp32, j padded to 128)
__global__ __launch_bounds__(256)
void k_prep_w(const float* __restrict__ gc1_W, const float* __restrict__ gc2_W,
              const float* __restrict__ wo_W, const float* __restrict__ ot_W,
              const float* __restrict__ concat_W, const float* __restrict__ nop_W,
              ushort_t* __restrict__ gc1LT, ushort_t* __restrict__ gc2WT,
              ushort_t* __restrict__ woWb, ushort_t* __restrict__ otWb,
              float* __restrict__ cWT, float* __restrict__ nWT)
{
  int idx = blockIdx.x * 256 + threadIdx.x;
  if (idx < 262144) {
    const int d = idx >> 9, k = idx & 511;
    gc1LT[idx] = f2bf(gc1_W[(size_t)(512 + k) * 512 + d]);
    return;
  }
  idx -= 262144;
  if (idx < 524288) {
    const int e = idx >> 9, d = idx & 511;
    gc2WT[idx] = f2bf(gc2_W[(size_t)d * 1024 + e]);
    return;
  }
  idx -= 524288;
  if (idx < 524288) { woWb[idx] = f2bf(wo_W[idx]); return; }
  idx -= 524288;
  if (idx < 524288) { otWb[idx] = f2bf(ot_W[idx]); return; }
  idx -= 524288;
  if (idx < 524288) {
    const int k = idx >> 9, o = idx & 511;
    cWT[idx] = concat_W[(size_t)o * 1024 + k];
    return;
  }
  idx -= 524288;
  if (idx < 65536) {
    const int k = idx >> 7, j = idx & 127;
    nWT[idx] = (j < 124) ? nop_W[(size_t)j * 512 + k] : 0.f;
  }
}

__global__ __launch_bounds__(256)
void k_gru(const float* __restrict__ giT, const float* __restrict__ ghT,
           const float* __restrict__ last_hidden, const float* __restrict__ b_ih,
           const float* __restrict__ b_hh, float* __restrict__ hnew, float* __restrict__ hnew_out)
{
  const int idx = blockIdx.x * 256 + threadIdx.x;
  const int b = idx >> 9, tt = idx & 511;
  const float ir  = giT[tt * 64 + b]          + b_ih[tt];
  const float iz  = giT[(512 + tt) * 64 + b]  + b_ih[512 + tt];
  const float inn = giT[(1024 + tt) * 64 + b] + b_ih[1024 + tt];
  const float hr  = ghT[tt * 64 + b]          + b_hh[tt];
  const float hz  = ghT[(512 + tt) * 64 + b]  + b_hh[512 + tt];
  const float hn  = ghT[(1024 + tt) * 64 + b] + b_hh[1024 + tt];
  const float h   = last_hidden[idx];
  const float r = 1.f / (1.f + __expf(-(ir + hr)));
  const float z = 1.f / (1.f + __expf(-(iz + hz)));
  const float n = tanhf(inn + r * hn);
  const float o = (1.f - z) * n + z * h;
  hnew[idx] = o;
  hnew_out[idx] = o;
}

// q = h_new @ attn_W ; u = h_new @ gc1_W[:512].  grid (64,4) x 128 threads.
__global__ __launch_bounds__(128)
void k_qu(const float* __restrict__ hnew, const float* __restrict__ attn_W,
          const float* __restrict__ gc1_W, float* __restrict__ q, float* __restrict__ u)
{
  const int b = blockIdx.x, j = blockIdx.y * 128 + threadIdx.x;
  __shared__ float hs[512];
  for (int i = threadIdx.x; i < 512; i += 128) hs[i] = hnew[b * 512 + i];
  __syncthreads();
  float qa = 0.f, ua = 0.f;
  for (int h = 0; h < 512; ++h) {
    const float hv = hs[h];
    qa += hv * attn_W[(size_t)h * 512 + j];
    ua += hv * gc1_W[(size_t)h * 512 + j];
  }
  q[b * 512 + j] = qa;
  u[b * 512 + j] = ua;
}

// scores[b,s] = q[b]·enc[s,b]; also emits encbf[b][s][k] (bf16) when emit!=0.
__global__ __launch_bounds__(256)
void k_score(const float* __restrict__ q, const float* __restrict__ enc,
             float* __restrict__ scores, ushort_t* __restrict__ encb, int emit)
{
  const int b = blockIdx.x, p = blockIdx.y;
  const int t = threadIdx.x, wv = t >> 6, ln = t & 63;
  __shared__ float qs[512];
  for (int i = t; i < 512; i += 256) qs[i] = q[b * 512 + i];
  __syncthreads();
  const int e0 = ln * 8;
  const float4 q0 = *(const float4*)&qs[e0];
  const float4 q1 = *(const float4*)&qs[e0 + 4];
  for (int it = 0; it < 8; ++it) {
    const int s = p * 32 + wv * 8 + it;
    const float* e = enc + ((size_t)s * 64 + b) * 512 + e0;
    const float4 v0 = *(const float4*)e;
    const float4 v1 = *(const float4*)(e + 4);
    float a = q0.x * v0.x + q0.y * v0.y + q0.z * v0.z + q0.w * v0.w
            + q1.x * v1.x + q1.y * v1.y + q1.z * v1.z + q1.w * v1.w;
    if (emit) {
      short8 o;
      o[0] = (short)f2bf(v0.x); o[1] = (short)f2bf(v0.y);
      o[2] = (short)f2bf(v0.z); o[3] = (short)f2bf(v0.w);
      o[4] = (short)f2bf(v1.x); o[5] = (short)f2bf(v1.y);
      o[6] = (short)f2bf(v1.z); o[7] = (short)f2bf(v1.w);
      *(short8*)&encb[(size_t)b * 262144 + (size_t)s * 512 + e0] = o;
    }
    a = wave_sum(a);
    if (ln == 0) scores[b * 512 + s] = a;
  }
}

// softmax over scores -> aw (ws + output)
__global__ __launch_bounds__(512)
void k_softmax(const float* __restrict__ scores, float* __restrict__ aw_dout,
               float* __restrict__ aw_ws)
{
  const int b = blockIdx.x, t = threadIdx.x;
  const int w = t >> 6, lane = t & 63;
  __shared__ float red[8];
  const float v = scores[b * 512 + t];
  float m = wave_max(v);
  if (lane == 0) red[w] = m;
  __syncthreads();
  float mm = red[0];
#pragma unroll
  for (int i = 1; i < 8; ++i) mm = fmaxf(mm, red[i]);
  const float e = __expf(v - mm);
  float s = wave_sum(e);
  __syncthreads();
  if (lane == 0) red[w] = s;
  __syncthreads();
  float tot = 0.f;
#pragma unroll
  for (int i = 0; i < 8; ++i) tot += red[i];
  const float awv = e / tot;
  aw_dout[b * 512 + t] = awv;
  aw_ws[b * 512 + t]   = awv;
}

// context partials: ctxpart[b][p][t] = sum_{s in p-chunk} aw[b,s]*enc[s,b,t]
// reads bf16 encb when use_bf (emitted by k_score), else fp32 enc.
__global__ __launch_bounds__(512)
void k_ctx(const float* __restrict__ aw, const float* __restrict__ enc,
           const ushort_t* __restrict__ encb, float* __restrict__ ctxpart, int use_bf)
{
  const int b = blockIdx.x, p = blockIdx.y, t = threadIdx.x;
  __shared__ float aws[32];
  if (t < 32) aws[t] = aw[b * 512 + p * 32 + t];
  __syncthreads();
  float acc = 0.f;
  if (use_bf) {
#pragma unroll 4
    for (int si = 0; si < 32; ++si)
      acc += aws[si] * bf2f(encb[((size_t)b * 512 + p * 32 + si) * 512 + t]);
  } else {
#pragma unroll 4
    for (int si = 0; si < 32; ++si)
      acc += aws[si] * enc[((size_t)(p * 32 + si) * 64 + b) * 512 + t];
  }
  ctxpart[((size_t)b * 16 + p) * 512 + t] = acc;
}

// concat_output = relu([h_new, sum_p ctxpart] @ cWT + b).  grid (64,4) x 128.
__global__ __launch_bounds__(128)
void k_concat(const float* __restrict__ hnew, const float* __restrict__ ctxpart,
              const float* __restrict__ cWT, const float* __restrict__ bias,
              float* __restrict__ out_cc, float* __restrict__ cc_ws)
{
  const int b = blockIdx.x, o = blockIdx.y * 128 + threadIdx.x;
  __shared__ __align__(16) float cat[1024];
  for (int m = 0; m < 8; ++m) {
    const int i = threadIdx.x + 128 * m;
    if (i < 512) {
      cat[i] = hnew[b * 512 + i];
    } else {
      const int d = i - 512;
      float s = 0.f;
#pragma unroll
      for (int pp = 0; pp < 16; ++pp) s += ctxpart[((size_t)b * 16 + pp) * 512 + d];
      cat[i] = s;
    }
  }
  __syncthreads();
  float acc = bias[o];
  for (int k = 0; k < 1024; k += 4) {
    acc += cat[k]     * cWT[(size_t)k * 512 + o]
         + cat[k + 1] * cWT[(size_t)(k + 1) * 512 + o]
         + cat[k + 2] * cWT[(size_t)(k + 2) * 512 + o]
         + cat[k + 3] * cWT[(size_t)(k + 3) * 512 + o];
  }
  acc = fmaxf(acc, 0.f);
  out_cc[b * 512 + o] = acc;
  cc_ws[b * 512 + o]  = acc;
}

__global__ __launch_bounds__(512)
void k_wo(const float* __restrict__ word_op, const int* __restrict__ seq_mask, float* __restrict__ won)
{
  const int b = blockIdx.x, o = blockIdx.y, s = threadIdx.x;
  float v = word_op[((size_t)(b * 512 + s)) * 4 + o];
  if (seq_mask[b * 512 + s] != 0) v = 0.f;
  __shared__ float red[8];
  float sm = wave_sum(v);
  if ((s & 63) == 0) red[s >> 6] = sm;
  __syncthreads();
  float tot = 0.f;
#pragma unroll
  for (int i = 0; i < 8; ++i) tot += red[i];
  won[((size_t)b * 4 + o) * 512 + s] = v / (tot + 1e-30f);
}

// adj (bf16) for chunk
__global__ __launch_bounds__(256)
void k_adjc(const float* __restrict__ ww, const int* __restrict__ ex,
            ushort_t* __restrict__ adj, int c0)
{
  const size_t i = (size_t)blockIdx.x * 256 + threadIdx.x;
  const size_t base4 = (size_t)c0 * 512 * 512 / 4;
  const float4 w4 = ((const float4*)ww)[base4 + i];
  const int4   e4 = ((const int4*)ex)[base4 + i];
  ushort4 r;
  r.x = (e4.x == 1) ? f2bf(w4.x) : 0;
  r.y = (e4.y == 1) ? f2bf(w4.y) : 0;
  r.z = (e4.z == 1) ? f2bf(w4.z) : 0;
  r.w = (e4.w == 1) ? f2bf(w4.w) : 0;
  ((ushort4*)adj)[i] = r;
}

// enc (bf16, batch-packed) for chunk (only used when CB<64)
__global__ __launch_bounds__(256)
void k_encc(const float* __restrict__ enc, ushort_t* __restrict__ encb, int c0)
{
  const size_t i = (size_t)blockIdx.x * 256 + threadIdx.x;
  const size_t el = i * 4;
  const int k = el & 511;
  const int s = (el >> 9) & 511;
  const int z = el >> 18;
  const float4 v = *(const float4*)&enc[((size_t)s * 64 + c0 + z) * 512 + k];
  ushort4 r;
  r.x = f2bf(v.x); r.y = f2bf(v.y); r.z = f2bf(v.z); r.w = f2bf(v.w);
  ((ushort4*)encb)[i] = r;
}

// Barrier-free fused LN + residual + wo_n contraction.
// grid (CB, 8); 4 waves/block; wave handles 16 s-rows, one full row (1024 d) per iter.
__global__ __launch_bounds__(256)
void k_red2(const ushort_t* __restrict__ w2w, const float* __restrict__ aw,
            const float* __restrict__ hnew, const ushort_t* __restrict__ encb,
            const float* __restrict__ won, const float* __restrict__ ng,
            const float* __restrict__ nb, float* __restrict__ part, int c0)
{
  const int z = blockIdx.x, b = c0 + z, yb = blockIdx.y;
  const int t = threadIdx.x, wv = t >> 6, ln = t & 63;
  __shared__ float sw[64][5];               // won0..3, aw per s-local
  __shared__ float accs[2][4][1024];        // cross-wave combine (32 KB)
  for (int i = t; i < 320; i += 256) {
    const int sl = i / 5, c_ = i - sl * 5;
    const int sg = yb * 64 + sl;
    sw[sl][c_] = (c_ < 4) ? won[((size_t)b * 4 + c_) * 512 + sg] : aw[b * 512 + sg];
  }
  const int d0 = ln * 16;
  float gg[16], bb[16], hv[16];
#pragma unroll
  for (int k = 0; k < 16; k += 4) {
    *(float4*)&gg[k] = *(const float4*)&ng[d0 + k];
    *(float4*)&bb[k] = *(const float4*)&nb[d0 + k];
  }
  if (ln < 32) {
#pragma unroll
    for (int k = 0; k < 16; k += 4)
      *(float4*)&hv[k] = *(const float4*)&hnew[b * 512 + d0 + k];
  }
  float acc[4][16];
#pragma unroll
  for (int o = 0; o < 4; ++o)
#pragma unroll
    for (int k = 0; k < 16; ++k) acc[o][k] = 0.f;
  __syncthreads();
  for (int it = 0; it < 16; ++it) {
    const int sl = wv * 16 + it;
    const int s = yb * 64 + sl;
    const ushort_t* row = w2w + ((size_t)z * 512 + s) * 1024 + d0;
    float x[16];
    bf8_to_f(row, x);
    bf8_to_f(row + 8, x + 8);
    float ls = 0.f, lss = 0.f;
#pragma unroll
    for (int k = 0; k < 16; ++k) { ls += x[k]; lss += x[k] * x[k]; }
#pragma unroll
    for (int off = 32; off; off >>= 1) {
      ls  += __shfl_xor(ls,  off, 64);
      lss += __shfl_xor(lss, off, 64);
    }
    const float mean = ls * (1.f / 1024.f);
    const float var  = lss * (1.f / 1024.f) - mean * mean;
    const float inv  = rsqrtf(var + 1e-6f);
    float res[16];
    if (ln < 32) {
      const float a_ = sw[sl][4];
#pragma unroll
      for (int k = 0; k < 16; ++k) res[k] = a_ * hv[k];
    } else {
      const ushort_t* er = encb + ((size_t)z * 512 + s) * 512 + (d0 - 512);
      bf8_to_f(er, res);
      bf8_to_f(er + 8, res + 8);
    }
    const float w0 = sw[sl][0], w1 = sw[sl][1], w2 = sw[sl][2], w3 = sw[sl][3];
#pragma unroll
    for (int k = 0; k < 16; ++k) {
      const float val = (x[k] - mean) * inv * gg[k] + bb[k] + res[k];
      acc[0][k] += w0 * val; acc[1][k] += w1 * val;
      acc[2][k] += w2 * val; acc[3][k] += w3 * val;
    }
  }
  if (wv < 2) {
#pragma unroll
    for (int o = 0; o < 4; ++o)
#pragma unroll
      for (int k = 0; k < 16; k += 4)
        *(float4*)&accs[wv][o][d0 + k] = *(float4*)&acc[o][k];
  }
  __syncthreads();
  if (wv >= 2) {
#pragma unroll
    for (int o = 0; o < 4; ++o)
#pragma unroll
      for (int k = 0; k < 16; ++k)
        accs[wv - 2][o][d0 + k] += acc[o][k];
  }
  __syncthreads();
  for (int i = t; i < 4096; i += 256) {
    const int o = i >> 10, d = i & 1023;
    part[(((size_t)(b * 8 + yb) * 4 + o) << 10) + d] = accs[0][o][d] + accs[1][o][d];
  }
}

// sum 8 partials -> ctx_op bf16 (256 x 1024)
__global__ __launch_bounds__(256)
void k_psum(const float* __restrict__ part, ushort_t* __restrict__ ctxop)
{
  const int idx = blockIdx.x * 256 + threadIdx.x;   // 262144
  const int r = idx >> 10, d = idx & 1023;
  const int b = r >> 2, o = r & 3;
  float s = 0.f;
#pragma unroll
  for (int p = 0; p < 8; ++p)
    s += part[(((size_t)(b * 8 + p) * 4 + o) << 10) + d];
  ctxop[idx] = f2bf(s);
}

// relu+bias, LN1, build op_all bf16 = [s1, ops[o]]
__global__ __launch_bounds__(512)
void k_ln1(const float* __restrict__ oppre, const float* __restrict__ wo_b,
           const float* __restrict__ n1g, const float* __restrict__ n1b,
           const float* __restrict__ ops, ushort_t* __restrict__ opall)
{
  const int r = blockIdx.x, t = threadIdx.x;
  const int o = r & 3;
  __shared__ float2 red[8];
  const float val = fmaxf(oppre[(size_t)r * 512 + t] + wo_b[t], 0.f);
  const float2 ss = blocksum2(val, val * val, red, t, 8);
  const float m = ss.x * (1.f / 512.f);
  const float v = ss.y * (1.f / 512.f) - m * m;
  const float s1 = (val - m) * rsqrtf(v + 1e-6f) * n1g[t] + n1b[t];
  opall[(size_t)r * 1024 + t] = f2bf(s1);
  opall[(size_t)r * 1024 + 512 + t] = f2bf(ops[o * 512 + t]);
}

// relu+bias, LN2 + ops, dot with concat_output -> oo
__global__ __launch_bounds__(512)
void k_ln2dot(const float* __restrict__ ohpre, const float* __restrict__ ot_b,
              const float* __restrict__ n2g, const float* __restrict__ n2b,
              const float* __restrict__ ops, const float* __restrict__ cc,
              const float* __restrict__ ops_bias, float* __restrict__ oo)
{
  const int r = blockIdx.x, t = threadIdx.x;
  const int b = r >> 2, o = r & 3;
  __shared__ float2 red[8];
  const float oh = fmaxf(ohpre[(size_t)r * 512 + t] + ot_b[t], 0.f);
  const float2 ss = blocksum2(oh, oh * oh, red, t, 8);
  const float m = ss.x * (1.f / 512.f);
  const float v = ss.y * (1.f / 512.f) - m * m;
  const float opo = (oh - m) * rsqrtf(v + 1e-6f) * n2g[t] + n2b[t] + ops[o * 512 + t];
  const float p = cc[b * 512 + t] * opo;
  const float2 s3 = blocksum2(p, 0.f, red, t, 8);
  if (t == 0) oo[r] = s3.x + ops_bias[o];
}

// nop head (coalesced via nWT) + log_softmax over 128
__global__ __launch_bounds__(128)
void k_final(const float* __restrict__ oo, const float* __restrict__ cc,
             const float* __restrict__ nWT, const float* __restrict__ nop_b,
             float* __restrict__ outp)
{
  const int b = blockIdx.x, t = threadIdx.x;
  __shared__ __align__(16) float ccs[512];
  __shared__ float red[2];
  __shared__ float red2[2];
  for (int i = t; i < 512; i += 128) ccs[i] = cc[b * 512 + i];
  __syncthreads();
  float v;
  if (t < 4) {
    v = oo[b * 4 + t];
  } else {
    const int j = t - 4;
    float a = nop_b[j];
    for (int k = 0; k < 512; ++k) a += ccs[k] * nWT[k * 128 + j];
    v = a;
  }
  float m = wave_max(v);
  if ((t & 63) == 0) red[t >> 6] = m;
  __syncthreads();
  m = fmaxf(red[0], red[1]);
  const float e = __expf(v - m);
  float s = wave_sum(e);
  if ((t & 63) == 0) red2[t >> 6] = s;
  __syncthreads();
  s = red2[0] + red2[1];
  outp[b * 128 + t] = v - m - logf(s);
}

} // namespace

extern "C" void kernel_launch(void* const* d_in, const int* in_sizes, int n_in,
                              void* d_out, int out_size, void* d_ws, size_t ws_size,
                              hipStream_t stream)
{
  const int*   input_step  = (const int*)  d_in[0];
  const float* last_hidden = (const float*)d_in[1];
  const float* enc         = (const float*)d_in[2];
  const float* word_word   = (const float*)d_in[3];
  const float* word_op     = (const float*)d_in[4];
  const int*   word_exist  = (const int*)  d_in[5];
  const int*   seq_mask    = (const int*)  d_in[6];
  const float* emb         = (const float*)d_in[7];
  const float* W_ih        = (const float*)d_in[8];
  const float* W_hh        = (const float*)d_in[9];
  const float* b_ih        = (const float*)d_in[10];
  const float* b_hh        = (const float*)d_in[11];
  const float* attn_W      = (const float*)d_in[12];
  const float* concat_W    = (const float*)d_in[14];
  const float* concat_b    = (const float*)d_in[15];
  const float* ops         = (const float*)d_in[16];
  const float* ops_bias    = (const float*)d_in[17];
  const float* nop_W       = (const float*)d_in[18];
  const float* nop_b       = (const float*)d_in[19];
  const float* gc1_W       = (const float*)d_in[20];
  const float* gc1_b       = (const float*)d_in[21];
  const float* gc2_W       = (const float*)d_in[22];
  const float* gc2_b       = (const float*)d_in[23];
  const float* norm_g      = (const float*)d_in[24];
  const float* norm_b      = (const float*)d_in[25];
  const float* norm1_g     = (const float*)d_in[26];
  const float* norm1_b     = (const float*)d_in[27];
  const float* norm2_g     = (const float*)d_in[28];
  const float* norm2_b     = (const float*)d_in[29];
  const float* wo_W        = (const float*)d_in[30];
  const float* wo_b        = (const float*)d_in[31];
  const float* ot_W        = (const float*)d_in[32];
  const float* ot_b        = (const float*)d_in[33];

  float* ws  = (float*)d_ws;
  float* out = (float*)d_out;

  // ---- workspace layout (floats) ----
  size_t off = 0;
  auto take = [&](size_t n) { size_t o = off; off += n; return o; };
  const size_t o_hnew = take(32768);
  const size_t o_q    = take(32768);
  const size_t o_u    = take(32768);
  const size_t o_aw   = take(32768);
  const size_t o_scores = take(32768);
  const size_t o_ctxpart = take(524288);   // 64*16*512
  const size_t o_cc   = take(32768);
  const size_t o_won  = take(131072);
  const size_t o_oo   = take(256);
  const size_t o_xT   = take(32768);
  const size_t o_hT   = take(32768);
  const size_t o_giT  = take(98304);
  const size_t o_ghT  = take(98304); (void)o_ghT;
  const size_t o_part = take(2097152);
  const size_t o_oppre = take(131072);
  const size_t o_ohpre = take(131072);
  const size_t o_gc1LT = take(131072);
  const size_t o_gc2WT = take(262144);
  const size_t o_woW   = take(262144);
  const size_t o_otW   = take(262144);
  const size_t o_cWT   = take(524288);
  const size_t o_nWT   = take(65536);
  const size_t o_ctxop = take(131072);
  const size_t o_opall = take(131072);
  const size_t base = off;

  // pick chunk size by available workspace (constant across calls -> graph-safe)
  int CB = 16;
  if (ws_size >= (base + 64ull * 655360) * 4) CB = 64;
  else if (ws_size >= (base + 32ull * 655360) * 4) CB = 32;
  const int nch = 64 / CB;

  const size_t o_adjbf = take((size_t)CB * 131072);
  const size_t o_h1t   = take((size_t)CB * 131072);
  const size_t o_tmat  = take((size_t)CB * 131072);
  const size_t o_encbf = take((size_t)CB * 131072);
  const size_t o_xw1t  = take((size_t)CB * 131072);
  const size_t o_w2w   = o_adjbf;          // overlays adjbf+h1t (dead after mgemm<2>)

  float* hnew = ws + o_hnew;
  float* q    = ws + o_q;
  float* u    = ws + o_u;
  float* aw   = ws + o_aw;
  float* scores = ws + o_scores;
  float* ctxpart = ws + o_ctxpart;
  float* cc   = ws + o_cc;
  float* won  = ws + o_won;
  float* oo   = ws + o_oo;
  float* xT   = ws + o_xT;
  float* hT   = ws + o_hT;
  float* giT  = ws + o_giT;
  float* part = ws + o_part;
  float* oppre = ws + o_oppre;
  float* ohpre = ws + o_ohpre;
  float* cWT  = ws + o_cWT;
  float* nWT  = ws + o_nWT;
  ushort_t* gc1LT = (ushort_t*)(ws + o_gc1LT);
  ushort_t* gc2WT = (ushort_t*)(ws + o_gc2WT);
  ushort_t* woWb  = (ushort_t*)(ws + o_woW);
  ushort_t* otWb  = (ushort_t*)(ws + o_otW);
  ushort_t* ctxop = (ushort_t*)(ws + o_ctxop);
  ushort_t* opall = (ushort_t*)(ws + o_opall);
  ushort_t* adjbf = (ushort_t*)(ws + o_adjbf);
  ushort_t* h1t   = (ushort_t*)(ws + o_h1t);
  ushort_t* tmat  = (ushort_t*)(ws + o_tmat);
  ushort_t* encbf = (ushort_t*)(ws + o_encbf);
  ushort_t* xw1t  = (ushort_t*)(ws + o_xw1t);
  ushort_t* w2wbf = (ushort_t*)(ws + o_w2w);

  float* out_logits = out;
  float* out_hnew   = out + 8192;
  float* out_aw     = out + 8192 + 32768;
  float* out_cc     = out + 8192 + 65536;

  // ---- weight conversions + GRU ----
  k_prep_w<<<9472, 256, 0, stream>>>(gc1_W, gc2_W, wo_W, ot_W, concat_W, nop_W,
                                     gc1LT, gc2WT, woWb, otWb, cWT, nWT);
  k_prep<<<128, 256, 0, stream>>>(input_step, emb, last_hidden, xT, hT);
  gemm_gru<<<dim3(1, 24, 2), 256, 0, stream>>>(W_ih, xT, W_hh, hT, giT);
  k_gru<<<128, 256, 0, stream>>>(giT, ws + o_ghT, last_hidden, b_ih, b_hh, hnew, out_hnew);

  // ---- attention (split, parallel) + concat + wo_n ----
  k_qu<<<dim3(64, 4), 128, 0, stream>>>(hnew, attn_W, gc1_W, q, u);
  k_score<<<dim3(64, 16), 256, 0, stream>>>(q, enc, scores, encbf, CB == 64 ? 1 : 0);
  k_softmax<<<64, 512, 0, stream>>>(scores, out_aw, aw);
  k_ctx<<<dim3(64, 16), 512, 0, stream>>>(aw, enc, encbf, ctxpart, CB == 64 ? 1 : 0);
  k_concat<<<dim3(64, 4), 128, 0, stream>>>(hnew, ctxpart, cWT, concat_b, out_cc, cc);
  k_wo<<<dim3(64, 4), 512, 0, stream>>>(word_op, seq_mask, won);

  // ---- GCN chain (bf16 MFMA), chunked ----
  for (int c = 0; c < nch; ++c) {
    const int c0 = c * CB;
    k_adjc<<<CB * 256, 256, 0, stream>>>(word_word, word_exist, adjbf, c0);
    if (CB != 64) k_encc<<<CB * 256, 256, 0, stream>>>(enc, encbf, c0);
    // XW1T[d][s] = gc1LT[d][:] . enc_b[s][:] + u[b][d]*aw[b][s]
    mgemm<0><<<dim3(4, 4, CB), 256, 0, stream>>>(gc1LT, 512, 0, encbf, 512, 262144,
        xw1t, 512, 262144, 512, nullptr, aw, u, c0);
    // h1T[d][s] = relu(XW1T[d][:] . adj[s][:] + gc1_b[d])
    mgemm<1><<<dim3(4, 4, CB), 256, 0, stream>>>(xw1t, 512, 262144, adjbf, 512, 262144,
        h1t, 512, 262144, 512, gc1_b, nullptr, nullptr, 0);
    // t[s][d] = adj[s][:] . h1T[d][:]
    mgemm<2><<<dim3(4, 4, CB), 256, 0, stream>>>(adjbf, 512, 262144, h1t, 512, 262144,
        tmat, 512, 262144, 512, nullptr, nullptr, nullptr, 0);
    // w2w[s][e] = t[s][:] . gc2WT[e][:] + gc2_b[e]   (overlays adjbf+h1t)
    mgemm<3><<<dim3(8, 4, CB), 256, 0, stream>>>(tmat, 512, 262144, gc2WT, 512, 0,
        w2wbf, 1024, 524288, 512, gc2_b, nullptr, nullptr, 0);
    k_red2<<<dim3(CB, 8), 256, 0, stream>>>(w2wbf, aw, hnew, encbf, won, norm_g, norm_b, part, c0);
  }

  // ---- op head (MFMA GEMMs) + nop head + log_softmax ----
  k_psum<<<1024, 256, 0, stream>>>(part, ctxop);
  mgemm<4><<<dim3(4, 2, 1), 256, 0, stream>>>(ctxop, 1024, 0, woWb, 1024, 0,
      oppre, 512, 0, 1024, nullptr, nullptr, nullptr, 0);
  k_ln1<<<256, 512, 0, stream>>>(oppre, wo_b, norm1_g, norm1_b, ops, opall);
  mgemm<4><<<dim3(4, 2, 1), 256, 0, stream>>>(opall, 1024, 0, otWb, 1024, 0,
      ohpre, 512, 0, 1024, nullptr, nullptr, nullptr, 0);
  k_ln2dot<<<256, 512, 0, stream>>>(ohpre, ot_b, norm2_g, norm2_b, ops, cc, ops_bias, oo);
  k_final<<<64, 128, 0, stream>>>(oo, cc, nWT, nop_b, out_logits);

  (void)in_sizes; (void)n_in; (void)out_size;
}

// Round 6
// 644.139 us; speedup vs baseline: 3.2803x; 1.0202x over previous
//
#include <hip/hip_runtime.h>
#include <math.h>

namespace {

typedef unsigned short ushort_t;
typedef __attribute__((ext_vector_type(8))) short short8;
typedef __attribute__((ext_vector_type(4))) float float4v;

__device__ __forceinline__ unsigned short f2bf(float x) {
  unsigned u = __float_as_uint(x);
  u += 0x7fffu + ((u >> 16) & 1u);        // RNE
  return (unsigned short)(u >> 16);
}
__device__ __forceinline__ float bf2f(unsigned short u) {
  return __uint_as_float((unsigned)u << 16);
}
__device__ __forceinline__ void bf8_to_f(const ushort_t* p, float* o) {
  const short8 v = *(const short8*)p;
#pragma unroll
  for (int k = 0; k < 8; ++k) o[k] = bf2f((unsigned short)v[k]);
}

__device__ __forceinline__ float wave_sum(float v) {
#pragma unroll
  for (int off = 32; off; off >>= 1) v += __shfl_down(v, off, 64);
  return v;
}
__device__ __forceinline__ float wave_max(float v) {
#pragma unroll
  for (int off = 32; off; off >>= 1) v = fmaxf(v, __shfl_down(v, off, 64));
  return v;
}
__device__ __forceinline__ float2 blocksum2(float a, float b, float2* red, int t, int nw) {
#pragma unroll
  for (int off = 32; off; off >>= 1) {
    a += __shfl_down(a, off, 64);
    b += __shfl_down(b, off, 64);
  }
  __syncthreads();
  if ((t & 63) == 0) red[t >> 6] = make_float2(a, b);
  __syncthreads();
  float sa = 0.f, sb = 0.f;
  for (int i = 0; i < nw; ++i) { sa += red[i].x; sb += red[i].y; }
  return make_float2(sa, sb);
}

// =================== bf16 MFMA NT-GEMM, 128x128 tile, BK=64 ===================
// C[M,N] = A[M,K] * Bt[N,K]^T.  M,N multiples of 128, K mult of 64.
// XCD-aware z-grouped block swizzle (nz % 8 == 0) + LDS seg-XOR (bank-conflict-free).
// MODE 0: bf16 out, v += u[(c0+z)*512+row]*aw[(c0+z)*512+col]
// MODE 1: bf16 out, relu(v + bias[row])
// MODE 2: bf16 out, plain
// MODE 3: bf16 out, v + bias[col]
// MODE 4: f32 out, plain
template<int MODE>
__global__ __launch_bounds__(256)
void mgemm(const ushort_t* __restrict__ A, int lda, long sA,
           const ushort_t* __restrict__ Bt, int ldb, long sB,
           void* __restrict__ C, int ldc, long sC, int K,
           const float* __restrict__ bias,
           const float* __restrict__ aw, const float* __restrict__ u, int c0)
{
  __shared__ __attribute__((aligned(16))) ushort_t As[2][128 * 32];
  __shared__ __attribute__((aligned(16))) ushort_t Bs[2][128 * 32];

  // ---- XCD-aware swizzle: group all xy-tiles of one z on one XCD ----
  int bx = blockIdx.x, by = blockIdx.y, bz = blockIdx.z;
  const int nx = gridDim.x, ny = gridDim.y, nz = gridDim.z;
  if ((nz & 7) == 0) {
    const int nxy = nx * ny;
    const int L = bx + nx * (by + ny * bz);
    const int xcd = L & 7;
    const int idx = L >> 3;
    const int lz = idx / nxy;
    const int xy = idx - lz * nxy;
    bz = xcd + 8 * lz;
    bx = xy % nx;
    by = xy / nx;
  }

  const int z = bz;
  const ushort_t* Ab = A  + (long)z * sA;
  const ushort_t* Bb = Bt + (long)z * sB;
  const int tm = by * 128, tn = bx * 128;
  const int t = threadIdx.x, wv = t >> 6, ln = t & 63;
  const int lrow = ln >> 2, lseg = ln & 3;        // staging: 16 rows x 4 segs of 16B
  const int gseg = lseg ^ ((lrow >> 1) & 3);      // bank-conflict-free seg XOR
  const int frow = ln & 15, q = ln >> 4;          // fragment: m=ln&15, k-quad
  const int sw8 = (frow >> 1) & 3;
  const int aoff = (q ^ sw8) << 3;
  const int wm = (wv >> 1) * 64, wn = (wv & 1) * 64;

  float4v acc[4][4];
#pragma unroll
  for (int i = 0; i < 4; ++i)
#pragma unroll
    for (int j = 0; j < 4; ++j) acc[i][j] = (float4v)0.f;

  for (int k0 = 0; k0 < K; k0 += 64) {
#pragma unroll
    for (int h2 = 0; h2 < 2; ++h2) {
#pragma unroll
      for (int half = 0; half < 2; ++half) {
        const int rbase = wv * 32 + half * 16;
        const ushort_t* ga = Ab + (long)(tm + rbase + lrow) * lda + k0 + h2 * 32 + gseg * 8;
        const ushort_t* gb = Bb + (long)(tn + rbase + lrow) * ldb + k0 + h2 * 32 + gseg * 8;
        __builtin_amdgcn_global_load_lds(
            (const __attribute__((address_space(1))) void*)ga,
            (__attribute__((address_space(3))) void*)&As[h2][rbase * 32], 16, 0, 0);
        __builtin_amdgcn_global_load_lds(
            (const __attribute__((address_space(1))) void*)gb,
            (__attribute__((address_space(3))) void*)&Bs[h2][rbase * 32], 16, 0, 0);
      }
    }
    __syncthreads();
#pragma unroll
    for (int h2 = 0; h2 < 2; ++h2) {
      short8 af[4], bfr[4];
#pragma unroll
      for (int i = 0; i < 4; ++i) af[i]  = *(const short8*)&As[h2][(wm + i * 16 + frow) * 32 + aoff];
#pragma unroll
      for (int j = 0; j < 4; ++j) bfr[j] = *(const short8*)&Bs[h2][(wn + j * 16 + frow) * 32 + aoff];
#pragma unroll
      for (int i = 0; i < 4; ++i)
#pragma unroll
        for (int j = 0; j < 4; ++j)
          acc[i][j] = __builtin_amdgcn_mfma_f32_16x16x32_bf16(af[i], bfr[j], acc[i][j], 0, 0, 0);
    }
    __syncthreads();
  }

  // epilogue: C/D layout col=lane&15, row=(lane>>4)*4+reg
#pragma unroll
  for (int i = 0; i < 4; ++i) {
#pragma unroll
    for (int j = 0; j < 4; ++j) {
      const int col = tn + wn + j * 16 + (ln & 15);
#pragma unroll
      for (int reg = 0; reg < 4; ++reg) {
        const int row = tm + wm + i * 16 + (ln >> 4) * 4 + reg;
        float v = acc[i][j][reg];
        if (MODE == 0) v += u[(c0 + z) * 512 + row] * aw[(c0 + z) * 512 + col];
        else if (MODE == 1) v = fmaxf(v + bias[row], 0.f);
        else if (MODE == 3) v += bias[col];
        if (MODE == 4) ((float*)C)[(long)z * sC + (long)row * ldc + col] = v;
        else ((ushort_t*)C)[(long)z * sC + (long)row * ldc + col] = f2bf(v);
      }
    }
  }
}

// =================== fused front kernel ===================
// Merges: weight bf16/transposed conversions, GRU input staging (bf16),
// full-64-batch adjacency conversion, wo_n normalization.
__global__ __launch_bounds__(256)
void k_front(const int* __restrict__ step, const float* __restrict__ emb,
             const float* __restrict__ last_hidden,
             const float* __restrict__ gc1_W, const float* __restrict__ gc2_W,
             const float* __restrict__ wo_W, const float* __restrict__ ot_W,
             const float* __restrict__ concat_W, const float* __restrict__ nop_W,
             const float* __restrict__ W_ih, const float* __restrict__ W_hh,
             const float* __restrict__ ww, const int* __restrict__ ex,
             const float* __restrict__ word_op, const int* __restrict__ seq_mask,
             ushort_t* __restrict__ gc1LT, ushort_t* __restrict__ gc2WT,
             ushort_t* __restrict__ woWb, ushort_t* __restrict__ otWb,
             float* __restrict__ cWT, float* __restrict__ nWT,
             ushort_t* __restrict__ wihb, ushort_t* __restrict__ xhb,
             ushort_t* __restrict__ adj, float* __restrict__ won, int do_adj)
{
  const int blk = blockIdx.x;
  const int t = threadIdx.x;
  if (blk < 9472) {
    // weight conversions (flat idx)
    int idx = blk * 256 + t;
    if (idx < 262144) {
      const int d = idx >> 9, k = idx & 511;
      gc1LT[idx] = f2bf(gc1_W[(size_t)(512 + k) * 512 + d]);
      return;
    }
    idx -= 262144;
    if (idx < 524288) {
      const int e = idx >> 9, d = idx & 511;
      gc2WT[idx] = f2bf(gc2_W[(size_t)d * 1024 + e]);
      return;
    }
    idx -= 524288;
    if (idx < 524288) { woWb[idx] = f2bf(wo_W[idx]); return; }
    idx -= 524288;
    if (idx < 524288) { otWb[idx] = f2bf(ot_W[idx]); return; }
    idx -= 524288;
    if (idx < 524288) {
      const int k = idx >> 9, o = idx & 511;
      cWT[idx] = concat_W[(size_t)o * 1024 + k];
      return;
    }
    idx -= 524288;
    if (idx < 65536) {
      const int k = idx >> 7, j = idx & 127;
      nWT[idx] = (j < 124) ? nop_W[(size_t)j * 512 + k] : 0.f;
    }
    return;
  }
  if (blk < 15616) {
    // GRU weights bf16: wihb = [W_ih ; W_hh]
    const int idx = (blk - 9472) * 256 + t;   // < 1572864
    if (idx < 786432) wihb[idx] = f2bf(W_ih[idx]);
    else              wihb[idx] = f2bf(W_hh[idx - 786432]);
    return;
  }
  if (blk < 16128) {
    // GRU inputs bf16, N padded 64->128 with zeros: xhb[z][b][k]
    const int idx = (blk - 15616) * 256 + t;  // < 131072
    const int z = idx >> 16, rem = idx & 65535, b = rem >> 9, k = rem & 511;
    float v = 0.f;
    if (b < 64) v = z ? last_hidden[b * 512 + k] : emb[(size_t)step[b] * 512 + k];
    xhb[idx] = f2bf(v);
    return;
  }
  if (blk < 32512) {
    // adjacency bf16 (all 64 batches; only when CB==64)
    if (!do_adj) return;
    const size_t i = (size_t)(blk - 16128) * 256 + t;
    const float4 w4 = ((const float4*)ww)[i];
    const int4   e4 = ((const int4*)ex)[i];
    ushort4 r;
    r.x = (e4.x == 1) ? f2bf(w4.x) : 0;
    r.y = (e4.y == 1) ? f2bf(w4.y) : 0;
    r.z = (e4.z == 1) ? f2bf(w4.z) : 0;
    r.w = (e4.w == 1) ? f2bf(w4.w) : 0;
    ((ushort4*)adj)[i] = r;
    return;
  }
  {
    // wo_n normalization: block r=(b,o), 256 threads handle s and s+256
    const int r = blk - 32512;
    const int b = r >> 2, o = r & 3;
    __shared__ float red[4];
    float v0 = word_op[((size_t)(b * 512 + t)) * 4 + o];
    if (seq_mask[b * 512 + t] != 0) v0 = 0.f;
    float v1 = word_op[((size_t)(b * 512 + t + 256)) * 4 + o];
    if (seq_mask[b * 512 + t + 256] != 0) v1 = 0.f;
    const float sm = wave_sum(v0 + v1);
    if ((t & 63) == 0) red[t >> 6] = sm;
    __syncthreads();
    const float tot = red[0] + red[1] + red[2] + red[3] + 1e-30f;
    won[((size_t)b * 4 + o) * 512 + t]       = v0 / tot;
    won[((size_t)b * 4 + o) * 512 + t + 256] = v1 / tot;
  }
}

// =================== small fused kernels ===================

// GRU gate combine; gi2 holds gi (1536x128) then gh (1536x128) f32
__global__ __launch_bounds__(256)
void k_gru(const float* __restrict__ gi2, const float* __restrict__ last_hidden,
           const float* __restrict__ b_ih, const float* __restrict__ b_hh,
           float* __restrict__ hnew, float* __restrict__ hnew_out)
{
  const int idx = blockIdx.x * 256 + threadIdx.x;
  const int b = idx >> 9, tt = idx & 511;
  const float* gh = gi2 + 196608;
  const float ir  = gi2[tt * 128 + b]          + b_ih[tt];
  const float iz  = gi2[(512 + tt) * 128 + b]  + b_ih[512 + tt];
  const float inn = gi2[(1024 + tt) * 128 + b] + b_ih[1024 + tt];
  const float hr  = gh[tt * 128 + b]          + b_hh[tt];
  const float hz  = gh[(512 + tt) * 128 + b]  + b_hh[512 + tt];
  const float hn  = gh[(1024 + tt) * 128 + b] + b_hh[1024 + tt];
  const float h   = last_hidden[idx];
  const float r = 1.f / (1.f + __expf(-(ir + hr)));
  const float z = 1.f / (1.f + __expf(-(iz + hz)));
  const float n = tanhf(inn + r * hn);
  const float o = (1.f - z) * n + z * h;
  hnew[idx] = o;
  hnew_out[idx] = o;
}

// q = h_new @ attn_W ; u = h_new @ gc1_W[:512].  grid (64,4) x 128 threads.
__global__ __launch_bounds__(128)
void k_qu(const float* __restrict__ hnew, const float* __restrict__ attn_W,
          const float* __restrict__ gc1_W, float* __restrict__ q, float* __restrict__ u)
{
  const int b = blockIdx.x, j = blockIdx.y * 128 + threadIdx.x;
  __shared__ float hs[512];
  for (int i = threadIdx.x; i < 512; i += 128) hs[i] = hnew[b * 512 + i];
  __syncthreads();
  float qa = 0.f, ua = 0.f;
  for (int h = 0; h < 512; ++h) {
    const float hv = hs[h];
    qa += hv * attn_W[(size_t)h * 512 + j];
    ua += hv * gc1_W[(size_t)h * 512 + j];
  }
  q[b * 512 + j] = qa;
  u[b * 512 + j] = ua;
}

// scores[b,s] = q[b]·enc[s,b]; also emits encbf[b][s][k] (bf16) when emit!=0.
__global__ __launch_bounds__(256)
void k_score(const float* __restrict__ q, const float* __restrict__ enc,
             float* __restrict__ scores, ushort_t* __restrict__ encb, int emit)
{
  const int b = blockIdx.x, p = blockIdx.y;
  const int t = threadIdx.x, wv = t >> 6, ln = t & 63;
  __shared__ float qs[512];
  for (int i = t; i < 512; i += 256) qs[i] = q[b * 512 + i];
  __syncthreads();
  const int e0 = ln * 8;
  const float4 q0 = *(const float4*)&qs[e0];
  const float4 q1 = *(const float4*)&qs[e0 + 4];
  for (int it = 0; it < 8; ++it) {
    const int s = p * 32 + wv * 8 + it;
    const float* e = enc + ((size_t)s * 64 + b) * 512 + e0;
    const float4 v0 = *(const float4*)e;
    const float4 v1 = *(const float4*)(e + 4);
    float a = q0.x * v0.x + q0.y * v0.y + q0.z * v0.z + q0.w * v0.w
            + q1.x * v1.x + q1.y * v1.y + q1.z * v1.z + q1.w * v1.w;
    if (emit) {
      short8 o;
      o[0] = (short)f2bf(v0.x); o[1] = (short)f2bf(v0.y);
      o[2] = (short)f2bf(v0.z); o[3] = (short)f2bf(v0.w);
      o[4] = (short)f2bf(v1.x); o[5] = (short)f2bf(v1.y);
      o[6] = (short)f2bf(v1.z); o[7] = (short)f2bf(v1.w);
      *(short8*)&encb[(size_t)b * 262144 + (size_t)s * 512 + e0] = o;
    }
    a = wave_sum(a);
    if (ln == 0) scores[b * 512 + s] = a;
  }
}

// Fused softmax + context partials.  grid (64,16) x 512.
// Every block recomputes the 512-wide softmax from scores (cheap, deterministic,
// identical across blocks); block p==0 writes aw (output + ws copy).
__global__ __launch_bounds__(512)
void k_ctx2(const float* __restrict__ scores, const ushort_t* __restrict__ encb,
            const float* __restrict__ enc, float* __restrict__ aw_dout,
            float* __restrict__ aw_ws, float* __restrict__ ctxpart, int use_bf)
{
  const int b = blockIdx.x, p = blockIdx.y, t = threadIdx.x;
  const int w = t >> 6, lane = t & 63;
  __shared__ float sc[512];
  __shared__ float red[8];
  __shared__ float red2[8];
  const float v = scores[b * 512 + t];
  float m = wave_max(v);
  if (lane == 0) red[w] = m;
  __syncthreads();
  float mm = red[0];
#pragma unroll
  for (int i = 1; i < 8; ++i) mm = fmaxf(mm, red[i]);
  const float e = __expf(v - mm);
  float s = wave_sum(e);
  if (lane == 0) red2[w] = s;
  __syncthreads();
  float tot = 0.f;
#pragma unroll
  for (int i = 0; i < 8; ++i) tot += red2[i];
  const float awv = e / tot;
  sc[t] = awv;
  if (p == 0) {
    aw_dout[b * 512 + t] = awv;
    aw_ws[b * 512 + t]   = awv;
  }
  __syncthreads();
  float acc = 0.f;
  if (use_bf) {
#pragma unroll 4
    for (int si = 0; si < 32; ++si)
      acc += sc[p * 32 + si] * bf2f(encb[((size_t)b * 512 + p * 32 + si) * 512 + t]);
  } else {
#pragma unroll 4
    for (int si = 0; si < 32; ++si)
      acc += sc[p * 32 + si] * enc[((size_t)(p * 32 + si) * 64 + b) * 512 + t];
  }
  ctxpart[((size_t)b * 16 + p) * 512 + t] = acc;
}

// concat_output = relu([h_new, sum_p ctxpart] @ cWT + b).  grid (64,4) x 128.
__global__ __launch_bounds__(128)
void k_concat(const float* __restrict__ hnew, const float* __restrict__ ctxpart,
              const float* __restrict__ cWT, const float* __restrict__ bias,
              float* __restrict__ out_cc, float* __restrict__ cc_ws)
{
  const int b = blockIdx.x, o = blockIdx.y * 128 + threadIdx.x;
  __shared__ __align__(16) float cat[1024];
  for (int m = 0; m < 8; ++m) {
    const int i = threadIdx.x + 128 * m;
    if (i < 512) {
      cat[i] = hnew[b * 512 + i];
    } else {
      const int d = i - 512;
      float s = 0.f;
#pragma unroll
      for (int pp = 0; pp < 16; ++pp) s += ctxpart[((size_t)b * 16 + pp) * 512 + d];
      cat[i] = s;
    }
  }
  __syncthreads();
  float acc = bias[o];
  for (int k = 0; k < 1024; k += 4) {
    acc += cat[k]     * cWT[(size_t)k * 512 + o]
         + cat[k + 1] * cWT[(size_t)(k + 1) * 512 + o]
         + cat[k + 2] * cWT[(size_t)(k + 2) * 512 + o]
         + cat[k + 3] * cWT[(size_t)(k + 3) * 512 + o];
  }
  acc = fmaxf(acc, 0.f);
  out_cc[b * 512 + o] = acc;
  cc_ws[b * 512 + o]  = acc;
}

// adj (bf16) for chunk (CB<64 fallback)
__global__ __launch_bounds__(256)
void k_adjc(const float* __restrict__ ww, const int* __restrict__ ex,
            ushort_t* __restrict__ adj, int c0)
{
  const size_t i = (size_t)blockIdx.x * 256 + threadIdx.x;
  const size_t base4 = (size_t)c0 * 512 * 512 / 4;
  const float4 w4 = ((const float4*)ww)[base4 + i];
  const int4   e4 = ((const int4*)ex)[base4 + i];
  ushort4 r;
  r.x = (e4.x == 1) ? f2bf(w4.x) : 0;
  r.y = (e4.y == 1) ? f2bf(w4.y) : 0;
  r.z = (e4.z == 1) ? f2bf(w4.z) : 0;
  r.w = (e4.w == 1) ? f2bf(w4.w) : 0;
  ((ushort4*)adj)[i] = r;
}

// enc (bf16, batch-packed) for chunk (CB<64 fallback)
__global__ __launch_bounds__(256)
void k_encc(const float* __restrict__ enc, ushort_t* __restrict__ encb, int c0)
{
  const size_t i = (size_t)blockIdx.x * 256 + threadIdx.x;
  const size_t el = i * 4;
  const int k = el & 511;
  const int s = (el >> 9) & 511;
  const int z = el >> 18;
  const float4 v = *(const float4*)&enc[((size_t)s * 64 + c0 + z) * 512 + k];
  ushort4 r;
  r.x = f2bf(v.x); r.y = f2bf(v.y); r.z = f2bf(v.z); r.w = f2bf(v.w);
  ((ushort4*)encb)[i] = r;
}

// Barrier-free fused LN + residual + wo_n contraction.
// grid (CB, 16); 4 waves/block; wave handles 8 s-rows, one full row (1024 d) per iter.
__global__ __launch_bounds__(256)
void k_red2(const ushort_t* __restrict__ w2w, const float* __restrict__ aw,
            const float* __restrict__ hnew, const ushort_t* __restrict__ encb,
            const float* __restrict__ won, const float* __restrict__ ng,
            const float* __restrict__ nb, float* __restrict__ part, int c0)
{
  const int z = blockIdx.x, b = c0 + z, yb = blockIdx.y;
  const int t = threadIdx.x, wv = t >> 6, ln = t & 63;
  __shared__ float sw[32][5];               // won0..3, aw per s-local
  __shared__ float accs[2][4][1024];        // cross-wave combine (32 KB)
  if (t < 160) {
    const int sl = t / 5, c_ = t - sl * 5;
    const int sg = yb * 32 + sl;
    sw[sl][c_] = (c_ < 4) ? won[((size_t)b * 4 + c_) * 512 + sg] : aw[b * 512 + sg];
  }
  const int d0 = ln * 16;
  float gg[16], bb[16], hv[16];
#pragma unroll
  for (int k = 0; k < 16; k += 4) {
    *(float4*)&gg[k] = *(const float4*)&ng[d0 + k];
    *(float4*)&bb[k] = *(const float4*)&nb[d0 + k];
  }
  if (ln < 32) {
#pragma unroll
    for (int k = 0; k < 16; k += 4)
      *(float4*)&hv[k] = *(const float4*)&hnew[b * 512 + d0 + k];
  }
  float acc[4][16];
#pragma unroll
  for (int o = 0; o < 4; ++o)
#pragma unroll
    for (int k = 0; k < 16; ++k) acc[o][k] = 0.f;
  __syncthreads();
  for (int it = 0; it < 8; ++it) {
    const int sl = wv * 8 + it;
    const int s = yb * 32 + sl;
    const ushort_t* row = w2w + ((size_t)z * 512 + s) * 1024 + d0;
    float x[16];
    bf8_to_f(row, x);
    bf8_to_f(row + 8, x + 8);
    float ls = 0.f, lss = 0.f;
#pragma unroll
    for (int k = 0; k < 16; ++k) { ls += x[k]; lss += x[k] * x[k]; }
#pragma unroll
    for (int off = 32; off; off >>= 1) {
      ls  += __shfl_xor(ls,  off, 64);
      lss += __shfl_xor(lss, off, 64);
    }
    const float mean = ls * (1.f / 1024.f);
    const float var  = lss * (1.f / 1024.f) - mean * mean;
    const float inv  = rsqrtf(var + 1e-6f);
    float res[16];
    if (ln < 32) {
      const float a_ = sw[sl][4];
#pragma unroll
      for (int k = 0; k < 16; ++k) res[k] = a_ * hv[k];
    } else {
      const ushort_t* er = encb + ((size_t)z * 512 + s) * 512 + (d0 - 512);
      bf8_to_f(er, res);
      bf8_to_f(er + 8, res + 8);
    }
    const float w0 = sw[sl][0], w1 = sw[sl][1], w2 = sw[sl][2], w3 = sw[sl][3];
#pragma unroll
    for (int k = 0; k < 16; ++k) {
      const float val = (x[k] - mean) * inv * gg[k] + bb[k] + res[k];
      acc[0][k] += w0 * val; acc[1][k] += w1 * val;
      acc[2][k] += w2 * val; acc[3][k] += w3 * val;
    }
  }
  if (wv < 2) {
#pragma unroll
    for (int o = 0; o < 4; ++o)
#pragma unroll
      for (int k = 0; k < 16; k += 4)
        *(float4*)&accs[wv][o][d0 + k] = *(float4*)&acc[o][k];
  }
  __syncthreads();
  if (wv >= 2) {
#pragma unroll
    for (int o = 0; o < 4; ++o)
#pragma unroll
      for (int k = 0; k < 16; ++k)
        accs[wv - 2][o][d0 + k] += acc[o][k];
  }
  __syncthreads();
  for (int i = t; i < 4096; i += 256) {
    const int o = i >> 10, d = i & 1023;
    part[(((size_t)(b * 16 + yb) * 4 + o) << 10) + d] = accs[0][o][d] + accs[1][o][d];
  }
}

// sum 16 partials -> ctx_op bf16 (256 x 1024)
__global__ __launch_bounds__(256)
void k_psum(const float* __restrict__ part, ushort_t* __restrict__ ctxop)
{
  const int idx = blockIdx.x * 256 + threadIdx.x;   // 262144
  const int r = idx >> 10, d = idx & 1023;
  const int b = r >> 2, o = r & 3;
  float s = 0.f;
#pragma unroll
  for (int p = 0; p < 16; ++p)
    s += part[(((size_t)(b * 16 + p) * 4 + o) << 10) + d];
  ctxop[idx] = f2bf(s);
}

// relu+bias, LN1, build op_all bf16 = [s1, ops[o]]
__global__ __launch_bounds__(512)
void k_ln1(const float* __restrict__ oppre, const float* __restrict__ wo_b,
           const float* __restrict__ n1g, const float* __restrict__ n1b,
           const float* __restrict__ ops, ushort_t* __restrict__ opall)
{
  const int r = blockIdx.x, t = threadIdx.x;
  const int o = r & 3;
  __shared__ float2 red[8];
  const float val = fmaxf(oppre[(size_t)r * 512 + t] + wo_b[t], 0.f);
  const float2 ss = blocksum2(val, val * val, red, t, 8);
  const float m = ss.x * (1.f / 512.f);
  const float v = ss.y * (1.f / 512.f) - m * m;
  const float s1 = (val - m) * rsqrtf(v + 1e-6f) * n1g[t] + n1b[t];
  opall[(size_t)r * 1024 + t] = f2bf(s1);
  opall[(size_t)r * 1024 + 512 + t] = f2bf(ops[o * 512 + t]);
}

// relu+bias, LN2 + ops, dot with concat_output -> oo
__global__ __launch_bounds__(512)
void k_ln2dot(const float* __restrict__ ohpre, const float* __restrict__ ot_b,
              const float* __restrict__ n2g, const float* __restrict__ n2b,
              const float* __restrict__ ops, const float* __restrict__ cc,
              const float* __restrict__ ops_bias, float* __restrict__ oo)
{
  const int r = blockIdx.x, t = threadIdx.x;
  const int b = r >> 2, o = r & 3;
  __shared__ float2 red[8];
  const float oh = fmaxf(ohpre[(size_t)r * 512 + t] + ot_b[t], 0.f);
  const float2 ss = blocksum2(oh, oh * oh, red, t, 8);
  const float m = ss.x * (1.f / 512.f);
  const float v = ss.y * (1.f / 512.f) - m * m;
  const float opo = (oh - m) * rsqrtf(v + 1e-6f) * n2g[t] + n2b[t] + ops[o * 512 + t];
  const float p = cc[b * 512 + t] * opo;
  const float2 s3 = blocksum2(p, 0.f, red, t, 8);
  if (t == 0) oo[r] = s3.x + ops_bias[o];
}

// nop head (coalesced via nWT) + log_softmax over 128
__global__ __launch_bounds__(128)
void k_final(const float* __restrict__ oo, const float* __restrict__ cc,
             const float* __restrict__ nWT, const float* __restrict__ nop_b,
             float* __restrict__ outp)
{
  const int b = blockIdx.x, t = threadIdx.x;
  __shared__ __align__(16) float ccs[512];
  __shared__ float red[2];
  __shared__ float red2[2];
  for (int i = t; i < 512; i += 128) ccs[i] = cc[b * 512 + i];
  __syncthreads();
  float v;
  if (t < 4) {
    v = oo[b * 4 + t];
  } else {
    const int j = t - 4;
    float a = nop_b[j];
    for (int k = 0; k < 512; ++k) a += ccs[k] * nWT[k * 128 + j];
    v = a;
  }
  float m = wave_max(v);
  if ((t & 63) == 0) red[t >> 6] = m;
  __syncthreads();
  m = fmaxf(red[0], red[1]);
  const float e = __expf(v - m);
  float s = wave_sum(e);
  if ((t & 63) == 0) red2[t >> 6] = s;
  __syncthreads();
  s = red2[0] + red2[1];
  outp[b * 128 + t] = v - m - logf(s);
}

} // namespace

extern "C" void kernel_launch(void* const* d_in, const int* in_sizes, int n_in,
                              void* d_out, int out_size, void* d_ws, size_t ws_size,
                              hipStream_t stream)
{
  const int*   input_step  = (const int*)  d_in[0];
  const float* last_hidden = (const float*)d_in[1];
  const float* enc         = (const float*)d_in[2];
  const float* word_word   = (const float*)d_in[3];
  const float* word_op     = (const float*)d_in[4];
  const int*   word_exist  = (const int*)  d_in[5];
  const int*   seq_mask    = (const int*)  d_in[6];
  const float* emb         = (const float*)d_in[7];
  const float* W_ih        = (const float*)d_in[8];
  const float* W_hh        = (const float*)d_in[9];
  const float* b_ih        = (const float*)d_in[10];
  const float* b_hh        = (const float*)d_in[11];
  const float* attn_W      = (const float*)d_in[12];
  const float* concat_W    = (const float*)d_in[14];
  const float* concat_b    = (const float*)d_in[15];
  const float* ops         = (const float*)d_in[16];
  const float* ops_bias    = (const float*)d_in[17];
  const float* nop_W       = (const float*)d_in[18];
  const float* nop_b       = (const float*)d_in[19];
  const float* gc1_W       = (const float*)d_in[20];
  const float* gc1_b       = (const float*)d_in[21];
  const float* gc2_W       = (const float*)d_in[22];
  const float* gc2_b       = (const float*)d_in[23];
  const float* norm_g      = (const float*)d_in[24];
  const float* norm_b      = (const float*)d_in[25];
  const float* norm1_g     = (const float*)d_in[26];
  const float* norm1_b     = (const float*)d_in[27];
  const float* norm2_g     = (const float*)d_in[28];
  const float* norm2_b     = (const float*)d_in[29];
  const float* wo_W        = (const float*)d_in[30];
  const float* wo_b        = (const float*)d_in[31];
  const float* ot_W        = (const float*)d_in[32];
  const float* ot_b        = (const float*)d_in[33];

  float* ws  = (float*)d_ws;
  float* out = (float*)d_out;

  // ---- workspace layout (floats) ----
  size_t off = 0;
  auto take = [&](size_t n) { size_t o = off; off += n; return o; };
  const size_t o_hnew = take(32768);
  const size_t o_q    = take(32768);
  const size_t o_u    = take(32768);
  const size_t o_aw   = take(32768);
  const size_t o_scores = take(32768);
  const size_t o_ctxpart = take(524288);   // 64*16*512
  const size_t o_cc   = take(32768);
  const size_t o_won  = take(131072);
  const size_t o_oo   = take(256);
  const size_t o_gi2  = take(393216);      // 2 x 1536 x 128 f32
  const size_t o_part = take(4194304);     // 64*16*4*1024
  const size_t o_oppre = take(131072);
  const size_t o_ohpre = take(131072);
  const size_t o_gc1LT = take(131072);
  const size_t o_gc2WT = take(262144);
  const size_t o_woW   = take(262144);
  const size_t o_otW   = take(262144);
  const size_t o_cWT   = take(524288);
  const size_t o_nWT   = take(65536);
  const size_t o_wihb  = take(786432);     // 2 x 1536 x 512 bf16
  const size_t o_xhb   = take(65536);      // 2 x 128 x 512 bf16
  const size_t o_ctxop = take(131072);
  const size_t o_opall = take(131072);
  const size_t base = off;

  // pick chunk size by available workspace (constant across calls -> graph-safe)
  int CB = 16;
  if (ws_size >= (base + 64ull * 524288) * 4) CB = 64;
  else if (ws_size >= (base + 32ull * 524288) * 4) CB = 32;
  const int nch = 64 / CB;

  const size_t o_adjbf = take((size_t)CB * 131072);
  const size_t o_h1t   = take((size_t)CB * 131072);
  const size_t o_encbf = take((size_t)CB * 131072);
  const size_t o_xw1t  = take((size_t)CB * 131072);
  const size_t o_tmat  = o_xw1t;           // overlays xw1t (dead after mgemm<1>)
  const size_t o_w2w   = o_adjbf;          // overlays adjbf+h1t (dead after mgemm<2>)

  float* hnew = ws + o_hnew;
  float* q    = ws + o_q;
  float* u    = ws + o_u;
  float* aw   = ws + o_aw;
  float* scores = ws + o_scores;
  float* ctxpart = ws + o_ctxpart;
  float* cc   = ws + o_cc;
  float* won  = ws + o_won;
  float* oo   = ws + o_oo;
  float* gi2  = ws + o_gi2;
  float* part = ws + o_part;
  float* oppre = ws + o_oppre;
  float* ohpre = ws + o_ohpre;
  float* cWT  = ws + o_cWT;
  float* nWT  = ws + o_nWT;
  ushort_t* gc1LT = (ushort_t*)(ws + o_gc1LT);
  ushort_t* gc2WT = (ushort_t*)(ws + o_gc2WT);
  ushort_t* woWb  = (ushort_t*)(ws + o_woW);
  ushort_t* otWb  = (ushort_t*)(ws + o_otW);
  ushort_t* wihb  = (ushort_t*)(ws + o_wihb);
  ushort_t* xhb   = (ushort_t*)(ws + o_xhb);
  ushort_t* ctxop = (ushort_t*)(ws + o_ctxop);
  ushort_t* opall = (ushort_t*)(ws + o_opall);
  ushort_t* adjbf = (ushort_t*)(ws + o_adjbf);
  ushort_t* h1t   = (ushort_t*)(ws + o_h1t);
  ushort_t* encbf = (ushort_t*)(ws + o_encbf);
  ushort_t* xw1t  = (ushort_t*)(ws + o_xw1t);
  ushort_t* tmat  = (ushort_t*)(ws + o_tmat);
  ushort_t* w2wbf = (ushort_t*)(ws + o_w2w);

  float* out_logits = out;
  float* out_hnew   = out + 8192;
  float* out_aw     = out + 8192 + 32768;
  float* out_cc     = out + 8192 + 65536;

  const int full = (CB == 64) ? 1 : 0;

  // ---- fused front (weights, GRU inputs, adjacency, wo_n) ----
  k_front<<<32768, 256, 0, stream>>>(input_step, emb, last_hidden,
      gc1_W, gc2_W, wo_W, ot_W, concat_W, nop_W, W_ih, W_hh,
      word_word, word_exist, word_op, seq_mask,
      gc1LT, gc2WT, woWb, otWb, cWT, nWT, wihb, xhb, adjbf, won, full);

  // ---- GRU via MFMA: gi/gh = [W_ih;W_hh] @ [x;h]^T, N padded to 128 ----
  mgemm<4><<<dim3(1, 12, 2), 256, 0, stream>>>(wihb, 512, 786432, xhb, 512, 65536,
      gi2, 128, 196608, 512, nullptr, nullptr, nullptr, 0);
  k_gru<<<128, 256, 0, stream>>>(gi2, last_hidden, b_ih, b_hh, hnew, out_hnew);

  // ---- attention + concat ----
  k_qu<<<dim3(64, 4), 128, 0, stream>>>(hnew, attn_W, gc1_W, q, u);
  k_score<<<dim3(64, 16), 256, 0, stream>>>(q, enc, scores, encbf, full);
  k_ctx2<<<dim3(64, 16), 512, 0, stream>>>(scores, encbf, enc, out_aw, aw, ctxpart, full);
  k_concat<<<dim3(64, 4), 128, 0, stream>>>(hnew, ctxpart, cWT, concat_b, out_cc, cc);

  // ---- GCN chain (bf16 MFMA), chunked ----
  for (int c = 0; c < nch; ++c) {
    const int c0 = c * CB;
    if (!full) {
      k_adjc<<<CB * 256, 256, 0, stream>>>(word_word, word_exist, adjbf, c0);
      k_encc<<<CB * 256, 256, 0, stream>>>(enc, encbf, c0);
    }
    // XW1T[d][s] = gc1LT[d][:] . enc_b[s][:] + u[b][d]*aw[b][s]
    mgemm<0><<<dim3(4, 4, CB), 256, 0, stream>>>(gc1LT, 512, 0, encbf, 512, 262144,
        xw1t, 512, 262144, 512, nullptr, aw, u, c0);
    // h1T[d][s] = relu(XW1T[d][:] . adj[s][:] + gc1_b[d])
    mgemm<1><<<dim3(4, 4, CB), 256, 0, stream>>>(xw1t, 512, 262144, adjbf, 512, 262144,
        h1t, 512, 262144, 512, gc1_b, nullptr, nullptr, 0);
    // t[s][d] = adj[s][:] . h1T[d][:]   (overlays xw1t, dead)
    mgemm<2><<<dim3(4, 4, CB), 256, 0, stream>>>(adjbf, 512, 262144, h1t, 512, 262144,
        tmat, 512, 262144, 512, nullptr, nullptr, nullptr, 0);
    // w2w[s][e] = t[s][:] . gc2WT[e][:] + gc2_b[e]   (overlays adjbf+h1t, dead)
    mgemm<3><<<dim3(8, 4, CB), 256, 0, stream>>>(tmat, 512, 262144, gc2WT, 512, 0,
        w2wbf, 1024, 524288, 512, gc2_b, nullptr, nullptr, 0);
    k_red2<<<dim3(CB, 16), 256, 0, stream>>>(w2wbf, aw, hnew, encbf, won, norm_g, norm_b, part, c0);
  }

  // ---- op head (MFMA GEMMs) + nop head + log_softmax ----
  k_psum<<<1024, 256, 0, stream>>>(part, ctxop);
  mgemm<4><<<dim3(4, 2, 1), 256, 0, stream>>>(ctxop, 1024, 0, woWb, 1024, 0,
      oppre, 512, 0, 1024, nullptr, nullptr, nullptr, 0);
  k_ln1<<<256, 512, 0, stream>>>(oppre, wo_b, norm1_g, norm1_b, ops, opall);
  mgemm<4><<<dim3(4, 2, 1), 256, 0, stream>>>(opall, 1024, 0, otWb, 1024, 0,
      ohpre, 512, 0, 1024, nullptr, nullptr, nullptr, 0);
  k_ln2dot<<<256, 512, 0, stream>>>(ohpre, ot_b, norm2_g, norm2_b, ops, cc, ops_bias, oo);
  k_final<<<64, 128, 0, stream>>>(oo, cc, nWT, nop_b, out_logits);

  (void)in_sizes; (void)n_in; (void)out_size;
}